// Round 1
// baseline (2119.368 us; speedup 1.0000x reference)
//
#include <hip/hip_runtime.h>
#include <hip/hip_bf16.h>

typedef __bf16 bf16;
typedef __bf16 bf16x8 __attribute__((ext_vector_type(8)));
typedef float f32x4 __attribute__((ext_vector_type(4)));

#define DEVI static __device__ __forceinline__

DEVI float sigmoidf_(float x){ return 1.0f/(1.0f+__expf(-x)); }
DEVI float eluf_(float x){ return x>0.f ? x : (__expf(x)-1.f); }
DEVI f32x4 mfma16(bf16x8 a, bf16x8 b, f32x4 c){ return __builtin_amdgcn_mfma_f32_16x16x32_bf16(a,b,c,0,0,0); }

#define B_ 8192
#define F_ 100
#define FP 112
#define H_ 128
#define HP 136

// ---------------- weight prep ----------------
__global__ void k_sigt(const float* __restrict__ tw, const float* __restrict__ tb,
                       const float* __restrict__ a1w, float* __restrict__ sigt){
    int j = threadIdx.x;
    float acc = 0.f;
    for (int h=0; h<128; ++h) acc += (tw[h]+tb[h]) * a1w[h*128+j];
    sigt[j] = sigmoidf_(acc);
}

// in [R][C] f32 -> out [C][R] bf16   (grid: (C/32, R/32), 256 thr)
__global__ void k_transpose_cvt(const float* __restrict__ in, bf16* __restrict__ out, int R, int C){
    __shared__ float t[32][33];
    int c0 = blockIdx.x*32, r0 = blockIdx.y*32;
    int tc = threadIdx.x & 31, tr = threadIdx.x >> 5;
    #pragma unroll
    for (int i=0;i<4;i++){
        int r = tr + i*8;
        t[r][tc] = in[(size_t)(r0+r)*C + c0 + tc];
    }
    __syncthreads();
    #pragma unroll
    for (int i=0;i<4;i++){
        int ro = tr + i*8;
        out[(size_t)(c0+ro)*R + r0 + tc] = (bf16)t[tc][ro];
    }
}

// ---------------- fused per-batch attention + uplift ----------------
__global__ __launch_bounds__(256,1) void k_attn(
    const float* __restrict__ feat, const float* __restrict__ emb,
    const bf16* __restrict__ wqt, const bf16* __restrict__ wkt,
    const bf16* __restrict__ wvt, const bf16* __restrict__ wa2t,
    const float* __restrict__ qb, const float* __restrict__ kb, const float* __restrict__ vb,
    const float* __restrict__ a2b, const float* __restrict__ a3w,
    const float* __restrict__ sigt_g,
    const float* __restrict__ u1w, const float* __restrict__ u1b,
    const float* __restrict__ u2w, const float* __restrict__ u2b,
    const float* __restrict__ u3w, const float* __restrict__ u3b,
    const float* __restrict__ u4w, const float* __restrict__ u4b,
    const float* __restrict__ tlw, const float* __restrict__ tlb,
    const float* __restrict__ utw, const float* __restrict__ utb,
    bf16* __restrict__ xx, float* __restrict__ outp)
{
    __shared__ bf16 sA[128][HP];     // nx rows 0..111 ; later Vt[h][g]
    __shared__ bf16 sQ[FP][HP];
    __shared__ bf16 sK[FP][HP];
    __shared__ bf16 sP[4][16][HP];   // per-wave scratch (Q-transpose not needed; P + xx staging)
    __shared__ float sNorm[H_], sRn[H_], sFeat[FP], sAtt[FP], sAw[FP], sXt[H_], sSig[H_];
    __shared__ float sU1[128], sU2[64], sU3[32], sU4[16];

    int b = blockIdx.x;
    int tid = threadIdx.x, w = tid>>6, lane = tid&63;
    int l15 = lane&15, l4 = lane>>4;

    if (tid < FP) sFeat[tid] = (tid<F_) ? feat[(size_t)b*F_+tid] : 0.f;
    if (tid < H_) sSig[tid] = sigt_g[tid];
    __syncthreads();

    // norm over feature axis
    if (tid < H_){
        int h=tid; float acc=0.f;
        for(int f=0; f<F_; f++){ float v = sFeat[f]*emb[f*H_+h]; acc += v*v; }
        float nrm = sqrtf(acc);
        sNorm[h]=nrm; sRn[h]=1.f/nrm;
    }
    __syncthreads();

    // nx (zero-padded rows 100..111)
    for (int idx=tid; idx<FP*H_; idx+=256){
        int f=idx>>7, h=idx&127;
        float v = (f<F_) ? sFeat[f]*emb[f*H_+h]*sRn[h] : 0.f;
        sA[f][h] = (bf16)v;
    }
    __syncthreads();

    // ---- projections: Q,K -> LDS ; V -> regs ----
    float vacc[2][8][4];
    for (int proj=0; proj<2; proj++){
        const bf16* wt = proj ? wkt : wqt;
        const float* bias = proj ? kb : qb;
        for (int nt=0; nt<8; nt++){
            bf16x8 bfr[4];
            #pragma unroll
            for(int kc=0;kc<4;kc++)
                bfr[kc] = *(const bf16x8*)(wt + (nt*16+l15)*H_ + kc*32 + l4*8);
            float bcol = bias[nt*16+l15];
            #pragma unroll
            for (int i=0;i<2;i++){
                int mt = w + 4*i;
                if (mt < 7){
                    f32x4 acc = {0.f,0.f,0.f,0.f};
                    #pragma unroll
                    for(int kc=0;kc<4;kc++){
                        bf16x8 af = *(const bf16x8*)(&sA[mt*16+l15][kc*32+l4*8]);
                        acc = mfma16(af, bfr[kc], acc);
                    }
                    if (proj==0){
                        #pragma unroll
                        for(int j=0;j<4;j++) sQ[mt*16 + l4*4 + j][nt*16+l15] = (bf16)(acc[j] + bcol);
                    } else {
                        #pragma unroll
                        for(int j=0;j<4;j++) sK[mt*16 + l4*4 + j][nt*16+l15] = (bf16)(acc[j] + bcol);
                    }
                }
            }
        }
    }
    #pragma unroll
    for (int nt=0; nt<8; nt++){
        bf16x8 bfr[4];
        #pragma unroll
        for(int kc=0;kc<4;kc++)
            bfr[kc] = *(const bf16x8*)(wvt + (nt*16+l15)*H_ + kc*32 + l4*8);
        float bcol = vb[nt*16+l15];
        #pragma unroll
        for (int i=0;i<2;i++){
            int mt = w + 4*i;
            f32x4 acc = {0.f,0.f,0.f,0.f};
            if (mt < 7){
                #pragma unroll
                for(int kc=0;kc<4;kc++){
                    bf16x8 af = *(const bf16x8*)(&sA[mt*16+l15][kc*32+l4*8]);
                    acc = mfma16(af, bfr[kc], acc);
                }
            }
            #pragma unroll
            for(int j=0;j<4;j++) vacc[i][nt][j] = acc[j] + bcol;
        }
    }

    // ---- interaction attention path: att[f] = sum_j relu(sig_t[j] + sig(x_rep@a2w + a2b)) * a3w[j]
    // fold norm into B:  x_rep@a2w = nx @ (norm[h] * a2w[h,:])
    float attp[2][4];
    #pragma unroll
    for(int i=0;i<2;i++){ attp[i][0]=0.f; attp[i][1]=0.f; attp[i][2]=0.f; attp[i][3]=0.f; }
    #pragma unroll 1
    for (int nt=0; nt<8; nt++){
        bf16x8 bfr[4];
        #pragma unroll
        for(int kc=0;kc<4;kc++){
            bf16x8 braw = *(const bf16x8*)(wa2t + (nt*16+l15)*H_ + kc*32 + l4*8);
            bf16x8 bs;
            #pragma unroll
            for(int e=0;e<8;e++) bs[e] = (bf16)((float)braw[e] * sNorm[kc*32 + l4*8 + e]);
            bfr[kc]=bs;
        }
        float a2bc = a2b[nt*16+l15], a3c = a3w[nt*16+l15], sgc = sSig[nt*16+l15];
        #pragma unroll
        for(int i=0;i<2;i++){
            int mt = w + 4*i;
            if (mt < 7){
                f32x4 acc = {0.f,0.f,0.f,0.f};
                #pragma unroll
                for(int kc=0;kc<4;kc++){
                    bf16x8 af = *(const bf16x8*)(&sA[mt*16+l15][kc*32+l4*8]);
                    acc = mfma16(af, bfr[kc], acc);
                }
                #pragma unroll
                for(int j=0;j<4;j++){
                    float u = sigmoidf_(acc[j] + a2bc);
                    float t = sgc + u;
                    t = t>0.f ? t : 0.f;
                    attp[i][j] += t * a3c;
                }
            }
        }
    }
    #pragma unroll
    for(int i=0;i<2;i++)
        #pragma unroll
        for(int j=0;j<4;j++){
            float v = attp[i][j];
            #pragma unroll
            for(int m=1;m<16;m<<=1) v += __shfl_xor(v,m,16);
            attp[i][j]=v;
        }
    if (l15==0){
        #pragma unroll
        for(int i=0;i<2;i++){ int mt=w+4*i; if(mt<7){
            #pragma unroll
            for(int j=0;j<4;j++) sAtt[mt*16 + l4*4 + j] = attp[i][j];
        } }
    }
    __syncthreads();

    // softmax over f (wave 0)
    if (w==0){
        float a0 = (lane<F_)? sAtt[lane] : -1e30f;
        float a1 = (lane+64<F_)? sAtt[lane+64] : -1e30f;
        float m = fmaxf(a0,a1);
        #pragma unroll
        for(int s=1;s<64;s<<=1) m = fmaxf(m, __shfl_xor(m,s,64));
        float e0 = (lane<F_)? __expf(a0-m):0.f;
        float e1 = (lane+64<F_)? __expf(a1-m):0.f;
        float s = e0+e1;
        #pragma unroll
        for(int t=1;t<64;t<<=1) s += __shfl_xor(s,t,64);
        float inv = 1.f/s;
        if (lane<FP) sAw[lane] = e0*inv;
        if (lane+64<FP) sAw[lane+64] = e1*inv;
    }
    __syncthreads();

    // xt = sum_f attn[f] * x_rep[f,h] = norm[h] * sum_f attn[f]*nx[f,h]
    if (tid < H_){
        int h=tid; float acc=0.f;
        for(int f=0;f<F_;f++) acc += sAw[f]*(float)sA[f][h];
        sXt[h] = acc * sNorm[h];
    }
    __syncthreads();
    // uplift tower
    if (tid<128){ int j=tid; float acc=u1b[j]; for(int h=0;h<128;h++) acc += sXt[h]*u1w[h*128+j]; sU1[j]=eluf_(acc); }
    __syncthreads();
    if (tid<64){ int j=tid; float acc=u2b[j]; for(int h=0;h<128;h++) acc += sU1[h]*u2w[h*64+j]; sU2[j]=eluf_(acc); }
    __syncthreads();
    if (tid<32){ int j=tid; float acc=u3b[j]; for(int h=0;h<64;h++) acc += sU2[h]*u3w[h*32+j]; sU3[j]=eluf_(acc); }
    __syncthreads();
    if (tid<16){ int j=tid; float acc=u4b[j]; for(int h=0;h<32;h++) acc += sU3[h]*u4w[h*16+j]; sU4[j]=eluf_(acc); }
    __syncthreads();
    if (tid==0){
        float tl=tlb[0], ut=utb[0];
        for(int i2=0;i2<16;i2++){ tl += sU4[i2]*tlw[i2]; ut += sU4[i2]*utw[i2]; }
        outp[(size_t)3*B_ + b] = tl;
        outp[(size_t)4*B_ + b] = sigmoidf_(tl);
        outp[(size_t)5*B_ + b] = ut;
    }

    // ---- Vt: overwrite sA with V^T (zero padding) ----
    __syncthreads();
    {
        unsigned int* p = (unsigned int*)&sA[0][0];
        for (int idx=tid; idx<128*HP/2; idx+=256) p[idx]=0u;
    }
    __syncthreads();
    union BF4 { uint2 u; bf16 bv[4]; };
    #pragma unroll
    for(int i=0;i<2;i++){
        int mt = w + 4*i;
        if (mt < 7){
            int gb = mt*16 + l4*4;
            if (gb + 3 < F_){
                #pragma unroll
                for(int nt=0;nt<8;nt++){
                    int h = nt*16 + l15;
                    BF4 t;
                    #pragma unroll
                    for(int j=0;j<4;j++) t.bv[j] = (bf16)vacc[i][nt][j];
                    *(uint2*)(&sA[h][gb]) = t.u;
                }
            }
        }
    }
    __syncthreads();

    // ---- scores + sigmoid-softmax + PV ----
    {
        unsigned int* p = (unsigned int*)&sP[w][0][0];
        for (int idx=lane; idx<16*HP/2; idx+=64) p[idx]=0u;
    }
    asm volatile("s_waitcnt lgkmcnt(0)" ::: "memory");

    const float rsc = 0.08838834764831845f; // 1/sqrt(128)
    #pragma unroll 1
    for(int i=0;i<2;i++){
        int mt = w + 4*i;
        if (mt >= 7) continue;
        float ex[7][4];
        float rs[4] = {0.f,0.f,0.f,0.f};
        #pragma unroll
        for(int gt=0; gt<7; gt++){
            f32x4 acc = {0.f,0.f,0.f,0.f};
            #pragma unroll
            for(int kc=0;kc<4;kc++){
                bf16x8 af = *(const bf16x8*)(&sQ[mt*16+l15][kc*32+l4*8]);
                bf16x8 bf_ = *(const bf16x8*)(&sK[gt*16+l15][kc*32+l4*8]);
                acc = mfma16(af,bf_,acc);
            }
            int g = gt*16 + l15;
            #pragma unroll
            for(int j=0;j<4;j++){
                float sg = sigmoidf_(acc[j]*rsc);
                float e = (g<F_) ? __expf(sg) : 0.f;
                ex[gt][j]=e; rs[j]+=e;
            }
        }
        #pragma unroll
        for(int j=0;j<4;j++){
            float v = rs[j];
            #pragma unroll
            for(int m2=1;m2<16;m2<<=1) v += __shfl_xor(v,m2,16);
            rs[j] = 1.f/v;
        }
        #pragma unroll
        for(int gt=0;gt<7;gt++)
            #pragma unroll
            for(int j=0;j<4;j++)
                sP[w][l4*4+j][gt*16+l15] = (bf16)(ex[gt][j]*rs[j]);
        asm volatile("s_waitcnt lgkmcnt(0)" ::: "memory");

        float xa[8][4];
        #pragma unroll
        for(int ht=0;ht<8;ht++){
            f32x4 acc = {0.f,0.f,0.f,0.f};
            #pragma unroll
            for(int kc=0;kc<4;kc++){
                bf16x8 af = *(const bf16x8*)(&sP[w][l15][kc*32+l4*8]);
                bf16x8 bf_ = *(const bf16x8*)(&sA[ht*16+l15][kc*32+l4*8]);
                acc = mfma16(af,bf_,acc);
            }
            #pragma unroll
            for(int j=0;j<4;j++) xa[ht][j]=acc[j];
        }
        asm volatile("s_waitcnt lgkmcnt(0)" ::: "memory");
        #pragma unroll
        for(int ht=0;ht<8;ht++)
            #pragma unroll
            for(int j=0;j<4;j++)
                sP[w][l4*4+j][ht*16+l15] = (bf16)xa[ht][j];
        asm volatile("s_waitcnt lgkmcnt(0)" ::: "memory");
        bf16* dst = xx + (size_t)b*12800 + (size_t)mt*16*128;
        for (int r=0; r<16; r++){
            int f = mt*16 + r;
            if (f < F_){
                unsigned int v = ((const unsigned int*)&sP[w][r][0])[lane];
                ((unsigned int*)(dst + r*128))[lane] = v;
            }
        }
    }
}

// ---------------- generic tiled GEMM: out = act(A @ Bt^T + bias) ----------------
// A [M,K] bf16 ; Bt [N,K] bf16 ; out [M,N] bf16. BM=128.
template<int BN, bool ELU>
__global__ __launch_bounds__(256,2) void k_gemm(const bf16* __restrict__ A, const bf16* __restrict__ Bt,
        const float* __restrict__ bias, bf16* __restrict__ out, int M, int N, int K)
{
    __shared__ bf16 sAt[128][72];
    __shared__ bf16 sBt[BN][72];
    int tid=threadIdx.x, w=tid>>6, lane=tid&63, l15=lane&15, l4=lane>>4;
    int m0 = blockIdx.x*128, n0 = blockIdx.y*BN;
    constexpr int MI = (BN==128)?4:2;
    int wr = (BN==128)? (w>>1) : w;
    int wc = (BN==128)? (w&1) : 0;
    f32x4 acc[MI][4];
    #pragma unroll
    for(int mi=0;mi<MI;mi++)
        #pragma unroll
        for(int ni=0;ni<4;ni++) acc[mi][ni] = (f32x4){0.f,0.f,0.f,0.f};

    for (int k0=0; k0<K; k0+=64){
        __syncthreads();
        for (int t=tid; t<128*8; t+=256){
            int row=t>>3, col=(t&7)*8;
            *(bf16x8*)&sAt[row][col] = *(const bf16x8*)(A + (size_t)(m0+row)*K + k0 + col);
        }
        for (int t=tid; t<BN*8; t+=256){
            int row=t>>3, col=(t&7)*8;
            *(bf16x8*)&sBt[row][col] = *(const bf16x8*)(Bt + (size_t)(n0+row)*K + k0 + col);
        }
        __syncthreads();
        #pragma unroll
        for(int ks=0;ks<2;ks++){
            bf16x8 af[MI], bfr[4];
            #pragma unroll
            for(int mi=0;mi<MI;mi++) af[mi] = *(const bf16x8*)&sAt[wr*(MI*16)+mi*16+l15][ks*32+l4*8];
            #pragma unroll
            for(int ni=0;ni<4;ni++) bfr[ni] = *(const bf16x8*)&sBt[wc*64+ni*16+l15][ks*32+l4*8];
            #pragma unroll
            for(int mi=0;mi<MI;mi++)
                #pragma unroll
                for(int ni=0;ni<4;ni++)
                    acc[mi][ni] = mfma16(af[mi], bfr[ni], acc[mi][ni]);
        }
    }
    #pragma unroll
    for(int mi=0;mi<MI;mi++)
        #pragma unroll
        for(int ni=0;ni<4;ni++){
            int col = n0 + wc*64 + ni*16 + l15;
            float bc = bias[col];
            #pragma unroll
            for(int j=0;j<4;j++){
                int row = m0 + wr*(MI*16) + mi*16 + l4*4 + j;
                float v = acc[mi][ni][j] + bc;
                if (ELU) v = eluf_(v);
                out[(size_t)row*N + col] = (bf16)v;
            }
        }
}

// ---------------- control heads ----------------
__global__ void k_heads(const bf16* __restrict__ c5o, const float* __restrict__ clw, const float* __restrict__ clb,
                        const float* __restrict__ ctw, const float* __restrict__ ctb, float* __restrict__ outp){
    int gid = blockIdx.x*4 + (threadIdx.x>>6);
    int lane = threadIdx.x & 63;
    float v = (float)c5o[(size_t)gid*64 + lane];
    float r1 = v*clw[lane], r2 = v*ctw[lane];
    #pragma unroll
    for(int m=1;m<64;m<<=1){ r1 += __shfl_xor(r1,m,64); r2 += __shfl_xor(r2,m,64); }
    if (lane==0){
        float cl = r1 + clb[0];
        outp[gid] = cl;
        outp[B_ + gid] = sigmoidf_(cl);
        outp[(size_t)2*B_ + gid] = r2 + ctb[0];
    }
}

extern "C" void kernel_launch(void* const* d_in, const int* in_sizes, int n_in,
                              void* d_out, int out_size, void* d_ws, size_t ws_size,
                              hipStream_t stream) {
    const float* feat=(const float*)d_in[0];
    const float* emb =(const float*)d_in[2];
    const float* t_w =(const float*)d_in[3]; const float* t_b=(const float*)d_in[4];
    const float* qw  =(const float*)d_in[5]; const float* qb =(const float*)d_in[6];
    const float* kw  =(const float*)d_in[7]; const float* kb =(const float*)d_in[8];
    const float* vw  =(const float*)d_in[9]; const float* vb =(const float*)d_in[10];
    const float* a1w =(const float*)d_in[11];
    const float* a2w =(const float*)d_in[12]; const float* a2b=(const float*)d_in[13];
    const float* a3w =(const float*)d_in[14];
    const float* c1w =(const float*)d_in[15]; const float* c1b=(const float*)d_in[16];
    const float* c2w =(const float*)d_in[17]; const float* c2b=(const float*)d_in[18];
    const float* c3w =(const float*)d_in[19]; const float* c3b=(const float*)d_in[20];
    const float* c4w =(const float*)d_in[21]; const float* c4b=(const float*)d_in[22];
    const float* c5w =(const float*)d_in[23]; const float* c5b=(const float*)d_in[24];
    const float* clw =(const float*)d_in[25]; const float* clb=(const float*)d_in[26];
    const float* ctw =(const float*)d_in[27]; const float* ctb=(const float*)d_in[28];
    const float* u1w =(const float*)d_in[29]; const float* u1b=(const float*)d_in[30];
    const float* u2w =(const float*)d_in[31]; const float* u2b=(const float*)d_in[32];
    const float* u3w =(const float*)d_in[33]; const float* u3b=(const float*)d_in[34];
    const float* u4w =(const float*)d_in[35]; const float* u4b=(const float*)d_in[36];
    const float* tlw =(const float*)d_in[37]; const float* tlb=(const float*)d_in[38];
    const float* utw =(const float*)d_in[39]; const float* utb=(const float*)d_in[40];
    float* outp = (float*)d_out;

    char* ws = (char*)d_ws;
    size_t off = 0;
    auto alloc = [&](size_t bytes)->char*{ char* p = ws + off; off += (bytes + 255) & ~(size_t)255; return p; };
    bf16* xx    = (bf16*)alloc((size_t)8192*12800*2);
    bf16* cbuf1 = (bf16*)alloc((size_t)8192*512*2);
    bf16* cbuf2 = (bf16*)alloc((size_t)8192*512*2);
    bf16* cbuf3 = (bf16*)alloc((size_t)8192*256*2);
    bf16* cbuf4 = (bf16*)alloc((size_t)8192*128*2);
    bf16* cbuf5 = (bf16*)alloc((size_t)8192*64*2);
    bf16* wqt   = (bf16*)alloc(128*128*2);
    bf16* wkt   = (bf16*)alloc(128*128*2);
    bf16* wvt   = (bf16*)alloc(128*128*2);
    bf16* wa2t  = (bf16*)alloc(128*128*2);
    bf16* c1wt  = (bf16*)alloc((size_t)12800*512*2);
    bf16* c2wt  = (bf16*)alloc((size_t)512*512*2);
    bf16* c3wt  = (bf16*)alloc((size_t)512*256*2);
    bf16* c4wt  = (bf16*)alloc((size_t)256*128*2);
    bf16* c5wt  = (bf16*)alloc((size_t)128*64*2);
    float* sigt = (float*)alloc(128*4);
    (void)ws_size; (void)in_sizes; (void)n_in; (void)out_size;

    k_sigt<<<1,128,0,stream>>>(t_w,t_b,a1w,sigt);
    k_transpose_cvt<<<dim3(4,4),256,0,stream>>>(qw,  wqt, 128,128);
    k_transpose_cvt<<<dim3(4,4),256,0,stream>>>(kw,  wkt, 128,128);
    k_transpose_cvt<<<dim3(4,4),256,0,stream>>>(vw,  wvt, 128,128);
    k_transpose_cvt<<<dim3(4,4),256,0,stream>>>(a2w, wa2t,128,128);
    k_transpose_cvt<<<dim3(16,400),256,0,stream>>>(c1w, c1wt, 12800,512);
    k_transpose_cvt<<<dim3(16,16),256,0,stream>>>(c2w, c2wt, 512,512);
    k_transpose_cvt<<<dim3(8,16),256,0,stream>>>(c3w, c3wt, 512,256);
    k_transpose_cvt<<<dim3(4,8),256,0,stream>>>(c4w, c4wt, 256,128);
    k_transpose_cvt<<<dim3(2,4),256,0,stream>>>(c5w, c5wt, 128,64);

    k_attn<<<8192,256,0,stream>>>(feat,emb,wqt,wkt,wvt,wa2t,qb,kb,vb,a2b,a3w,sigt,
        u1w,u1b,u2w,u2b,u3w,u3b,u4w,u4b,tlw,tlb,utw,utb, xx, outp);

    k_gemm<128,true><<<dim3(64,4),256,0,stream>>>(xx,    c1wt, c1b, cbuf1, 8192,512,12800);
    k_gemm<128,true><<<dim3(64,4),256,0,stream>>>(cbuf1, c2wt, c2b, cbuf2, 8192,512,512);
    k_gemm<128,true><<<dim3(64,2),256,0,stream>>>(cbuf2, c3wt, c3b, cbuf3, 8192,256,512);
    k_gemm<128,true><<<dim3(64,1),256,0,stream>>>(cbuf3, c4wt, c4b, cbuf4, 8192,128,256);
    k_gemm<64, true><<<dim3(64,1),256,0,stream>>>(cbuf4, c5wt, c5b, cbuf5, 8192,64,128);
    k_heads<<<2048,256,0,stream>>>(cbuf5,clw,clb,ctw,ctb,outp);
}

// Round 3
// 1726.372 us; speedup vs baseline: 1.2276x; 1.2276x over previous
//
#include <hip/hip_runtime.h>
#include <hip/hip_bf16.h>

typedef __bf16 bf16;
typedef __bf16 bf16x8 __attribute__((ext_vector_type(8)));
typedef float f32x4 __attribute__((ext_vector_type(4)));

#define DEVI static __device__ __forceinline__

DEVI float sigmoidf_(float x){ return 1.0f/(1.0f+__expf(-x)); }
DEVI float eluf_(float x){ return x>0.f ? x : (__expf(x)-1.f); }
DEVI f32x4 mfma16(bf16x8 a, bf16x8 b, f32x4 c){ return __builtin_amdgcn_mfma_f32_16x16x32_bf16(a,b,c,0,0,0); }
DEVI unsigned pack2_(float a, float b){
    union { bf16 v[2]; unsigned u; } t; t.v[0]=(bf16)a; t.v[1]=(bf16)b; return t.u;
}

#define B_ 8192
#define F_ 100
#define FP 112
#define H_ 128
#define KC_ 12800   // compact kappa-blocked K: 48*256 + 8*64

// ---------------- weight prep ----------------
// MextT [144][128]: rows n<128: rsc*M[h,n]=rsc*sum_d qw[h,d]kw[n,d]; row128: rsc*Wq@kb; row129: rsc*Wk@qb; rows>=130: 0
__global__ void k_prepw(const float* __restrict__ qw, const float* __restrict__ qb,
                        const float* __restrict__ kw, const float* __restrict__ kb,
                        const float* __restrict__ tw, const float* __restrict__ tb,
                        const float* __restrict__ a1w,
                        bf16* __restrict__ mextT, float* __restrict__ sigt, float* __restrict__ cconst){
    const float rsc = 0.08838834764831845f;
    int blk = blockIdx.x, tid = threadIdx.x;
    if (blk < 9){
        #pragma unroll 1
        for (int e=0; e<8; ++e){
            int idx = e*256 + tid;
            int n = blk*16 + (idx>>7), h = idx&127;
            float acc = 0.f;
            if (n < 128){
                for (int d=0; d<128; ++d) acc += qw[h*128+d]*kw[n*128+d];
            } else if (n == 128){
                for (int d=0; d<128; ++d) acc += qw[h*128+d]*kb[d];
            } else if (n == 129){
                for (int d=0; d<128; ++d) acc += kw[h*128+d]*qb[d];
            }
            mextT[n*128+h] = (bf16)(acc*rsc);
        }
    } else {
        if (tid < 128){
            float acc = 0.f;
            for (int h=0; h<128; ++h) acc += (tw[h]+tb[h]) * a1w[h*128+tid];
            sigt[tid] = sigmoidf_(acc);
        } else if (tid == 128){
            float acc = 0.f;
            for (int d=0; d<128; ++d) acc += qb[d]*kb[d];
            cconst[0] = acc*rsc;
        }
    }
}

// in [R][C] f32 -> out [C][R] bf16
__global__ void k_transpose_cvt(const float* __restrict__ in, bf16* __restrict__ out, int R, int C){
    __shared__ float t[32][33];
    int c0 = blockIdx.x*32, r0 = blockIdx.y*32;
    int tc = threadIdx.x & 31, tr = threadIdx.x >> 5;
    #pragma unroll
    for (int i=0;i<4;i++){
        int r = tr + i*8;
        t[r][tc] = in[(size_t)(r0+r)*C + c0 + tc];
    }
    __syncthreads();
    #pragma unroll
    for (int i=0;i<4;i++){
        int ro = tr + i*8;
        out[(size_t)(c0+ro)*R + r0 + tc] = (bf16)t[tc][ro];
    }
}

// compact kappa: bijection on [0,12800)
DEVI int kappa_(int k){
    int f = k>>7, h = k&127;
    if (f < 96)
        return (((f>>4)<<3) | (h>>4))*256 + (h&15)*16 + (f&15);
    else
        return 12288 + (h>>4)*64 + (h&15)*4 + (f&3);
}
// c1w [12800][512] f32 -> c1wtk [512][12800] bf16, kappa-permuted K
__global__ void k_tc_kappa(const float* __restrict__ in, bf16* __restrict__ out){
    __shared__ float t[32][33];
    const int C = 512;
    int c0 = blockIdx.x*32, r0 = blockIdx.y*32;
    int tc = threadIdx.x & 31, tr = threadIdx.x >> 5;
    #pragma unroll
    for (int i=0;i<4;i++){
        int r = tr + i*8;
        t[r][tc] = in[(size_t)(r0+r)*C + c0 + tc];
    }
    __syncthreads();
    #pragma unroll
    for (int i=0;i<4;i++){
        int ro = tr + i*8;
        out[(size_t)(c0+ro)*KC_ + kappa_(r0+tc)] = (bf16)t[tc][ro];
    }
}

// ---------------- fused per-batch attention (one block per batch) ----------------
__global__ __launch_bounds__(256,3) void k_attn2(
    const float* __restrict__ feat, const float* __restrict__ emb,
    const bf16* __restrict__ mextT, const bf16* __restrict__ wa2t,
    const bf16* __restrict__ wvT, const float* __restrict__ vb,
    const float* __restrict__ a2b, const float* __restrict__ a3w,
    const float* __restrict__ sigt_g, const float* __restrict__ cconst,
    bf16* __restrict__ xx, bf16* __restrict__ xtb)
{
    __shared__ char arena[30720];     // sNx [112][136] bf16 (30464B)  UNION  sVT [128][120] bf16 (30720B)
    __shared__ bf16 sP[4][16][136];   // per-wave S1/P staging
    __shared__ float sFeat[112], sNorm[128], sRn[128];
    __shared__ float sAlpha[112], sBeta[112], sAtt[112], sAw[112];
    bf16 (*sNx)[136] = (bf16(*)[136])arena;
    bf16 (*sVT)[120] = (bf16(*)[120])arena;

    int b = blockIdx.x;
    int tid = threadIdx.x, w = tid>>6, lane = tid&63;
    int l15 = lane&15, l4 = lane>>4;

    if (tid < 112) sFeat[tid] = (tid<F_) ? feat[(size_t)b*F_+tid] : 0.f;
    {   // zero sP
        unsigned* p = (unsigned*)&sP[0][0][0];
        #pragma unroll
        for (int i=0;i<17;i++) p[tid + i*256] = 0u;
    }
    __syncthreads();

    // norm over feature axis
    if (tid < 128){
        int h=tid; float acc=0.f;
        #pragma unroll 4
        for(int f=0; f<F_; f++){ float v = sFeat[f]*emb[f*H_+h]; acc += v*v; }
        float nrm = sqrtf(acc);
        sNorm[h]=nrm; sRn[h]=1.f/nrm;
    }
    __syncthreads();

    // nx rows 0..111 (zero pad f>=100)
    for (int idx=tid; idx<FP*H_; idx+=256){
        int f=idx>>7, h=idx&127;
        float v = (f<F_) ? sFeat[f]*emb[f*H_+h]*sRn[h] : 0.f;
        sNx[f][h] = (bf16)v;
    }
    __syncthreads();

    int mt0 = w, mt1 = w+4;   // wave's two f-tiles (mt1==7 inactive)

    // ---- att path: A = x_rep = nx*norm ----
    bf16x8 axf[2][4];
    #pragma unroll
    for (int i=0;i<2;i++){
        int mt = i? mt1 : mt0;
        if (mt<7){
            #pragma unroll
            for (int kc=0;kc<4;kc++){
                bf16x8 raw = *(const bf16x8*)(&sNx[mt*16+l15][kc*32+l4*8]);
                bf16x8 s;
                #pragma unroll
                for (int e=0;e<8;e++) s[e] = (bf16)((float)raw[e] * sNorm[kc*32+l4*8+e]);
                axf[i][kc]=s;
            }
        }
    }
    float attp[2][4] = {{0,0,0,0},{0,0,0,0}};
    #pragma unroll 1
    for (int nt=0; nt<8; nt++){
        bf16x8 bfr[4];
        #pragma unroll
        for(int kc=0;kc<4;kc++)
            bfr[kc] = *(const bf16x8*)(wa2t + (nt*16+l15)*H_ + kc*32 + l4*8);
        float a2bc = a2b[nt*16+l15], a3c = a3w[nt*16+l15], sgc = sigt_g[nt*16+l15];
        #pragma unroll
        for(int i=0;i<2;i++){
            int mt = i? mt1 : mt0;
            if (mt < 7){
                f32x4 acc = {0.f,0.f,0.f,0.f};
                #pragma unroll
                for(int kc=0;kc<4;kc++) acc = mfma16(axf[i][kc], bfr[kc], acc);
                #pragma unroll
                for(int j=0;j<4;j++){
                    float u = sigmoidf_(acc[j] + a2bc);
                    float t = sgc + u;
                    t = t>0.f ? t : 0.f;
                    attp[i][j] += t * a3c;
                }
            }
        }
    }
    #pragma unroll
    for(int i=0;i<2;i++)
        #pragma unroll
        for(int j=0;j<4;j++){
            float v = attp[i][j];
            #pragma unroll
            for(int m=1;m<16;m<<=1) v += __shfl_xor(v,m,16);
            attp[i][j]=v;
        }
    if (l15==0){
        #pragma unroll
        for(int i=0;i<2;i++){ int mt = i? mt1 : mt0; if(mt<7){
            #pragma unroll
            for(int j=0;j<4;j++) sAtt[mt*16 + l4*4 + j] = attp[i][j];
        } }
    }
    __syncthreads();

    // softmax over f (wave 0)
    if (w==0){
        float a0 = (lane<F_)? sAtt[lane] : -1e30f;
        float a1 = (lane+64<F_)? sAtt[lane+64] : -1e30f;
        float m = fmaxf(a0,a1);
        #pragma unroll
        for(int s=1;s<64;s<<=1) m = fmaxf(m, __shfl_xor(m,s,64));
        float e0 = (lane<F_)? __expf(a0-m):0.f;
        float e1 = (lane+64<F_)? __expf(a1-m):0.f;
        float s = e0+e1;
        #pragma unroll
        for(int t=1;t<64;t<<=1) s += __shfl_xor(s,t,64);
        float inv = 1.f/s;
        if (lane<FP) sAw[lane] = e0*inv;
        if (lane+64<FP) sAw[lane+64] = e1*inv;
    }
    __syncthreads();

    // ---- alpha/beta via Mext rows 128/129 (A = raw nx) ----
    bf16x8 afx[2][4];
    #pragma unroll
    for (int i=0;i<2;i++){
        int mt = i? mt1 : mt0;
        if (mt<7){
            #pragma unroll
            for (int kc=0;kc<4;kc++)
                afx[i][kc] = *(const bf16x8*)(&sNx[mt*16+l15][kc*32+l4*8]);
        }
    }
    {
        bf16x8 bfr8[4];
        #pragma unroll
        for (int kc=0;kc<4;kc++)
            bfr8[kc] = *(const bf16x8*)(mextT + (128+l15)*H_ + kc*32 + l4*8);
        #pragma unroll
        for (int i=0;i<2;i++){
            int mt = i? mt1 : mt0;
            if (mt<7){
                f32x4 acc = {0.f,0.f,0.f,0.f};
                #pragma unroll
                for (int kc=0;kc<4;kc++) acc = mfma16(afx[i][kc], bfr8[kc], acc);
                if (l15==0){
                    #pragma unroll
                    for (int j=0;j<4;j++) sAlpha[mt*16+l4*4+j] = acc[j];
                }
                if (l15==1){
                    #pragma unroll
                    for (int j=0;j<4;j++) sBeta[mt*16+l4*4+j] = acc[j];
                }
            }
        }
    }
    __syncthreads();

    // xt (tid<128): xt[h] = norm[h]*sum_f aw[f]*nx[f,h]
    if (tid < 128){
        int h=tid; float acc=0.f;
        #pragma unroll 4
        for(int f=0;f<F_;f++) acc += sAw[f]*(float)sNx[f][h];
        xtb[(size_t)b*H_ + h] = (bf16)(acc * sNorm[h]);
    }

    // ---- scores: S1 = nx@Mext (staged), P = exp(sig(scores))/rowsum ----
    const float cc = cconst[0];
    float ex[2][7][4];
    float inv_[2][4];
    #pragma unroll 1
    for (int i=0;i<2;i++){
        int mt = i? mt1 : mt0;
        if (mt >= 7) continue;
        // stage S1 tile for this mt
        #pragma unroll 1
        for (int nt=0; nt<8; nt++){
            bf16x8 bfr[4];
            #pragma unroll
            for (int kc=0;kc<4;kc++)
                bfr[kc] = *(const bf16x8*)(mextT + (nt*16+l15)*H_ + kc*32 + l4*8);
            f32x4 acc = {0.f,0.f,0.f,0.f};
            #pragma unroll
            for (int kc=0;kc<4;kc++) acc = mfma16(afx[i][kc], bfr[kc], acc);
            #pragma unroll
            for (int j=0;j<4;j++) sP[w][l4*4+j][nt*16+l15] = (bf16)acc[j];
        }
        bf16x8 afs[4];
        #pragma unroll
        for (int kc=0;kc<4;kc++)
            afs[kc] = *(const bf16x8*)(&sP[w][l15][kc*32+l4*8]);
        float aj[4];
        #pragma unroll
        for (int j=0;j<4;j++) aj[j] = sAlpha[mt*16+l4*4+j];
        float rs[4] = {0.f,0.f,0.f,0.f};
        #pragma unroll
        for (int gt=0; gt<7; gt++){
            f32x4 acc = {0.f,0.f,0.f,0.f};
            #pragma unroll
            for (int kc=0;kc<4;kc++){
                bf16x8 bfr = *(const bf16x8*)(&sNx[gt*16+l15][kc*32+l4*8]);
                acc = mfma16(afs[kc], bfr, acc);
            }
            float bg = sBeta[gt*16+l15];
            int g = gt*16+l15;
            #pragma unroll
            for (int j=0;j<4;j++){
                float val = acc[j] + aj[j] + bg + cc;
                float e = (g<F_) ? __expf(sigmoidf_(val)) : 0.f;
                ex[i][gt][j]=e; rs[j]+=e;
            }
        }
        #pragma unroll
        for (int j=0;j<4;j++){
            float v = rs[j];
            #pragma unroll
            for (int m2=1;m2<16;m2<<=1) v += __shfl_xor(v,m2,16);
            inv_[i][j] = 1.f/v;
        }
    }
    // stage P0; keep P1 in regs
    if (mt0 < 7){
        #pragma unroll
        for (int gt=0; gt<7; gt++)
            #pragma unroll
            for (int j=0;j<4;j++)
                sP[w][l4*4+j][gt*16+l15] = (bf16)(ex[0][gt][j]*inv_[0][j]);
        #pragma unroll
        for (int j=0;j<4;j++) sP[w][l4*4+j][112+l15] = (bf16)0.f;   // zero pad cols 112..127
    }

    // ---- V^T = wvT x nx  (into regs; nx still live) ----
    f32x4 vacc[2][7];
    #pragma unroll 1
    for (int i2=0;i2<2;i2++){
        int ht = w + 4*i2;
        bf16x8 awv[4];
        #pragma unroll
        for (int kc=0;kc<4;kc++)
            awv[kc] = *(const bf16x8*)(wvT + (ht*16+l15)*H_ + kc*32 + l4*8);
        #pragma unroll
        for (int gt=0; gt<7; gt++){
            f32x4 acc = {0.f,0.f,0.f,0.f};
            #pragma unroll
            for (int kc=0;kc<4;kc++){
                bf16x8 bfr = *(const bf16x8*)(&sNx[gt*16+l15][kc*32+l4*8]);
                acc = mfma16(awv[kc], bfr, acc);
            }
            vacc[i2][gt] = acc;
        }
    }
    __syncthreads();   // all sNx reads complete (incl. xt)

    // write V^T (+vb) over the nx region; zero pad cols 112..119
    #pragma unroll
    for (int i2=0;i2<2;i2++){
        int ht = w + 4*i2;
        float vbj[4];
        #pragma unroll
        for (int j=0;j<4;j++) vbj[j] = vb[ht*16+l4*4+j];
        #pragma unroll
        for (int gt=0; gt<7; gt++)
            #pragma unroll
            for (int j=0;j<4;j++)
                sVT[ht*16+l4*4+j][gt*16+l15] = (bf16)(vacc[i2][gt][j] + vbj[j]);
        if (l15 < 8){
            #pragma unroll
            for (int j=0;j<4;j++) sVT[ht*16+l4*4+j][112+l15] = (bf16)0.f;
        }
    }
    __syncthreads();

    // ---- PV: ctx = P @ V, store compact-kappa ----
    #pragma unroll 1
    for (int i=0;i<2;i++){
        int mt = i? mt1 : mt0;
        if (mt >= 7) continue;
        if (i==1){
            // stage P1 now (after i0's ap reads)
            #pragma unroll
            for (int gt=0; gt<7; gt++)
                #pragma unroll
                for (int j=0;j<4;j++)
                    sP[w][l4*4+j][gt*16+l15] = (bf16)(ex[1][gt][j]*inv_[1][j]);
            #pragma unroll
            for (int j=0;j<4;j++) sP[w][l4*4+j][112+l15] = (bf16)0.f;
        }
        bf16x8 ap[4];
        #pragma unroll
        for (int kc=0;kc<4;kc++)
            ap[kc] = *(const bf16x8*)(&sP[w][l15][kc*32+l4*8]);
        #pragma unroll 1
        for (int ht=0; ht<8; ht++){
            f32x4 acc = {0.f,0.f,0.f,0.f};
            #pragma unroll
            for (int kc=0;kc<4;kc++){
                int co = kc*32 + l4*8;
                if (co == 120) co = 112;   // clamp: stay in-row; P is zero for k>=112 so result unchanged
                bf16x8 bv = *(const bf16x8*)(&sVT[ht*16+l15][co]);
                acc = mfma16(ap[kc], bv, acc);
            }
            if (mt < 6){
                uint2 u; u.x = pack2_(acc[0],acc[1]); u.y = pack2_(acc[2],acc[3]);
                *(uint2*)(xx + (size_t)b*KC_ + (mt*8+ht)*256 + l15*16 + l4*4) = u;
            } else if (l4 == 0){
                // f = 96..99 -> quarter tile at 12288 + ht*64
                uint2 u; u.x = pack2_(acc[0],acc[1]); u.y = pack2_(acc[2],acc[3]);
                *(uint2*)(xx + (size_t)b*KC_ + 12288 + ht*64 + l15*4) = u;
            }
        }
    }
}

// ---------------- generic tiled GEMM: out = act(A @ Bt^T + bias) ----------------
template<int BN, bool ELU>
__global__ __launch_bounds__(256,2) void k_gemm(const bf16* __restrict__ A, const bf16* __restrict__ Bt,
        const float* __restrict__ bias, bf16* __restrict__ out, int M, int N, int K)
{
    __shared__ bf16 sAt[128][72];
    __shared__ bf16 sBt[BN][72];
    int tid=threadIdx.x, w=tid>>6, lane=tid&63, l15=lane&15, l4=lane>>4;
    int m0 = blockIdx.x*128, n0 = blockIdx.y*BN;
    constexpr int MI = (BN==128)?4:2;
    constexpr int NI = (BN==128)?4:BN/16;
    int wr = (BN==128)? (w>>1) : w;
    int wc = (BN==128)? (w&1) : 0;
    f32x4 acc[MI][NI];
    #pragma unroll
    for(int mi=0;mi<MI;mi++)
        #pragma unroll
        for(int ni=0;ni<NI;ni++) acc[mi][ni] = (f32x4){0.f,0.f,0.f,0.f};

    for (int k0=0; k0<K; k0+=64){
        __syncthreads();
        for (int t=tid; t<128*8; t+=256){
            int row=t>>3, col=(t&7)*8;
            *(bf16x8*)&sAt[row][col] = *(const bf16x8*)(A + (size_t)(m0+row)*K + k0 + col);
        }
        for (int t=tid; t<BN*8; t+=256){
            int row=t>>3, col=(t&7)*8;
            *(bf16x8*)&sBt[row][col] = *(const bf16x8*)(Bt + (size_t)(n0+row)*K + k0 + col);
        }
        __syncthreads();
        #pragma unroll
        for(int ks=0;ks<2;ks++){
            bf16x8 af[MI], bfr[NI];
            #pragma unroll
            for(int mi=0;mi<MI;mi++) af[mi] = *(const bf16x8*)&sAt[wr*(MI*16)+mi*16+l15][ks*32+l4*8];
            #pragma unroll
            for(int ni=0;ni<NI;ni++) bfr[ni] = *(const bf16x8*)&sBt[wc*64+ni*16+l15][ks*32+l4*8];
            #pragma unroll
            for(int mi=0;mi<MI;mi++)
                #pragma unroll
                for(int ni=0;ni<NI;ni++)
                    acc[mi][ni] = mfma16(af[mi], bfr[ni], acc[mi][ni]);
        }
    }
    #pragma unroll
    for(int mi=0;mi<MI;mi++)
        #pragma unroll
        for(int ni=0;ni<NI;ni++){
            int col = n0 + wc*64 + ni*16 + l15;
            float bc = bias[col];
            #pragma unroll
            for(int j=0;j<4;j++){
                int row = m0 + wr*(MI*16) + mi*16 + l4*4 + j;
                float v = acc[mi][ni][j] + bc;
                if (ELU) v = eluf_(v);
                out[(size_t)row*N + col] = (bf16)v;
            }
        }
}

// ---------------- control heads ----------------
__global__ void k_heads(const bf16* __restrict__ c5o, const float* __restrict__ clw, const float* __restrict__ clb,
                        const float* __restrict__ ctw, const float* __restrict__ ctb, float* __restrict__ outp){
    int gid = blockIdx.x*4 + (threadIdx.x>>6);
    int lane = threadIdx.x & 63;
    float v = (float)c5o[(size_t)gid*64 + lane];
    float r1 = v*clw[lane], r2 = v*ctw[lane];
    #pragma unroll
    for(int m=1;m<64;m<<=1){ r1 += __shfl_xor(r1,m,64); r2 += __shfl_xor(r2,m,64); }
    if (lane==0){
        float cl = r1 + clb[0];
        outp[gid] = cl;
        outp[B_ + gid] = sigmoidf_(cl);
        outp[(size_t)2*B_ + gid] = r2 + ctb[0];
    }
}

// ---------------- uplift tail: u4 (K=32 -> 16) + heads ----------------
__global__ void k_utail(const bf16* __restrict__ u3o, const float* __restrict__ u4w, const float* __restrict__ u4b,
                        const float* __restrict__ tlw, const float* __restrict__ tlb,
                        const float* __restrict__ utw, const float* __restrict__ utb, float* __restrict__ outp){
    int row = blockIdx.x*4 + (threadIdx.x>>6);
    int lane = threadIdx.x & 63;
    int j = lane & 15;
    float acc = u4b[j];
    #pragma unroll 4
    for (int h=0; h<32; ++h) acc += (float)u3o[(size_t)row*32+h] * u4w[h*16+j];
    float u4 = eluf_(acc);
    float r1 = u4*tlw[j], r2 = u4*utw[j];
    #pragma unroll
    for(int m=1;m<16;m<<=1){ r1 += __shfl_xor(r1,m,16); r2 += __shfl_xor(r2,m,16); }
    if (lane==0){
        float tl = r1 + tlb[0];
        outp[(size_t)3*B_ + row] = tl;
        outp[(size_t)4*B_ + row] = sigmoidf_(tl);
        outp[(size_t)5*B_ + row] = r2 + utb[0];
    }
}

extern "C" void kernel_launch(void* const* d_in, const int* in_sizes, int n_in,
                              void* d_out, int out_size, void* d_ws, size_t ws_size,
                              hipStream_t stream) {
    const float* feat=(const float*)d_in[0];
    const float* emb =(const float*)d_in[2];
    const float* t_w =(const float*)d_in[3]; const float* t_b=(const float*)d_in[4];
    const float* qw  =(const float*)d_in[5]; const float* qb =(const float*)d_in[6];
    const float* kw  =(const float*)d_in[7]; const float* kb =(const float*)d_in[8];
    const float* vw  =(const float*)d_in[9]; const float* vb =(const float*)d_in[10];
    const float* a1w =(const float*)d_in[11];
    const float* a2w =(const float*)d_in[12]; const float* a2b=(const float*)d_in[13];
    const float* a3w =(const float*)d_in[14];
    const float* c1w =(const float*)d_in[15]; const float* c1b=(const float*)d_in[16];
    const float* c2w =(const float*)d_in[17]; const float* c2b=(const float*)d_in[18];
    const float* c3w =(const float*)d_in[19]; const float* c3b=(const float*)d_in[20];
    const float* c4w =(const float*)d_in[21]; const float* c4b=(const float*)d_in[22];
    const float* c5w =(const float*)d_in[23]; const float* c5b=(const float*)d_in[24];
    const float* clw =(const float*)d_in[25]; const float* clb=(const float*)d_in[26];
    const float* ctw =(const float*)d_in[27]; const float* ctb=(const float*)d_in[28];
    const float* u1w =(const float*)d_in[29]; const float* u1b=(const float*)d_in[30];
    const float* u2w =(const float*)d_in[31]; const float* u2b=(const float*)d_in[32];
    const float* u3w =(const float*)d_in[33]; const float* u3b=(const float*)d_in[34];
    const float* u4w =(const float*)d_in[35]; const float* u4b=(const float*)d_in[36];
    const float* tlw =(const float*)d_in[37]; const float* tlb=(const float*)d_in[38];
    const float* utw =(const float*)d_in[39]; const float* utb=(const float*)d_in[40];
    float* outp = (float*)d_out;

    char* ws = (char*)d_ws;
    size_t off = 0;
    auto alloc = [&](size_t bytes)->char*{ char* p = ws + off; off += (bytes + 255) & ~(size_t)255; return p; };
    bf16* xx    = (bf16*)alloc((size_t)B_*KC_*2);      // 209.7 MB; region reused below after c1 GEMM
    bf16* xtb   = (bf16*)alloc((size_t)B_*128*2);
    bf16* cbuf1 = (bf16*)alloc((size_t)B_*512*2);
    bf16* mextT = (bf16*)alloc(144*128*2);
    bf16* wvT   = (bf16*)alloc(128*128*2);
    bf16* wa2t  = (bf16*)alloc(128*128*2);
    bf16* c1wtk = (bf16*)alloc((size_t)512*KC_*2);
    bf16* c2wt  = (bf16*)alloc((size_t)512*512*2);
    bf16* c3wt  = (bf16*)alloc((size_t)512*256*2);
    bf16* c4wt  = (bf16*)alloc((size_t)256*128*2);
    bf16* c5wt  = (bf16*)alloc((size_t)128*64*2);
    bf16* u1t   = (bf16*)alloc(128*128*2);
    bf16* u2t   = (bf16*)alloc(64*128*2);
    bf16* u3t   = (bf16*)alloc(32*64*2);
    float* sigt = (float*)alloc(128*4);
    float* cconst = (float*)alloc(4);
    // aliases into the xx region (xx is dead after the c1 GEMM; stream is sequential)
    bf16* cbuf2 = xx;
    bf16* cbuf3 = xx +  8388608;
    bf16* cbuf4 = xx + 16777216;
    bf16* cbuf5 = xx + 25165824;
    bf16* ubuf1 = xx + 33554432;
    bf16* ubuf2 = xx + 41943040;
    bf16* ubuf3 = xx + 50331648;
    (void)ws_size; (void)in_sizes; (void)n_in; (void)out_size;

    k_prepw<<<10,256,0,stream>>>(qw,qb,kw,kb,t_w,t_b,a1w,mextT,sigt,cconst);
    k_transpose_cvt<<<dim3(4,4),256,0,stream>>>(vw,  wvT, 128,128);
    k_transpose_cvt<<<dim3(4,4),256,0,stream>>>(a2w, wa2t,128,128);
    k_tc_kappa<<<dim3(16,400),256,0,stream>>>(c1w, c1wtk);
    k_transpose_cvt<<<dim3(16,16),256,0,stream>>>(c2w, c2wt, 512,512);
    k_transpose_cvt<<<dim3(8,16),256,0,stream>>>(c3w, c3wt, 512,256);
    k_transpose_cvt<<<dim3(4,8),256,0,stream>>>(c4w, c4wt, 256,128);
    k_transpose_cvt<<<dim3(2,4),256,0,stream>>>(c5w, c5wt, 128,64);
    k_transpose_cvt<<<dim3(4,4),256,0,stream>>>(u1w, u1t, 128,128);
    k_transpose_cvt<<<dim3(2,4),256,0,stream>>>(u2w, u2t, 128,64);
    k_transpose_cvt<<<dim3(1,2),256,0,stream>>>(u3w, u3t, 64,32);

    k_attn2<<<B_,256,0,stream>>>(feat,emb,mextT,wa2t,wvT,vb,a2b,a3w,sigt,cconst, xx, xtb);

    k_gemm<128,true><<<dim3(64,4),256,0,stream>>>(xx,    c1wtk, c1b, cbuf1, B_,512,KC_);
    k_gemm<128,true><<<dim3(64,4),256,0,stream>>>(cbuf1, c2wt, c2b, cbuf2, B_,512,512);
    k_gemm<128,true><<<dim3(64,2),256,0,stream>>>(cbuf2, c3wt, c3b, cbuf3, B_,256,512);
    k_gemm<128,true><<<dim3(64,1),256,0,stream>>>(cbuf3, c4wt, c4b, cbuf4, B_,128,256);
    k_gemm<64, true><<<dim3(64,1),256,0,stream>>>(cbuf4, c5wt, c5b, cbuf5, B_,64,128);
    k_heads<<<2048,256,0,stream>>>(cbuf5,clw,clb,ctw,ctb,outp);

    k_gemm<128,true><<<dim3(64,1),256,0,stream>>>(xtb,   u1t, u1b, ubuf1, B_,128,128);
    k_gemm<64, true><<<dim3(64,1),256,0,stream>>>(ubuf1, u2t, u2b, ubuf2, B_,64,128);
    k_gemm<32, true><<<dim3(64,1),256,0,stream>>>(ubuf2, u3t, u3b, ubuf3, B_,32,64);
    k_utail<<<2048,256,0,stream>>>(ubuf3,u4w,u4b,tlw,tlb,utw,utb,outp);
}

// Round 5
// 1703.580 us; speedup vs baseline: 1.2441x; 1.0134x over previous
//
#include <hip/hip_runtime.h>
#include <hip/hip_bf16.h>

typedef __bf16 bf16;
typedef __bf16 bf16x8 __attribute__((ext_vector_type(8)));
typedef __bf16 bf16x4 __attribute__((ext_vector_type(4)));
typedef float f32x4 __attribute__((ext_vector_type(4)));

#define DEVI static __device__ __forceinline__

DEVI float sigmoidf_(float x){ return 1.0f/(1.0f+__expf(-x)); }
DEVI float eluf_(float x){ return x>0.f ? x : (__expf(x)-1.f); }
DEVI f32x4 mfma16(bf16x8 a, bf16x8 b, f32x4 c){ return __builtin_amdgcn_mfma_f32_16x16x32_bf16(a,b,c,0,0,0); }
DEVI unsigned pack2_(float a, float b){
    union { bf16 v[2]; unsigned u; } t; t.v[0]=(bf16)a; t.v[1]=(bf16)b; return t.u;
}
DEVI unsigned long long pack4_(float a, float b, float c, float d){
    union { bf16 v[4]; unsigned long long u; } t;
    t.v[0]=(bf16)a; t.v[1]=(bf16)b; t.v[2]=(bf16)c; t.v[3]=(bf16)d; return t.u;
}
DEVI bf16x8 ldb64x2(const bf16* p0, const bf16* p1){
    union { bf16x8 v8; bf16x4 v4[2]; } u;
    u.v4[0] = *(const bf16x4*)p0;
    u.v4[1] = *(const bf16x4*)p1;
    return u.v8;
}

#define B_ 8192
#define F_ 100
#define FP 112
#define H_ 128
#define KC_ 12800   // compact kappa-blocked K: 48*256 + 8*64

// ---------------- weight prep ----------------
__global__ void k_prepw(const float* __restrict__ qw, const float* __restrict__ qb,
                        const float* __restrict__ kw, const float* __restrict__ kb,
                        const float* __restrict__ tw, const float* __restrict__ tb,
                        const float* __restrict__ a1w,
                        bf16* __restrict__ mextT, float* __restrict__ sigt, float* __restrict__ cconst){
    const float rsc = 0.08838834764831845f;
    int blk = blockIdx.x, tid = threadIdx.x;
    if (blk < 9){
        #pragma unroll 1
        for (int e=0; e<8; ++e){
            int idx = e*256 + tid;
            int n = blk*16 + (idx>>7), h = idx&127;
            float acc = 0.f;
            if (n < 128){
                for (int d=0; d<128; ++d) acc += qw[h*128+d]*kw[n*128+d];
            } else if (n == 128){
                for (int d=0; d<128; ++d) acc += qw[h*128+d]*kb[d];
            } else if (n == 129){
                for (int d=0; d<128; ++d) acc += kw[h*128+d]*qb[d];
            }
            mextT[n*128+h] = (bf16)(acc*rsc);
        }
    } else {
        if (tid < 128){
            float acc = 0.f;
            for (int h=0; h<128; ++h) acc += (tw[h]+tb[h]) * a1w[h*128+tid];
            sigt[tid] = sigmoidf_(acc);
        } else if (tid == 128){
            float acc = 0.f;
            for (int d=0; d<128; ++d) acc += qb[d]*kb[d];
            cconst[0] = acc*rsc;
        }
    }
}

// in [R][C] f32 -> out [C][R] bf16
__global__ void k_transpose_cvt(const float* __restrict__ in, bf16* __restrict__ out, int R, int C){
    __shared__ float t[32][33];
    int c0 = blockIdx.x*32, r0 = blockIdx.y*32;
    int tc = threadIdx.x & 31, tr = threadIdx.x >> 5;
    #pragma unroll
    for (int i=0;i<4;i++){
        int r = tr + i*8;
        t[r][tc] = in[(size_t)(r0+r)*C + c0 + tc];
    }
    __syncthreads();
    #pragma unroll
    for (int i=0;i<4;i++){
        int ro = tr + i*8;
        out[(size_t)(c0+ro)*R + r0 + tc] = (bf16)t[tc][ro];
    }
}

// compact kappa: bijection on [0,12800). In-tile layout is LANE-LINEAR for the
// k_attn2 PV store: lane = l4*16+l15, f-in-tile = l4*4+j, h-in-tile = l15
//   -> idx = ((f&15)>>2)*64 + (h&15)*4 + (f&3) = 4*lane + j
DEVI int kappa_(int k){
    int f = k>>7, h = k&127;
    if (f < 96)
        return (((f>>4)<<3) | (h>>4))*256 + ((f&15)>>2)*64 + (h&15)*4 + (f&3);
    else
        return 12288 + (h>>4)*64 + (h&15)*4 + (f&3);
}
// c1w [12800][512] f32 -> c1wtk [512][12800] bf16, kappa-permuted K
__global__ void k_tc_kappa(const float* __restrict__ in, bf16* __restrict__ out){
    __shared__ float t[32][33];
    const int C = 512;
    int c0 = blockIdx.x*32, r0 = blockIdx.y*32;
    int tc = threadIdx.x & 31, tr = threadIdx.x >> 5;
    #pragma unroll
    for (int i=0;i<4;i++){
        int r = tr + i*8;
        t[r][tc] = in[(size_t)(r0+r)*C + c0 + tc];
    }
    __syncthreads();
    #pragma unroll
    for (int i=0;i<4;i++){
        int ro = tr + i*8;
        out[(size_t)(c0+ro)*KC_ + kappa_(r0+tc)] = (bf16)t[tc][ro];
    }
}

// ---------------- fused per-batch attention (one block per batch, 4 blocks/CU) ----------------
__global__ __launch_bounds__(256,4) void k_attn2(
    const float* __restrict__ feat, const float* __restrict__ emb,
    const bf16* __restrict__ mextT, const bf16* __restrict__ wa2t,
    const bf16* __restrict__ wvT, const float* __restrict__ vb,
    const float* __restrict__ a2b, const float* __restrict__ a3w,
    const float* __restrict__ sigt_g, const float* __restrict__ cconst,
    bf16* __restrict__ xx, bf16* __restrict__ xtb)
{
    // Manual arena, 40576 B -> 4 blocks/CU.
    //   [0,30464)      sNx[112][136] bf16   UNION (later) sVT[128][116] bf16 (29696)
    //   [30464,39680)  sP[4][16][72] bf16   UNION (earlier) sFeat/sNorm/sAtt/sAw f32
    //   [39680,40576)  sAlpha f32[112], sBeta f32[112]
    __shared__ char L[40576];
    bf16 (*sNx)[136] = (bf16(*)[136])L;
    bf16 (*sVT)[116] = (bf16(*)[116])L;
    float* sFeat  = (float*)(L+30464);
    float* sNorm  = (float*)(L+30912);
    float* sAtt   = (float*)(L+31424);
    float* sAw    = (float*)(L+31872);
    float* sAlpha = (float*)(L+39680);
    float* sBeta  = (float*)(L+40128);

    int b = blockIdx.x;
    int tid = threadIdx.x, w = tid>>6, lane = tid&63;
    int l15 = lane&15, l4 = lane>>4;
    bf16 (*sP)[72] = (bf16(*)[72])(L + 30464 + w*2304);   // per-wave 16x72 slot

    if (tid < FP) sFeat[tid] = (tid<F_) ? feat[(size_t)b*F_+tid] : 0.f;
    __syncthreads();   // B1

    // ---- phase A: stage x_rep (bf16) + column sums of squares (2-way f split) ----
    int hA = tid & 127, fpA = tid >> 7;
    float facc = 0.f;
    #pragma unroll 4
    for (int it=0; it<56; ++it){
        int f = fpA + 2*it;
        float v = 0.f;
        if (f < F_) v = sFeat[f] * emb[f*H_ + hA];
        facc += v*v;
        sNx[f][hA] = (bf16)v;
    }
    if (tid >= 128) sNorm[hA] = facc;
    __syncthreads();   // B2
    if (tid < 128) sNorm[hA] = sqrtf(facc + sNorm[hA]);

    int mt0 = w, mt1 = w+4;   // wave's two f-tiles (mt1==7 inactive)

    // ---- att path (uses RAW x_rep): att[f] = sum_n relu(sigt[n] + sig(x_rep@a2w + a2b)[f,n]) * a3w[n]
    bf16x8 axf[2][4];
    #pragma unroll
    for (int i=0;i<2;i++){
        int mt = i? mt1 : mt0;
        if (mt<7){
            #pragma unroll
            for (int kc=0;kc<4;kc++)
                axf[i][kc] = *(const bf16x8*)(&sNx[mt*16+l15][kc*32+l4*8]);
        }
    }
    float attp[2][4] = {{0,0,0,0},{0,0,0,0}};
    #pragma unroll 2
    for (int nt=0; nt<8; nt++){
        bf16x8 bfr[4];
        #pragma unroll
        for(int kc=0;kc<4;kc++)
            bfr[kc] = *(const bf16x8*)(wa2t + (nt*16+l15)*H_ + kc*32 + l4*8);
        float a2bc = a2b[nt*16+l15], a3c = a3w[nt*16+l15], sgc = sigt_g[nt*16+l15];
        #pragma unroll
        for(int i=0;i<2;i++){
            int mt = i? mt1 : mt0;
            if (mt < 7){
                f32x4 acc = {0.f,0.f,0.f,0.f};
                #pragma unroll
                for(int kc=0;kc<4;kc++) acc = mfma16(axf[i][kc], bfr[kc], acc);
                #pragma unroll
                for(int j=0;j<4;j++){
                    float u = sigmoidf_(acc[j] + a2bc);
                    float t = sgc + u;
                    t = t>0.f ? t : 0.f;
                    attp[i][j] += t * a3c;
                }
            }
        }
    }
    #pragma unroll
    for(int i=0;i<2;i++)
        #pragma unroll
        for(int j=0;j<4;j++){
            float v = attp[i][j];
            #pragma unroll
            for(int m=1;m<16;m<<=1) v += __shfl_xor(v,m,16);
            attp[i][j]=v;
        }
    if (l15==0){
        #pragma unroll
        for(int i=0;i<2;i++){ int mt = i? mt1 : mt0; if(mt<7){
            #pragma unroll
            for(int j=0;j<4;j++) sAtt[mt*16 + l4*4 + j] = attp[i][j];
        } }
    }
    __syncthreads();   // B3 (norm final + att done)

    // ---- softmax over f (wave 0 first), then all: rescale sNx in place to nx ----
    if (w==0){
        float a0 = (lane<F_)? sAtt[lane] : -1e30f;
        float a1 = (lane+64<F_)? sAtt[lane+64] : -1e30f;
        float m = fmaxf(a0,a1);
        #pragma unroll
        for(int s=1;s<64;s<<=1) m = fmaxf(m, __shfl_xor(m,s,64));
        float e0 = (lane<F_)? __expf(a0-m):0.f;
        float e1 = (lane+64<F_)? __expf(a1-m):0.f;
        float s = e0+e1;
        #pragma unroll
        for(int t=1;t<64;t<<=1) s += __shfl_xor(s,t,64);
        float inv = 1.f/s;
        if (lane<FP) sAw[lane] = e0*inv;
        if (lane+64<FP) sAw[lane+64] = e1*inv;
    }
    {
        float rn = __builtin_amdgcn_rcpf(sNorm[hA]);
        #pragma unroll 4
        for (int it=0; it<56; ++it){
            int f = fpA + 2*it;
            sNx[f][hA] = (bf16)((float)sNx[f][hA] * rn);
        }
    }
    __syncthreads();   // B4

    // ---- afx (normalized nx) fragments; alpha/beta; xt ----
    bf16x8 afx[2][4];
    #pragma unroll
    for (int i=0;i<2;i++){
        int mt = i? mt1 : mt0;
        if (mt<7){
            #pragma unroll
            for (int kc=0;kc<4;kc++)
                afx[i][kc] = *(const bf16x8*)(&sNx[mt*16+l15][kc*32+l4*8]);
        }
    }
    {
        bf16x8 bfr8[4];
        #pragma unroll
        for (int kc=0;kc<4;kc++)
            bfr8[kc] = *(const bf16x8*)(mextT + (128+l15)*H_ + kc*32 + l4*8);
        #pragma unroll
        for (int i=0;i<2;i++){
            int mt = i? mt1 : mt0;
            if (mt<7){
                f32x4 acc = {0.f,0.f,0.f,0.f};
                #pragma unroll
                for (int kc=0;kc<4;kc++) acc = mfma16(afx[i][kc], bfr8[kc], acc);
                if (l15==0){
                    #pragma unroll
                    for (int j=0;j<4;j++) sAlpha[mt*16+l4*4+j] = acc[j];
                }
                if (l15==1){
                    #pragma unroll
                    for (int j=0;j<4;j++) sBeta[mt*16+l4*4+j] = acc[j];
                }
            }
        }
    }
    // xt[h] = norm[h] * sum_f aw[f]*nx[f,h]
    if (tid < 128){
        int h=tid; float acc=0.f;
        #pragma unroll 4
        for(int f=0;f<F_;f++) acc += sAw[f]*(float)sNx[f][h];
        xtb[(size_t)b*H_ + h] = (bf16)(acc * sNorm[h]);
    }
    __syncthreads();   // B5 (beta cross-wave; sP region now free)

    // ---- S1 = nx@Mext (two-pass staged in 64-col sP) + scores + P (packed bf16) ----
    const float cc = cconst[0];
    unsigned uex[2][7][2];
    float inv_[2][4];
    #pragma unroll 1
    for (int i=0;i<2;i++){
        int mt = i? mt1 : mt0;
        if (mt >= 7) continue;
        f32x4 sc[7];
        #pragma unroll
        for (int gt=0; gt<7; gt++) sc[gt] = (f32x4){0.f,0.f,0.f,0.f};
        #pragma unroll 1
        for (int p=0; p<2; p++){
            #pragma unroll 2
            for (int nt4=0; nt4<4; nt4++){
                int nt = p*4 + nt4;
                bf16x8 bw[4];
                #pragma unroll
                for (int kc=0;kc<4;kc++)
                    bw[kc] = *(const bf16x8*)(mextT + (nt*16+l15)*H_ + kc*32 + l4*8);
                f32x4 d = {0.f,0.f,0.f,0.f};
                #pragma unroll
                for (int kc=0;kc<4;kc++) d = mfma16(afx[i][kc], bw[kc], d);
                #pragma unroll
                for (int j=0;j<4;j++) sP[l4*4+j][nt4*16+l15] = (bf16)d[j];
            }
            bf16x8 afs0 = *(const bf16x8*)&sP[l15][l4*8];
            bf16x8 afs1 = *(const bf16x8*)&sP[l15][32+l4*8];
            #pragma unroll
            for (int gt=0; gt<7; gt++){
                bf16x8 b0 = *(const bf16x8*)&sNx[gt*16+l15][p*64 + l4*8];
                bf16x8 b1 = *(const bf16x8*)&sNx[gt*16+l15][p*64 + 32 + l4*8];
                sc[gt] = mfma16(afs0, b0, sc[gt]);
                sc[gt] = mfma16(afs1, b1, sc[gt]);
            }
        }
        float aj[4];
        #pragma unroll
        for (int j=0;j<4;j++) aj[j] = sAlpha[mt*16+l4*4+j];
        float rs[4] = {0.f,0.f,0.f,0.f};
        #pragma unroll
        for (int gt=0; gt<7; gt++){
            float bg = sBeta[gt*16+l15];
            int g = gt*16+l15;
            float e[4];
            #pragma unroll
            for (int j=0;j<4;j++){
                float val = sc[gt][j] + aj[j] + bg + cc;
                e[j] = (g<F_) ? __expf(sigmoidf_(val)) : 0.f;
                rs[j] += e[j];
            }
            uex[i][gt][0] = pack2_(e[0],e[1]);
            uex[i][gt][1] = pack2_(e[2],e[3]);
        }
        #pragma unroll
        for (int j=0;j<4;j++){
            float v = rs[j];
            #pragma unroll
            for (int m2=1;m2<16;m2<<=1) v += __shfl_xor(v,m2,16);
            inv_[i][j] = 1.f/v;
        }
    }

    // stage P0 pass-A (g 0..63)
    union UP { unsigned u; bf16 v[2]; };
    if (mt0 < 7){
        #pragma unroll
        for (int gt=0; gt<4; gt++){
            #pragma unroll
            for (int j2=0; j2<2; j2++){
                UP u; u.u = uex[0][gt][j2];
                sP[l4*4+j2*2  ][gt*16+l15] = (bf16)((float)u.v[0] * inv_[0][j2*2  ]);
                sP[l4*4+j2*2+1][gt*16+l15] = (bf16)((float)u.v[1] * inv_[0][j2*2+1]);
            }
        }
    }

    // ---- V^T = wvT x nx (into regs; nx still live) ----
    f32x4 vacc[2][7];
    #pragma unroll 1
    for (int i2=0;i2<2;i2++){
        int ht = w + 4*i2;
        bf16x8 awv[4];
        #pragma unroll
        for (int kc=0;kc<4;kc++)
            awv[kc] = *(const bf16x8*)(wvT + (ht*16+l15)*H_ + kc*32 + l4*8);
        #pragma unroll
        for (int gt=0; gt<7; gt++){
            f32x4 acc = {0.f,0.f,0.f,0.f};
            #pragma unroll
            for (int kc=0;kc<4;kc++){
                bf16x8 bfr = *(const bf16x8*)(&sNx[gt*16+l15][kc*32+l4*8]);
                acc = mfma16(awv[kc], bfr, acc);
            }
            vacc[i2][gt] = acc;
        }
    }
    __syncthreads();   // B6: all sNx reads complete

    // write V^T (+vb) over the nx region (cols 0..111 all real)
    #pragma unroll
    for (int i2=0;i2<2;i2++){
        int ht = w + 4*i2;
        float vbj[4];
        #pragma unroll
        for (int j=0;j<4;j++) vbj[j] = vb[ht*16+l4*4+j];
        #pragma unroll
        for (int gt=0; gt<7; gt++)
            #pragma unroll
            for (int j=0;j<4;j++)
                sVT[ht*16+l4*4+j][gt*16+l15] = (bf16)(vacc[i2][gt][j] + vbj[j]);
    }
    __syncthreads();   // B7

    // ---- PV: ctx = P @ V (two-pass over g), lane-contiguous nontemporal store ----
    #pragma unroll 1
    for (int i=0;i<2;i++){
        int mt = i? mt1 : mt0;
        if (mt >= 7) continue;
        if (i==1){
            // stage P1 pass-A
            #pragma unroll
            for (int gt=0; gt<4; gt++){
                #pragma unroll
                for (int j2=0; j2<2; j2++){
                    UP u; u.u = uex[1][gt][j2];
                    sP[l4*4+j2*2  ][gt*16+l15] = (bf16)((float)u.v[0] * inv_[1][j2*2  ]);
                    sP[l4*4+j2*2+1][gt*16+l15] = (bf16)((float)u.v[1] * inv_[1][j2*2+1]);
                }
            }
        }
        bf16x8 ap0 = *(const bf16x8*)&sP[l15][l4*8];
        bf16x8 ap1 = *(const bf16x8*)&sP[l15][32+l4*8];
        f32x4 acc[8];
        #pragma unroll
        for (int ht=0;ht<8;ht++) acc[ht] = (f32x4){0.f,0.f,0.f,0.f};
        #pragma unroll
        for (int ht=0; ht<8; ht++){
            const bf16* vr = &sVT[ht*16+l15][0];
            int c0 = l4*8, c1 = 32+l4*8;
            acc[ht] = mfma16(ap0, ldb64x2(vr+c0, vr+c0+4), acc[ht]);
            acc[ht] = mfma16(ap1, ldb64x2(vr+c1, vr+c1+4), acc[ht]);
        }
        // restage pass-B (g 64..127; gt==7 -> zeros)
        #pragma unroll
        for (int gt=4; gt<7; gt++){
            #pragma unroll
            for (int j2=0; j2<2; j2++){
                UP u; u.u = uex[i][gt][j2];
                sP[l4*4+j2*2  ][(gt-4)*16+l15] = (bf16)((float)u.v[0] * inv_[i][j2*2  ]);
                sP[l4*4+j2*2+1][(gt-4)*16+l15] = (bf16)((float)u.v[1] * inv_[i][j2*2+1]);
            }
        }
        #pragma unroll
        for (int j=0;j<4;j++) sP[l4*4+j][48+l15] = (bf16)0.f;
        bf16x8 ap2 = *(const bf16x8*)&sP[l15][l4*8];
        bf16x8 ap3 = *(const bf16x8*)&sP[l15][32+l4*8];
        #pragma unroll
        for (int ht=0; ht<8; ht++){
            const bf16* vr = &sVT[ht*16+l15][0];
            int c2 = 64+l4*8;  if (c2 >= 112) c2 = 96;
            int c3 = 96+l4*8;  if (c3 >= 112) c3 = 96;
            acc[ht] = mfma16(ap2, ldb64x2(vr+c2, vr+c2+4), acc[ht]);
            acc[ht] = mfma16(ap3, ldb64x2(vr+c3, vr+c3+4), acc[ht]);
        }
        if (mt < 6){
            #pragma unroll
            for (int ht=0; ht<8; ht++){
                unsigned long long u = pack4_(acc[ht][0],acc[ht][1],acc[ht][2],acc[ht][3]);
                __builtin_nontemporal_store(u, (unsigned long long*)(xx + (size_t)b*KC_ + (mt*8+ht)*256 + lane*4));
            }
        } else if (l4 == 0){
            #pragma unroll
            for (int ht=0; ht<8; ht++){
                unsigned long long u = pack4_(acc[ht][0],acc[ht][1],acc[ht][2],acc[ht][3]);
                __builtin_nontemporal_store(u, (unsigned long long*)(xx + (size_t)b*KC_ + 12288 + ht*64 + l15*4));
            }
        }
    }
}

// ---------------- generic tiled GEMM: out = act(A @ Bt^T + bias) ----------------
// grid: (N/BN, M/128) so blocks sharing an A-tile are dispatch-adjacent
template<int BN, bool ELU>
__global__ __launch_bounds__(256,2) void k_gemm(const bf16* __restrict__ A, const bf16* __restrict__ Bt,
        const float* __restrict__ bias, bf16* __restrict__ out, int M, int N, int K)
{
    __shared__ bf16 sAt[128][72];
    __shared__ bf16 sBt[BN][72];
    int tid=threadIdx.x, w=tid>>6, lane=tid&63, l15=lane&15, l4=lane>>4;
    int m0 = blockIdx.y*128, n0 = blockIdx.x*BN;
    constexpr int MI = (BN==128)?4:2;
    constexpr int NI = (BN==128)?4:BN/16;
    int wr = (BN==128)? (w>>1) : w;
    int wc = (BN==128)? (w&1) : 0;
    f32x4 acc[MI][NI];
    #pragma unroll
    for(int mi=0;mi<MI;mi++)
        #pragma unroll
        for(int ni=0;ni<NI;ni++) acc[mi][ni] = (f32x4){0.f,0.f,0.f,0.f};

    for (int k0=0; k0<K; k0+=64){
        __syncthreads();
        for (int t=tid; t<128*8; t+=256){
            int row=t>>3, col=(t&7)*8;
            *(bf16x8*)&sAt[row][col] = *(const bf16x8*)(A + (size_t)(m0+row)*K + k0 + col);
        }
        for (int t=tid; t<BN*8; t+=256){
            int row=t>>3, col=(t&7)*8;
            *(bf16x8*)&sBt[row][col] = *(const bf16x8*)(Bt + (size_t)(n0+row)*K + k0 + col);
        }
        __syncthreads();
        #pragma unroll
        for(int ks=0;ks<2;ks++){
            bf16x8 af[MI], bfr[NI];
            #pragma unroll
            for(int mi=0;mi<MI;mi++) af[mi] = *(const bf16x8*)&sAt[wr*(MI*16)+mi*16+l15][ks*32+l4*8];
            #pragma unroll
            for(int ni=0;ni<NI;ni++) bfr[ni] = *(const bf16x8*)&sBt[wc*64+ni*16+l15][ks*32+l4*8];
            #pragma unroll
            for(int mi=0;mi<MI;mi++)
                #pragma unroll
                for(int ni=0;ni<NI;ni++)
                    acc[mi][ni] = mfma16(af[mi], bfr[ni], acc[mi][ni]);
        }
    }
    #pragma unroll
    for(int mi=0;mi<MI;mi++)
        #pragma unroll
        for(int ni=0;ni<NI;ni++){
            int col = n0 + wc*64 + ni*16 + l15;
            float bc = bias[col];
            #pragma unroll
            for(int j=0;j<4;j++){
                int row = m0 + wr*(MI*16) + mi*16 + l4*4 + j;
                float v = acc[mi][ni][j] + bc;
                if (ELU) v = eluf_(v);
                out[(size_t)row*N + col] = (bf16)v;
            }
        }
}

// ---------------- control heads ----------------
__global__ void k_heads(const bf16* __restrict__ c5o, const float* __restrict__ clw, const float* __restrict__ clb,
                        const float* __restrict__ ctw, const float* __restrict__ ctb, float* __restrict__ outp){
    int gid = blockIdx.x*4 + (threadIdx.x>>6);
    int lane = threadIdx.x & 63;
    float v = (float)c5o[(size_t)gid*64 + lane];
    float r1 = v*clw[lane], r2 = v*ctw[lane];
    #pragma unroll
    for(int m=1;m<64;m<<=1){ r1 += __shfl_xor(r1,m,64); r2 += __shfl_xor(r2,m,64); }
    if (lane==0){
        float cl = r1 + clb[0];
        outp[gid] = cl;
        outp[B_ + gid] = sigmoidf_(cl);
        outp[(size_t)2*B_ + gid] = r2 + ctb[0];
    }
}

// ---------------- uplift tail: u4 (K=32 -> 16) + heads ----------------
__global__ void k_utail(const bf16* __restrict__ u3o, const float* __restrict__ u4w, const float* __restrict__ u4b,
                        const float* __restrict__ tlw, const float* __restrict__ tlb,
                        const float* __restrict__ utw, const float* __restrict__ utb, float* __restrict__ outp){
    int row = blockIdx.x*4 + (threadIdx.x>>6);
    int lane = threadIdx.x & 63;
    int j = lane & 15;
    float acc = u4b[j];
    #pragma unroll 4
    for (int h=0; h<32; ++h) acc += (float)u3o[(size_t)row*32+h] * u4w[h*16+j];
    float u4 = eluf_(acc);
    float r1 = u4*tlw[j], r2 = u4*utw[j];
    #pragma unroll
    for(int m=1;m<16;m<<=1){ r1 += __shfl_xor(r1,m,16); r2 += __shfl_xor(r2,m,16); }
    if (lane==0){
        float tl = r1 + tlb[0];
        outp[(size_t)3*B_ + row] = tl;
        outp[(size_t)4*B_ + row] = sigmoidf_(tl);
        outp[(size_t)5*B_ + row] = r2 + utb[0];
    }
}

extern "C" void kernel_launch(void* const* d_in, const int* in_sizes, int n_in,
                              void* d_out, int out_size, void* d_ws, size_t ws_size,
                              hipStream_t stream) {
    const float* feat=(const float*)d_in[0];
    const float* emb =(const float*)d_in[2];
    const float* t_w =(const float*)d_in[3]; const float* t_b=(const float*)d_in[4];
    const float* qw  =(const float*)d_in[5]; const float* qb =(const float*)d_in[6];
    const float* kw  =(const float*)d_in[7]; const float* kb =(const float*)d_in[8];
    const float* vw  =(const float*)d_in[9]; const float* vb =(const float*)d_in[10];
    const float* a1w =(const float*)d_in[11];
    const float* a2w =(const float*)d_in[12]; const float* a2b=(const float*)d_in[13];
    const float* a3w =(const float*)d_in[14];
    const float* c1w =(const float*)d_in[15]; const float* c1b=(const float*)d_in[16];
    const float* c2w =(const float*)d_in[17]; const float* c2b=(const float*)d_in[18];
    const float* c3w =(const float*)d_in[19]; const float* c3b=(const float*)d_in[20];
    const float* c4w =(const float*)d_in[21]; const float* c4b=(const float*)d_in[22];
    const float* c5w =(const float*)d_in[23]; const float* c5b=(const float*)d_in[24];
    const float* clw =(const float*)d_in[25]; const float* clb=(const float*)d_in[26];
    const float* ctw =(const float*)d_in[27]; const float* ctb=(const float*)d_in[28];
    const float* u1w =(const float*)d_in[29]; const float* u1b=(const float*)d_in[30];
    const float* u2w =(const float*)d_in[31]; const float* u2b=(const float*)d_in[32];
    const float* u3w =(const float*)d_in[33]; const float* u3b=(const float*)d_in[34];
    const float* u4w =(const float*)d_in[35]; const float* u4b=(const float*)d_in[36];
    const float* tlw =(const float*)d_in[37]; const float* tlb=(const float*)d_in[38];
    const float* utw =(const float*)d_in[39]; const float* utb=(const float*)d_in[40];
    float* outp = (float*)d_out;

    char* ws = (char*)d_ws;
    size_t off = 0;
    auto alloc = [&](size_t bytes)->char*{ char* p = ws + off; off += (bytes + 255) & ~(size_t)255; return p; };
    bf16* xx    = (bf16*)alloc((size_t)B_*KC_*2);      // 209.7 MB; region reused below
    bf16* xtb   = (bf16*)alloc((size_t)B_*128*2);
    bf16* cbuf1 = (bf16*)alloc((size_t)B_*512*2);
    bf16* mextT = (bf16*)alloc(144*128*2);
    bf16* wvT   = (bf16*)alloc(128*128*2);
    bf16* wa2t  = (bf16*)alloc(128*128*2);
    bf16* c1wtk = (bf16*)alloc((size_t)512*KC_*2);
    bf16* c2wt  = (bf16*)alloc((size_t)512*512*2);
    bf16* c3wt  = (bf16*)alloc((size_t)512*256*2);
    bf16* c4wt  = (bf16*)alloc((size_t)256*128*2);
    bf16* c5wt  = (bf16*)alloc((size_t)128*64*2);
    bf16* u1t   = (bf16*)alloc(128*128*2);
    bf16* u2t   = (bf16*)alloc(64*128*2);
    bf16* u3t   = (bf16*)alloc(32*64*2);
    float* sigt = (float*)alloc(128*4);
    float* cconst = (float*)alloc(4);
    // aliases into the xx region (xx is dead after the c1 GEMM; stream is sequential)
    bf16* cbuf2 = xx;
    bf16* cbuf3 = xx +  8388608;
    bf16* cbuf4 = xx + 16777216;
    bf16* cbuf5 = xx + 25165824;
    bf16* ubuf1 = xx + 33554432;
    bf16* ubuf2 = xx + 41943040;
    bf16* ubuf3 = xx + 50331648;
    (void)ws_size; (void)in_sizes; (void)n_in; (void)out_size;

    k_prepw<<<10,256,0,stream>>>(qw,qb,kw,kb,t_w,t_b,a1w,mextT,sigt,cconst);
    k_transpose_cvt<<<dim3(4,4),256,0,stream>>>(vw,  wvT, 128,128);
    k_transpose_cvt<<<dim3(4,4),256,0,stream>>>(a2w, wa2t,128,128);
    k_tc_kappa<<<dim3(16,400),256,0,stream>>>(c1w, c1wtk);
    k_transpose_cvt<<<dim3(16,16),256,0,stream>>>(c2w, c2wt, 512,512);
    k_transpose_cvt<<<dim3(8,16),256,0,stream>>>(c3w, c3wt, 512,256);
    k_transpose_cvt<<<dim3(4,8),256,0,stream>>>(c4w, c4wt, 256,128);
    k_transpose_cvt<<<dim3(2,4),256,0,stream>>>(c5w, c5wt, 128,64);
    k_transpose_cvt<<<dim3(4,4),256,0,stream>>>(u1w, u1t, 128,128);
    k_transpose_cvt<<<dim3(2,4),256,0,stream>>>(u2w, u2t, 128,64);
    k_transpose_cvt<<<dim3(1,2),256,0,stream>>>(u3w, u3t, 64,32);

    k_attn2<<<B_,256,0,stream>>>(feat,emb,mextT,wa2t,wvT,vb,a2b,a3w,sigt,cconst, xx, xtb);

    k_gemm<128,true><<<dim3(4,64),256,0,stream>>>(xx,    c1wtk, c1b, cbuf1, B_,512,KC_);
    k_gemm<128,true><<<dim3(4,64),256,0,stream>>>(cbuf1, c2wt, c2b, cbuf2, B_,512,512);
    k_gemm<128,true><<<dim3(2,64),256,0,stream>>>(cbuf2, c3wt, c3b, cbuf3, B_,256,512);
    k_gemm<128,true><<<dim3(1,64),256,0,stream>>>(cbuf3, c4wt, c4b, cbuf4, B_,128,256);
    k_gemm<64, true><<<dim3(1,64),256,0,stream>>>(cbuf4, c5wt, c5b, cbuf5, B_,64,128);
    k_heads<<<2048,256,0,stream>>>(cbuf5,clw,clb,ctw,ctb,outp);

    k_gemm<128,true><<<dim3(1,64),256,0,stream>>>(xtb,   u1t, u1b, ubuf1, B_,128,128);
    k_gemm<64, true><<<dim3(1,64),256,0,stream>>>(ubuf1, u2t, u2b, ubuf2, B_,64,128);
    k_gemm<32, true><<<dim3(1,64),256,0,stream>>>(ubuf2, u3t, u3b, ubuf3, B_,32,64);
    k_utail<<<2048,256,0,stream>>>(ubuf3,u4w,u4b,tlw,tlb,utw,utb,outp);
}

// Round 6
// 1020.135 us; speedup vs baseline: 2.0775x; 1.6700x over previous
//
#include <hip/hip_runtime.h>
#include <hip/hip_bf16.h>

typedef __bf16 bf16;
typedef __bf16 bf16x8 __attribute__((ext_vector_type(8)));
typedef __bf16 bf16x4 __attribute__((ext_vector_type(4)));
typedef float f32x4 __attribute__((ext_vector_type(4)));
typedef unsigned u32x4 __attribute__((ext_vector_type(4)));

#define DEVI static __device__ __forceinline__

DEVI float sigmoidf_(float x){ return 1.0f/(1.0f+__expf(-x)); }
DEVI float eluf_(float x){ return x>0.f ? x : (__expf(x)-1.f); }
DEVI f32x4 mfma16(bf16x8 a, bf16x8 b, f32x4 c){ return __builtin_amdgcn_mfma_f32_16x16x32_bf16(a,b,c,0,0,0); }
DEVI f32x4 mfma8(long a, long b, f32x4 c){ return __builtin_amdgcn_mfma_f32_16x16x32_fp8_fp8(a,b,c,0,0,0); }
DEVI unsigned pack2_(float a, float b){
    union { bf16 v[2]; unsigned u; } t; t.v[0]=(bf16)a; t.v[1]=(bf16)b; return t.u;
}
DEVI unsigned long long pack4_(float a, float b, float c, float d){
    union { bf16 v[4]; unsigned long long u; } t;
    t.v[0]=(bf16)a; t.v[1]=(bf16)b; t.v[2]=(bf16)c; t.v[3]=(bf16)d; return t.u;
}
// 4 floats (pre-scaled) -> 4 fp8 e4m3 bytes
DEVI unsigned cvtfp8x4_(float a, float b, float c, float d){
    int v = __builtin_amdgcn_cvt_pk_fp8_f32(a, b, 0, false);
    v = __builtin_amdgcn_cvt_pk_fp8_f32(c, d, v, true);
    return (unsigned)v;
}
DEVI bf16x8 ldb64x2(const bf16* p0, const bf16* p1){
    union { bf16x8 v8; bf16x4 v4[2]; } u;
    u.v4[0] = *(const bf16x4*)p0;
    u.v4[1] = *(const bf16x4*)p1;
    return u.v8;
}

#define B_ 8192
#define F_ 100
#define FP 112
#define H_ 128
#define KC_ 12800   // compact kappa-blocked K: 48*256 + 8*64
#define SPLIT_ 4
#define FP8SC 16.0f   // operand scale; product carries 256, epilogue divides

// ---------------- weight prep ----------------
__global__ void k_prepw(const float* __restrict__ qw, const float* __restrict__ qb,
                        const float* __restrict__ kw, const float* __restrict__ kb,
                        const float* __restrict__ tw, const float* __restrict__ tb,
                        const float* __restrict__ a1w,
                        bf16* __restrict__ mextT, float* __restrict__ sigt, float* __restrict__ cconst){
    const float rsc = 0.08838834764831845f;
    int blk = blockIdx.x, tid = threadIdx.x;
    if (blk < 9){
        #pragma unroll 1
        for (int e=0; e<8; ++e){
            int idx = e*256 + tid;
            int n = blk*16 + (idx>>7), h = idx&127;
            float acc = 0.f;
            if (n < 128){
                for (int d=0; d<128; ++d) acc += qw[h*128+d]*kw[n*128+d];
            } else if (n == 128){
                for (int d=0; d<128; ++d) acc += qw[h*128+d]*kb[d];
            } else if (n == 129){
                for (int d=0; d<128; ++d) acc += kw[h*128+d]*qb[d];
            }
            mextT[n*128+h] = (bf16)(acc*rsc);
        }
    } else {
        if (tid < 128){
            float acc = 0.f;
            for (int h=0; h<128; ++h) acc += (tw[h]+tb[h]) * a1w[h*128+tid];
            sigt[tid] = sigmoidf_(acc);
        } else if (tid == 128){
            float acc = 0.f;
            for (int d=0; d<128; ++d) acc += qb[d]*kb[d];
            cconst[0] = acc*rsc;
        }
    }
}

// in [R][C] f32 -> out [C][R] bf16
__global__ void k_transpose_cvt(const float* __restrict__ in, bf16* __restrict__ out, int R, int C){
    __shared__ float t[32][33];
    int c0 = blockIdx.x*32, r0 = blockIdx.y*32;
    int tc = threadIdx.x & 31, tr = threadIdx.x >> 5;
    #pragma unroll
    for (int i=0;i<4;i++){
        int r = tr + i*8;
        t[r][tc] = in[(size_t)(r0+r)*C + c0 + tc];
    }
    __syncthreads();
    #pragma unroll
    for (int i=0;i<4;i++){
        int ro = tr + i*8;
        out[(size_t)(c0+ro)*R + r0 + tc] = (bf16)t[tc][ro];
    }
}

// compact kappa: bijection on [0,12800). In-tile layout is LANE-LINEAR for the
// k_attn2 PV store: in-tile idx = 4*lane + j
DEVI int kappa_(int k){
    int f = k>>7, h = k&127;
    if (f < 96)
        return (((f>>4)<<3) | (h>>4))*256 + ((f&15)>>2)*64 + (h&15)*4 + (f&3);
    else
        return 12288 + (h>>4)*64 + (h&15)*4 + (f&3);
}
// c1w [12800][512] f32 -> c1wtk8 [512][12800] fp8 (scaled x16), kappa-permuted K
__global__ void k_tc_kappa8(const float* __restrict__ in, unsigned char* __restrict__ out){
    __shared__ float t[32][33];
    const int C = 512;
    int c0 = blockIdx.x*32, r0 = blockIdx.y*32;
    int tc = threadIdx.x & 31, tr = threadIdx.x >> 5;
    #pragma unroll
    for (int i=0;i<4;i++){
        int r = tr + i*8;
        t[r][tc] = in[(size_t)(r0+r)*C + c0 + tc];
    }
    __syncthreads();
    #pragma unroll
    for (int i=0;i<4;i++){
        int ro = tr + i*8;
        float x = t[tc][ro]*FP8SC;
        int v = __builtin_amdgcn_cvt_pk_fp8_f32(x, x, 0, false);
        out[(size_t)(c0+ro)*KC_ + kappa_(r0+tc)] = (unsigned char)v;
    }
}

// ---------------- fused per-batch attention (one block per batch, 4 blocks/CU) ----------------
__global__ __launch_bounds__(256,4) void k_attn2(
    const float* __restrict__ feat, const float* __restrict__ emb,
    const bf16* __restrict__ mextT, const bf16* __restrict__ wa2t,
    const bf16* __restrict__ wvT, const float* __restrict__ vb,
    const float* __restrict__ a2b, const float* __restrict__ a3w,
    const float* __restrict__ sigt_g, const float* __restrict__ cconst,
    unsigned char* __restrict__ xxb, bf16* __restrict__ xtb)
{
    __shared__ char L[40576];
    bf16 (*sNx)[136] = (bf16(*)[136])L;
    bf16 (*sVT)[116] = (bf16(*)[116])L;
    float* sFeat  = (float*)(L+30464);
    float* sNorm  = (float*)(L+30912);
    float* sAtt   = (float*)(L+31424);
    float* sAw    = (float*)(L+31872);
    float* sAlpha = (float*)(L+39680);
    float* sBeta  = (float*)(L+40128);

    int b = blockIdx.x;
    int tid = threadIdx.x, w = tid>>6, lane = tid&63;
    int l15 = lane&15, l4 = lane>>4;
    bf16 (*sP)[72] = (bf16(*)[72])(L + 30464 + w*2304);

    if (tid < FP) sFeat[tid] = (tid<F_) ? feat[(size_t)b*F_+tid] : 0.f;
    __syncthreads();   // B1

    int hA = tid & 127, fpA = tid >> 7;
    float facc = 0.f;
    #pragma unroll 4
    for (int it=0; it<56; ++it){
        int f = fpA + 2*it;
        float v = 0.f;
        if (f < F_) v = sFeat[f] * emb[f*H_ + hA];
        facc += v*v;
        sNx[f][hA] = (bf16)v;
    }
    if (tid >= 128) sNorm[hA] = facc;
    __syncthreads();   // B2
    if (tid < 128) sNorm[hA] = sqrtf(facc + sNorm[hA]);

    int mt0 = w, mt1 = w+4;

    bf16x8 axf[2][4];
    #pragma unroll
    for (int i=0;i<2;i++){
        int mt = i? mt1 : mt0;
        if (mt<7){
            #pragma unroll
            for (int kc=0;kc<4;kc++)
                axf[i][kc] = *(const bf16x8*)(&sNx[mt*16+l15][kc*32+l4*8]);
        }
    }
    float attp[2][4] = {{0,0,0,0},{0,0,0,0}};
    #pragma unroll 2
    for (int nt=0; nt<8; nt++){
        bf16x8 bfr[4];
        #pragma unroll
        for(int kc=0;kc<4;kc++)
            bfr[kc] = *(const bf16x8*)(wa2t + (nt*16+l15)*H_ + kc*32 + l4*8);
        float a2bc = a2b[nt*16+l15], a3c = a3w[nt*16+l15], sgc = sigt_g[nt*16+l15];
        #pragma unroll
        for(int i=0;i<2;i++){
            int mt = i? mt1 : mt0;
            if (mt < 7){
                f32x4 acc = {0.f,0.f,0.f,0.f};
                #pragma unroll
                for(int kc=0;kc<4;kc++) acc = mfma16(axf[i][kc], bfr[kc], acc);
                #pragma unroll
                for(int j=0;j<4;j++){
                    float u = sigmoidf_(acc[j] + a2bc);
                    float t = sgc + u;
                    t = t>0.f ? t : 0.f;
                    attp[i][j] += t * a3c;
                }
            }
        }
    }
    #pragma unroll
    for(int i=0;i<2;i++)
        #pragma unroll
        for(int j=0;j<4;j++){
            float v = attp[i][j];
            #pragma unroll
            for(int m=1;m<16;m<<=1) v += __shfl_xor(v,m,16);
            attp[i][j]=v;
        }
    if (l15==0){
        #pragma unroll
        for(int i=0;i<2;i++){ int mt = i? mt1 : mt0; if(mt<7){
            #pragma unroll
            for(int j=0;j<4;j++) sAtt[mt*16 + l4*4 + j] = attp[i][j];
        } }
    }
    __syncthreads();   // B3

    if (w==0){
        float a0 = (lane<F_)? sAtt[lane] : -1e30f;
        float a1 = (lane+64<F_)? sAtt[lane+64] : -1e30f;
        float m = fmaxf(a0,a1);
        #pragma unroll
        for(int s=1;s<64;s<<=1) m = fmaxf(m, __shfl_xor(m,s,64));
        float e0 = (lane<F_)? __expf(a0-m):0.f;
        float e1 = (lane+64<F_)? __expf(a1-m):0.f;
        float s = e0+e1;
        #pragma unroll
        for(int t=1;t<64;t<<=1) s += __shfl_xor(s,t,64);
        float inv = 1.f/s;
        if (lane<FP) sAw[lane] = e0*inv;
        if (lane+64<FP) sAw[lane+64] = e1*inv;
    }
    {
        float rn = __builtin_amdgcn_rcpf(sNorm[hA]);
        #pragma unroll 4
        for (int it=0; it<56; ++it){
            int f = fpA + 2*it;
            sNx[f][hA] = (bf16)((float)sNx[f][hA] * rn);
        }
    }
    __syncthreads();   // B4

    bf16x8 afx[2][4];
    #pragma unroll
    for (int i=0;i<2;i++){
        int mt = i? mt1 : mt0;
        if (mt<7){
            #pragma unroll
            for (int kc=0;kc<4;kc++)
                afx[i][kc] = *(const bf16x8*)(&sNx[mt*16+l15][kc*32+l4*8]);
        }
    }
    {
        bf16x8 bfr8[4];
        #pragma unroll
        for (int kc=0;kc<4;kc++)
            bfr8[kc] = *(const bf16x8*)(mextT + (128+l15)*H_ + kc*32 + l4*8);
        #pragma unroll
        for (int i=0;i<2;i++){
            int mt = i? mt1 : mt0;
            if (mt<7){
                f32x4 acc = {0.f,0.f,0.f,0.f};
                #pragma unroll
                for (int kc=0;kc<4;kc++) acc = mfma16(afx[i][kc], bfr8[kc], acc);
                if (l15==0){
                    #pragma unroll
                    for (int j=0;j<4;j++) sAlpha[mt*16+l4*4+j] = acc[j];
                }
                if (l15==1){
                    #pragma unroll
                    for (int j=0;j<4;j++) sBeta[mt*16+l4*4+j] = acc[j];
                }
            }
        }
    }
    if (tid < 128){
        int h=tid; float acc=0.f;
        #pragma unroll 4
        for(int f=0;f<F_;f++) acc += sAw[f]*(float)sNx[f][h];
        xtb[(size_t)b*H_ + h] = (bf16)(acc * sNorm[h]);
    }
    __syncthreads();   // B5

    const float cc = cconst[0];
    unsigned uex[2][7][2];
    float inv_[2][4];
    #pragma unroll 1
    for (int i=0;i<2;i++){
        int mt = i? mt1 : mt0;
        if (mt >= 7) continue;
        f32x4 sc[7];
        #pragma unroll
        for (int gt=0; gt<7; gt++) sc[gt] = (f32x4){0.f,0.f,0.f,0.f};
        #pragma unroll 1
        for (int p=0; p<2; p++){
            #pragma unroll 2
            for (int nt4=0; nt4<4; nt4++){
                int nt = p*4 + nt4;
                bf16x8 bw[4];
                #pragma unroll
                for (int kc=0;kc<4;kc++)
                    bw[kc] = *(const bf16x8*)(mextT + (nt*16+l15)*H_ + kc*32 + l4*8);
                f32x4 d = {0.f,0.f,0.f,0.f};
                #pragma unroll
                for (int kc=0;kc<4;kc++) d = mfma16(afx[i][kc], bw[kc], d);
                #pragma unroll
                for (int j=0;j<4;j++) sP[l4*4+j][nt4*16+l15] = (bf16)d[j];
            }
            bf16x8 afs0 = *(const bf16x8*)&sP[l15][l4*8];
            bf16x8 afs1 = *(const bf16x8*)&sP[l15][32+l4*8];
            #pragma unroll
            for (int gt=0; gt<7; gt++){
                bf16x8 b0 = *(const bf16x8*)&sNx[gt*16+l15][p*64 + l4*8];
                bf16x8 b1 = *(const bf16x8*)&sNx[gt*16+l15][p*64 + 32 + l4*8];
                sc[gt] = mfma16(afs0, b0, sc[gt]);
                sc[gt] = mfma16(afs1, b1, sc[gt]);
            }
        }
        float aj[4];
        #pragma unroll
        for (int j=0;j<4;j++) aj[j] = sAlpha[mt*16+l4*4+j];
        float rs[4] = {0.f,0.f,0.f,0.f};
        #pragma unroll
        for (int gt=0; gt<7; gt++){
            float bg = sBeta[gt*16+l15];
            int g = gt*16+l15;
            float e[4];
            #pragma unroll
            for (int j=0;j<4;j++){
                float val = sc[gt][j] + aj[j] + bg + cc;
                e[j] = (g<F_) ? __expf(sigmoidf_(val)) : 0.f;
                rs[j] += e[j];
            }
            uex[i][gt][0] = pack2_(e[0],e[1]);
            uex[i][gt][1] = pack2_(e[2],e[3]);
        }
        #pragma unroll
        for (int j=0;j<4;j++){
            float v = rs[j];
            #pragma unroll
            for (int m2=1;m2<16;m2<<=1) v += __shfl_xor(v,m2,16);
            inv_[i][j] = 1.f/v;
        }
    }

    union UP { unsigned u; bf16 v[2]; };
    if (mt0 < 7){
        #pragma unroll
        for (int gt=0; gt<4; gt++){
            #pragma unroll
            for (int j2=0; j2<2; j2++){
                UP u; u.u = uex[0][gt][j2];
                sP[l4*4+j2*2  ][gt*16+l15] = (bf16)((float)u.v[0] * inv_[0][j2*2  ]);
                sP[l4*4+j2*2+1][gt*16+l15] = (bf16)((float)u.v[1] * inv_[0][j2*2+1]);
            }
        }
    }

    f32x4 vacc[2][7];
    #pragma unroll 1
    for (int i2=0;i2<2;i2++){
        int ht = w + 4*i2;
        bf16x8 awv[4];
        #pragma unroll
        for (int kc=0;kc<4;kc++)
            awv[kc] = *(const bf16x8*)(wvT + (ht*16+l15)*H_ + kc*32 + l4*8);
        #pragma unroll
        for (int gt=0; gt<7; gt++){
            f32x4 acc = {0.f,0.f,0.f,0.f};
            #pragma unroll
            for (int kc=0;kc<4;kc++){
                bf16x8 bfr = *(const bf16x8*)(&sNx[gt*16+l15][kc*32+l4*8]);
                acc = mfma16(awv[kc], bfr, acc);
            }
            vacc[i2][gt] = acc;
        }
    }
    __syncthreads();   // B6

    #pragma unroll
    for (int i2=0;i2<2;i2++){
        int ht = w + 4*i2;
        float vbj[4];
        #pragma unroll
        for (int j=0;j<4;j++) vbj[j] = vb[ht*16+l4*4+j];
        #pragma unroll
        for (int gt=0; gt<7; gt++)
            #pragma unroll
            for (int j=0;j<4;j++)
                sVT[ht*16+l4*4+j][gt*16+l15] = (bf16)(vacc[i2][gt][j] + vbj[j]);
    }
    __syncthreads();   // B7

    #pragma unroll 1
    for (int i=0;i<2;i++){
        int mt = i? mt1 : mt0;
        if (mt >= 7) continue;
        if (i==1){
            #pragma unroll
            for (int gt=0; gt<4; gt++){
                #pragma unroll
                for (int j2=0; j2<2; j2++){
                    UP u; u.u = uex[1][gt][j2];
                    sP[l4*4+j2*2  ][gt*16+l15] = (bf16)((float)u.v[0] * inv_[1][j2*2  ]);
                    sP[l4*4+j2*2+1][gt*16+l15] = (bf16)((float)u.v[1] * inv_[1][j2*2+1]);
                }
            }
        }
        bf16x8 ap0 = *(const bf16x8*)&sP[l15][l4*8];
        bf16x8 ap1 = *(const bf16x8*)&sP[l15][32+l4*8];
        f32x4 acc[8];
        #pragma unroll
        for (int ht=0;ht<8;ht++) acc[ht] = (f32x4){0.f,0.f,0.f,0.f};
        #pragma unroll
        for (int ht=0; ht<8; ht++){
            const bf16* vr = &sVT[ht*16+l15][0];
            int c0 = l4*8, c1 = 32+l4*8;
            acc[ht] = mfma16(ap0, ldb64x2(vr+c0, vr+c0+4), acc[ht]);
            acc[ht] = mfma16(ap1, ldb64x2(vr+c1, vr+c1+4), acc[ht]);
        }
        #pragma unroll
        for (int gt=4; gt<7; gt++){
            #pragma unroll
            for (int j2=0; j2<2; j2++){
                UP u; u.u = uex[i][gt][j2];
                sP[l4*4+j2*2  ][(gt-4)*16+l15] = (bf16)((float)u.v[0] * inv_[i][j2*2  ]);
                sP[l4*4+j2*2+1][(gt-4)*16+l15] = (bf16)((float)u.v[1] * inv_[i][j2*2+1]);
            }
        }
        #pragma unroll
        for (int j=0;j<4;j++) sP[l4*4+j][48+l15] = (bf16)0.f;
        bf16x8 ap2 = *(const bf16x8*)&sP[l15][l4*8];
        bf16x8 ap3 = *(const bf16x8*)&sP[l15][32+l4*8];
        #pragma unroll
        for (int ht=0; ht<8; ht++){
            const bf16* vr = &sVT[ht*16+l15][0];
            int c2 = 64+l4*8;  if (c2 >= 112) c2 = 96;
            int c3 = 96+l4*8;  if (c3 >= 112) c3 = 96;
            acc[ht] = mfma16(ap2, ldb64x2(vr+c2, vr+c2+4), acc[ht]);
            acc[ht] = mfma16(ap3, ldb64x2(vr+c3, vr+c3+4), acc[ht]);
        }
        // fp8 store (scaled x16), lane-contiguous u32 per lane
        if (mt < 6){
            #pragma unroll
            for (int ht=0; ht<8; ht++){
                unsigned u = cvtfp8x4_(acc[ht][0]*FP8SC, acc[ht][1]*FP8SC, acc[ht][2]*FP8SC, acc[ht][3]*FP8SC);
                *(unsigned*)(xxb + (size_t)b*KC_ + (mt*8+ht)*256 + lane*4) = u;
            }
        } else if (l4 == 0){
            #pragma unroll
            for (int ht=0; ht<8; ht++){
                unsigned u = cvtfp8x4_(acc[ht][0]*FP8SC, acc[ht][1]*FP8SC, acc[ht][2]*FP8SC, acc[ht][3]*FP8SC);
                *(unsigned*)(xxb + (size_t)b*KC_ + 12288 + ht*64 + l15*4) = u;
            }
        }
    }
}

// ---------------- fp8 split-K GEMM: part[z] = A[:, zK..] @ Bt[:, zK..]^T ----------------
// grid (N/128, M/128, SPLIT)
__global__ __launch_bounds__(256,4) void k_gemm_fp8(const unsigned char* __restrict__ A,
        const unsigned char* __restrict__ Bt, float* __restrict__ part, int M, int N, int K, int KS)
{
    __shared__ unsigned char sA[128][72];
    __shared__ unsigned char sB[128][72];
    int tid=threadIdx.x, w=tid>>6, lane=tid&63, l15=lane&15, l4=lane>>4;
    int m0 = blockIdx.y*128, n0 = blockIdx.x*128;
    int kbeg = blockIdx.z*KS, kend = kbeg + KS;
    int wr = w>>1, wc = w&1;
    f32x4 acc[4][4];
    #pragma unroll
    for(int mi=0;mi<4;mi++)
        #pragma unroll
        for(int ni=0;ni<4;ni++) acc[mi][ni] = (f32x4){0.f,0.f,0.f,0.f};

    for (int k0=kbeg; k0<kend; k0+=64){
        __syncthreads();
        #pragma unroll
        for (int t2=0;t2<2;t2++){
            int t = tid + t2*256;
            int row=t>>2, col=(t&3)*16;
            *(u32x4*)&sA[row][col] = *(const u32x4*)(A + (size_t)(m0+row)*K + k0 + col);
            *(u32x4*)&sB[row][col] = *(const u32x4*)(Bt + (size_t)(n0+row)*K + k0 + col);
        }
        __syncthreads();
        #pragma unroll
        for(int ks=0;ks<2;ks++){
            long af[4], bfr[4];
            #pragma unroll
            for(int mi=0;mi<4;mi++) af[mi] = *(const long*)&sA[wr*64+mi*16+l15][ks*32+l4*8];
            #pragma unroll
            for(int ni=0;ni<4;ni++) bfr[ni] = *(const long*)&sB[wc*64+ni*16+l15][ks*32+l4*8];
            #pragma unroll
            for(int mi=0;mi<4;mi++)
                #pragma unroll
                for(int ni=0;ni<4;ni++)
                    acc[mi][ni] = mfma8(af[mi], bfr[ni], acc[mi][ni]);
        }
    }
    float* pz = part + (size_t)blockIdx.z*M*N;
    #pragma unroll
    for(int mi=0;mi<4;mi++)
        #pragma unroll
        for(int ni=0;ni<4;ni++){
            int col = n0 + wc*64 + ni*16 + l15;
            #pragma unroll
            for(int j=0;j<4;j++){
                int row = m0 + wr*64 + mi*16 + l4*4 + j;
                pz[(size_t)row*N + col] = acc[mi][ni][j];
            }
        }
}

// reduce SPLIT partials + bias + ELU -> bf16  (grid: M*N/1024 blocks)
__global__ void k_c1fin(const float* __restrict__ part, const float* __restrict__ bias,
                        bf16* __restrict__ out){
    const size_t MN = (size_t)B_*512;
    size_t e0 = ((size_t)blockIdx.x*256 + threadIdx.x)*4;
    f32x4 s = *(const f32x4*)(part + e0);
    s += *(const f32x4*)(part + MN + e0);
    s += *(const f32x4*)(part + 2*MN + e0);
    s += *(const f32x4*)(part + 3*MN + e0);
    f32x4 bb = *(const f32x4*)(bias + (e0 & 511));
    const float ds = 1.0f/(FP8SC*FP8SC);
    unsigned long long u = pack4_(eluf_(s[0]*ds+bb[0]), eluf_(s[1]*ds+bb[1]),
                                  eluf_(s[2]*ds+bb[2]), eluf_(s[3]*ds+bb[3]));
    *(unsigned long long*)(out + e0) = u;
}

// ---------------- generic tiled GEMM: out = act(A @ Bt^T + bias) ----------------
template<int BN, bool ELU>
__global__ __launch_bounds__(256,2) void k_gemm(const bf16* __restrict__ A, const bf16* __restrict__ Bt,
        const float* __restrict__ bias, bf16* __restrict__ out, int M, int N, int K)
{
    __shared__ bf16 sAt[128][72];
    __shared__ bf16 sBt[BN][72];
    int tid=threadIdx.x, w=tid>>6, lane=tid&63, l15=lane&15, l4=lane>>4;
    int m0 = blockIdx.y*128, n0 = blockIdx.x*BN;
    constexpr int MI = (BN==128)?4:2;
    constexpr int NI = (BN==128)?4:BN/16;
    int wr = (BN==128)? (w>>1) : w;
    int wc = (BN==128)? (w&1) : 0;
    f32x4 acc[MI][NI];
    #pragma unroll
    for(int mi=0;mi<MI;mi++)
        #pragma unroll
        for(int ni=0;ni<NI;ni++) acc[mi][ni] = (f32x4){0.f,0.f,0.f,0.f};

    for (int k0=0; k0<K; k0+=64){
        __syncthreads();
        for (int t=tid; t<128*8; t+=256){
            int row=t>>3, col=(t&7)*8;
            *(bf16x8*)&sAt[row][col] = *(const bf16x8*)(A + (size_t)(m0+row)*K + k0 + col);
        }
        for (int t=tid; t<BN*8; t+=256){
            int row=t>>3, col=(t&7)*8;
            *(bf16x8*)&sBt[row][col] = *(const bf16x8*)(Bt + (size_t)(n0+row)*K + k0 + col);
        }
        __syncthreads();
        #pragma unroll
        for(int ks=0;ks<2;ks++){
            bf16x8 af[MI], bfr[NI];
            #pragma unroll
            for(int mi=0;mi<MI;mi++) af[mi] = *(const bf16x8*)&sAt[wr*(MI*16)+mi*16+l15][ks*32+l4*8];
            #pragma unroll
            for(int ni=0;ni<NI;ni++) bfr[ni] = *(const bf16x8*)&sBt[wc*64+ni*16+l15][ks*32+l4*8];
            #pragma unroll
            for(int mi=0;mi<MI;mi++)
                #pragma unroll
                for(int ni=0;ni<NI;ni++)
                    acc[mi][ni] = mfma16(af[mi], bfr[ni], acc[mi][ni]);
        }
    }
    #pragma unroll
    for(int mi=0;mi<MI;mi++)
        #pragma unroll
        for(int ni=0;ni<NI;ni++){
            int col = n0 + wc*64 + ni*16 + l15;
            float bc = bias[col];
            #pragma unroll
            for(int j=0;j<4;j++){
                int row = m0 + wr*(MI*16) + mi*16 + l4*4 + j;
                float v = acc[mi][ni][j] + bc;
                if (ELU) v = eluf_(v);
                out[(size_t)row*N + col] = (bf16)v;
            }
        }
}

// ---------------- control heads ----------------
__global__ void k_heads(const bf16* __restrict__ c5o, const float* __restrict__ clw, const float* __restrict__ clb,
                        const float* __restrict__ ctw, const float* __restrict__ ctb, float* __restrict__ outp){
    int gid = blockIdx.x*4 + (threadIdx.x>>6);
    int lane = threadIdx.x & 63;
    float v = (float)c5o[(size_t)gid*64 + lane];
    float r1 = v*clw[lane], r2 = v*ctw[lane];
    #pragma unroll
    for(int m=1;m<64;m<<=1){ r1 += __shfl_xor(r1,m,64); r2 += __shfl_xor(r2,m,64); }
    if (lane==0){
        float cl = r1 + clb[0];
        outp[gid] = cl;
        outp[B_ + gid] = sigmoidf_(cl);
        outp[(size_t)2*B_ + gid] = r2 + ctb[0];
    }
}

// ---------------- uplift tail ----------------
__global__ void k_utail(const bf16* __restrict__ u3o, const float* __restrict__ u4w, const float* __restrict__ u4b,
                        const float* __restrict__ tlw, const float* __restrict__ tlb,
                        const float* __restrict__ utw, const float* __restrict__ utb, float* __restrict__ outp){
    int row = blockIdx.x*4 + (threadIdx.x>>6);
    int lane = threadIdx.x & 63;
    int j = lane & 15;
    float acc = u4b[j];
    #pragma unroll 4
    for (int h=0; h<32; ++h) acc += (float)u3o[(size_t)row*32+h] * u4w[h*16+j];
    float u4 = eluf_(acc);
    float r1 = u4*tlw[j], r2 = u4*utw[j];
    #pragma unroll
    for(int m=1;m<16;m<<=1){ r1 += __shfl_xor(r1,m,16); r2 += __shfl_xor(r2,m,16); }
    if (lane==0){
        float tl = r1 + tlb[0];
        outp[(size_t)3*B_ + row] = tl;
        outp[(size_t)4*B_ + row] = sigmoidf_(tl);
        outp[(size_t)5*B_ + row] = r2 + utb[0];
    }
}

extern "C" void kernel_launch(void* const* d_in, const int* in_sizes, int n_in,
                              void* d_out, int out_size, void* d_ws, size_t ws_size,
                              hipStream_t stream) {
    const float* feat=(const float*)d_in[0];
    const float* emb =(const float*)d_in[2];
    const float* t_w =(const float*)d_in[3]; const float* t_b=(const float*)d_in[4];
    const float* qw  =(const float*)d_in[5]; const float* qb =(const float*)d_in[6];
    const float* kw  =(const float*)d_in[7]; const float* kb =(const float*)d_in[8];
    const float* vw  =(const float*)d_in[9]; const float* vb =(const float*)d_in[10];
    const float* a1w =(const float*)d_in[11];
    const float* a2w =(const float*)d_in[12]; const float* a2b=(const float*)d_in[13];
    const float* a3w =(const float*)d_in[14];
    const float* c1w =(const float*)d_in[15]; const float* c1b=(const float*)d_in[16];
    const float* c2w =(const float*)d_in[17]; const float* c2b=(const float*)d_in[18];
    const float* c3w =(const float*)d_in[19]; const float* c3b=(const float*)d_in[20];
    const float* c4w =(const float*)d_in[21]; const float* c4b=(const float*)d_in[22];
    const float* c5w =(const float*)d_in[23]; const float* c5b=(const float*)d_in[24];
    const float* clw =(const float*)d_in[25]; const float* clb=(const float*)d_in[26];
    const float* ctw =(const float*)d_in[27]; const float* ctb=(const float*)d_in[28];
    const float* u1w =(const float*)d_in[29]; const float* u1b=(const float*)d_in[30];
    const float* u2w =(const float*)d_in[31]; const float* u2b=(const float*)d_in[32];
    const float* u3w =(const float*)d_in[33]; const float* u3b=(const float*)d_in[34];
    const float* u4w =(const float*)d_in[35]; const float* u4b=(const float*)d_in[36];
    const float* tlw =(const float*)d_in[37]; const float* tlb=(const float*)d_in[38];
    const float* utw =(const float*)d_in[39]; const float* utb=(const float*)d_in[40];
    float* outp = (float*)d_out;

    char* ws = (char*)d_ws;
    size_t off = 0;
    auto alloc = [&](size_t bytes)->char*{ char* p = ws + off; off += (bytes + 255) & ~(size_t)255; return p; };
    unsigned char* xxb = (unsigned char*)alloc((size_t)B_*KC_);          // 104.9 MB fp8
    float* part  = (float*)alloc((size_t)SPLIT_*B_*512*4);               // 67.1 MB
    bf16* xtb    = (bf16*)alloc((size_t)B_*128*2);
    bf16* cbuf1  = (bf16*)alloc((size_t)B_*512*2);
    bf16* mextT  = (bf16*)alloc(144*128*2);
    bf16* wvT    = (bf16*)alloc(128*128*2);
    bf16* wa2t   = (bf16*)alloc(128*128*2);
    unsigned char* c1wtk8 = (unsigned char*)alloc((size_t)512*KC_);      // 6.5 MB fp8
    bf16* c2wt   = (bf16*)alloc((size_t)512*512*2);
    bf16* c3wt   = (bf16*)alloc((size_t)512*256*2);
    bf16* c4wt   = (bf16*)alloc((size_t)256*128*2);
    bf16* c5wt   = (bf16*)alloc((size_t)128*64*2);
    bf16* u1t    = (bf16*)alloc(128*128*2);
    bf16* u2t    = (bf16*)alloc(64*128*2);
    bf16* u3t    = (bf16*)alloc(32*64*2);
    float* sigt  = (float*)alloc(128*4);
    float* cconst= (float*)alloc(4);
    // aliases into the xx region (xx dead after c1 GEMM; stream is sequential)
    bf16* cbuf2 = (bf16*)(xxb);
    bf16* cbuf3 = (bf16*)(xxb + (16u<<20));
    bf16* cbuf4 = (bf16*)(xxb + (32u<<20));
    bf16* cbuf5 = (bf16*)(xxb + (48u<<20));
    bf16* ubuf1 = (bf16*)(xxb + (64u<<20));
    bf16* ubuf2 = (bf16*)(xxb + (80u<<20));
    bf16* ubuf3 = (bf16*)(xxb + (96u<<20));
    (void)ws_size; (void)in_sizes; (void)n_in; (void)out_size;

    k_prepw<<<10,256,0,stream>>>(qw,qb,kw,kb,t_w,t_b,a1w,mextT,sigt,cconst);
    k_transpose_cvt<<<dim3(4,4),256,0,stream>>>(vw,  wvT, 128,128);
    k_transpose_cvt<<<dim3(4,4),256,0,stream>>>(a2w, wa2t,128,128);
    k_tc_kappa8<<<dim3(16,400),256,0,stream>>>(c1w, c1wtk8);
    k_transpose_cvt<<<dim3(16,16),256,0,stream>>>(c2w, c2wt, 512,512);
    k_transpose_cvt<<<dim3(8,16),256,0,stream>>>(c3w, c3wt, 512,256);
    k_transpose_cvt<<<dim3(4,8),256,0,stream>>>(c4w, c4wt, 256,128);
    k_transpose_cvt<<<dim3(2,4),256,0,stream>>>(c5w, c5wt, 128,64);
    k_transpose_cvt<<<dim3(4,4),256,0,stream>>>(u1w, u1t, 128,128);
    k_transpose_cvt<<<dim3(2,4),256,0,stream>>>(u2w, u2t, 128,64);
    k_transpose_cvt<<<dim3(1,2),256,0,stream>>>(u3w, u3t, 64,32);

    k_attn2<<<B_,256,0,stream>>>(feat,emb,mextT,wa2t,wvT,vb,a2b,a3w,sigt,cconst, xxb, xtb);

    k_gemm_fp8<<<dim3(4,64,SPLIT_),256,0,stream>>>(xxb, c1wtk8, part, B_,512,KC_, KC_/SPLIT_);
    k_c1fin<<<4096,256,0,stream>>>(part, c1b, cbuf1);

    k_gemm<128,true><<<dim3(4,64),256,0,stream>>>(cbuf1, c2wt, c2b, cbuf2, B_,512,512);
    k_gemm<128,true><<<dim3(2,64),256,0,stream>>>(cbuf2, c3wt, c3b, cbuf3, B_,256,512);
    k_gemm<128,true><<<dim3(1,64),256,0,stream>>>(cbuf3, c4wt, c4b, cbuf4, B_,128,256);
    k_gemm<64, true><<<dim3(1,64),256,0,stream>>>(cbuf4, c5wt, c5b, cbuf5, B_,64,128);
    k_heads<<<2048,256,0,stream>>>(cbuf5,clw,clb,ctw,ctb,outp);

    k_gemm<128,true><<<dim3(1,64),256,0,stream>>>(xtb,   u1t, u1b, ubuf1, B_,128,128);
    k_gemm<64, true><<<dim3(1,64),256,0,stream>>>(ubuf1, u2t, u2b, ubuf2, B_,64,128);
    k_gemm<32, true><<<dim3(1,64),256,0,stream>>>(ubuf2, u3t, u3b, ubuf3, B_,32,64);
    k_utail<<<2048,256,0,stream>>>(ubuf3,u4w,u4b,tlw,tlb,utw,utb,outp);
}

// Round 7
// 977.527 us; speedup vs baseline: 2.1681x; 1.0436x over previous
//
#include <hip/hip_runtime.h>
#include <hip/hip_bf16.h>

typedef __bf16 bf16;
typedef __bf16 bf16x8 __attribute__((ext_vector_type(8)));
typedef __bf16 bf16x4 __attribute__((ext_vector_type(4)));
typedef float f32x4 __attribute__((ext_vector_type(4)));
typedef unsigned u32x4 __attribute__((ext_vector_type(4)));

#define DEVI static __device__ __forceinline__

DEVI float sigmoidf_(float x){ return 1.0f/(1.0f+__expf(-x)); }
DEVI float eluf_(float x){ return x>0.f ? x : (__expf(x)-1.f); }
DEVI f32x4 mfma16(bf16x8 a, bf16x8 b, f32x4 c){ return __builtin_amdgcn_mfma_f32_16x16x32_bf16(a,b,c,0,0,0); }
DEVI f32x4 mfma8(long a, long b, f32x4 c){ return __builtin_amdgcn_mfma_f32_16x16x32_fp8_fp8(a,b,c,0,0,0); }
DEVI unsigned pack2_(float a, float b){
    union { bf16 v[2]; unsigned u; } t; t.v[0]=(bf16)a; t.v[1]=(bf16)b; return t.u;
}
DEVI unsigned long long pack4_(float a, float b, float c, float d){
    union { bf16 v[4]; unsigned long long u; } t;
    t.v[0]=(bf16)a; t.v[1]=(bf16)b; t.v[2]=(bf16)c; t.v[3]=(bf16)d; return t.u;
}
DEVI unsigned cvtfp8x4_(float a, float b, float c, float d){
    int v = __builtin_amdgcn_cvt_pk_fp8_f32(a, b, 0, false);
    v = __builtin_amdgcn_cvt_pk_fp8_f32(c, d, v, true);
    return (unsigned)v;
}
DEVI bf16x8 ldb64x2(const bf16* p0, const bf16* p1){
    union { bf16x8 v8; bf16x4 v4[2]; } u;
    u.v4[0] = *(const bf16x4*)p0;
    u.v4[1] = *(const bf16x4*)p1;
    return u.v8;
}

#define B_ 8192
#define F_ 100
#define FP 112
#define H_ 128
#define KC_ 12800   // compact kappa-blocked K: 48*256 + 8*64
#define SPLIT_ 4
#define FP8SC 16.0f

// ---------------- weight prep ----------------
__global__ void k_prepw(const float* __restrict__ qw, const float* __restrict__ qb,
                        const float* __restrict__ kw, const float* __restrict__ kb,
                        const float* __restrict__ tw, const float* __restrict__ tb,
                        const float* __restrict__ a1w,
                        bf16* __restrict__ mextT, float* __restrict__ sigt, float* __restrict__ cconst){
    const float rsc = 0.08838834764831845f;
    int blk = blockIdx.x, tid = threadIdx.x;
    if (blk < 9){
        #pragma unroll 1
        for (int e=0; e<8; ++e){
            int idx = e*256 + tid;
            int n = blk*16 + (idx>>7), h = idx&127;
            float acc = 0.f;
            if (n < 128){
                for (int d=0; d<128; ++d) acc += qw[h*128+d]*kw[n*128+d];
            } else if (n == 128){
                for (int d=0; d<128; ++d) acc += qw[h*128+d]*kb[d];
            } else if (n == 129){
                for (int d=0; d<128; ++d) acc += kw[h*128+d]*qb[d];
            }
            mextT[n*128+h] = (bf16)(acc*rsc);
        }
    } else {
        if (tid < 128){
            float acc = 0.f;
            for (int h=0; h<128; ++h) acc += (tw[h]+tb[h]) * a1w[h*128+tid];
            sigt[tid] = sigmoidf_(acc);
        } else if (tid == 128){
            float acc = 0.f;
            for (int d=0; d<128; ++d) acc += qb[d]*kb[d];
            cconst[0] = acc*rsc;
        }
    }
}

// in [R][C] f32 -> out [C][R] bf16
__global__ void k_transpose_cvt(const float* __restrict__ in, bf16* __restrict__ out, int R, int C){
    __shared__ float t[32][33];
    int c0 = blockIdx.x*32, r0 = blockIdx.y*32;
    int tc = threadIdx.x & 31, tr = threadIdx.x >> 5;
    #pragma unroll
    for (int i=0;i<4;i++){
        int r = tr + i*8;
        t[r][tc] = in[(size_t)(r0+r)*C + c0 + tc];
    }
    __syncthreads();
    #pragma unroll
    for (int i=0;i<4;i++){
        int ro = tr + i*8;
        out[(size_t)(c0+ro)*R + r0 + tc] = (bf16)t[tc][ro];
    }
}

// compact kappa: bijection on [0,12800). In-tile idx = 4*lane + j (lane-linear PV store)
DEVI int kappa_(int k){
    int f = k>>7, h = k&127;
    if (f < 96)
        return (((f>>4)<<3) | (h>>4))*256 + ((f&15)>>2)*64 + (h&15)*4 + (f&3);
    else
        return 12288 + (h>>4)*64 + (h&15)*4 + (f&3);
}
__global__ void k_tc_kappa8(const float* __restrict__ in, unsigned char* __restrict__ out){
    __shared__ float t[32][33];
    const int C = 512;
    int c0 = blockIdx.x*32, r0 = blockIdx.y*32;
    int tc = threadIdx.x & 31, tr = threadIdx.x >> 5;
    #pragma unroll
    for (int i=0;i<4;i++){
        int r = tr + i*8;
        t[r][tc] = in[(size_t)(r0+r)*C + c0 + tc];
    }
    __syncthreads();
    #pragma unroll
    for (int i=0;i<4;i++){
        int ro = tr + i*8;
        float x = t[tc][ro]*FP8SC;
        int v = __builtin_amdgcn_cvt_pk_fp8_f32(x, x, 0, false);
        out[(size_t)(c0+ro)*KC_ + kappa_(r0+tc)] = (unsigned char)v;
    }
}

// ---------------- fused per-batch attention (one block per batch, 4 blocks/CU) ----------------
__global__ __launch_bounds__(256,4) void k_attn2(
    const float* __restrict__ feat, const float* __restrict__ emb,
    const bf16* __restrict__ mextT, const bf16* __restrict__ wa2t,
    const bf16* __restrict__ wvT, const float* __restrict__ vb,
    const float* __restrict__ a2b, const float* __restrict__ a3w,
    const float* __restrict__ sigt_g, const float* __restrict__ cconst,
    unsigned char* __restrict__ xxb, bf16* __restrict__ xtb)
{
    __shared__ char L[40576];
    bf16 (*sNx)[136] = (bf16(*)[136])L;
    bf16 (*sVT)[116] = (bf16(*)[116])L;
    float* sFeat  = (float*)(L+30464);
    float* sNorm  = (float*)(L+30912);
    float* sAtt   = (float*)(L+31424);
    float* sAw    = (float*)(L+31872);
    float* sAlpha = (float*)(L+39680);
    float* sBeta  = (float*)(L+40128);

    int b = blockIdx.x;
    int tid = threadIdx.x, w = tid>>6, lane = tid&63;
    int l15 = lane&15, l4 = lane>>4;
    bf16 (*sP)[72] = (bf16(*)[72])(L + 30464 + w*2304);

    if (tid < FP) sFeat[tid] = (tid<F_) ? feat[(size_t)b*F_+tid] : 0.f;
    __syncthreads();   // B1

    int hA = tid & 127, fpA = tid >> 7;
    float facc = 0.f;
    #pragma unroll 4
    for (int it=0; it<56; ++it){
        int f = fpA + 2*it;
        float v = 0.f;
        if (f < F_) v = sFeat[f] * emb[f*H_ + hA];
        facc += v*v;
        sNx[f][hA] = (bf16)v;
    }
    if (tid >= 128) sNorm[hA] = facc;
    __syncthreads();   // B2
    if (tid < 128) sNorm[hA] = sqrtf(facc + sNorm[hA]);

    const int mts[2] = {w, w+4};   // compile-time-indexed below

    // ---- att path (raw x_rep) ----
    bf16x8 axf[2][4];
    #pragma unroll
    for (int i=0;i<2;i++){
        int mt = mts[i];
        if (mt<7){
            #pragma unroll
            for (int kc=0;kc<4;kc++)
                axf[i][kc] = *(const bf16x8*)(&sNx[mt*16+l15][kc*32+l4*8]);
        }
    }
    float attp[2][4] = {{0,0,0,0},{0,0,0,0}};
    #pragma unroll 2
    for (int nt=0; nt<8; nt++){
        bf16x8 bfr[4];
        #pragma unroll
        for(int kc=0;kc<4;kc++)
            bfr[kc] = *(const bf16x8*)(wa2t + (nt*16+l15)*H_ + kc*32 + l4*8);
        float a2bc = a2b[nt*16+l15], a3c = a3w[nt*16+l15], sgc = sigt_g[nt*16+l15];
        #pragma unroll
        for(int i=0;i<2;i++){
            int mt = mts[i];
            if (mt < 7){
                f32x4 acc = {0.f,0.f,0.f,0.f};
                #pragma unroll
                for(int kc=0;kc<4;kc++) acc = mfma16(axf[i][kc], bfr[kc], acc);
                #pragma unroll
                for(int j=0;j<4;j++){
                    float u = sigmoidf_(acc[j] + a2bc);
                    float t = sgc + u;
                    t = t>0.f ? t : 0.f;
                    attp[i][j] += t * a3c;
                }
            }
        }
    }
    #pragma unroll
    for(int i=0;i<2;i++)
        #pragma unroll
        for(int j=0;j<4;j++){
            float v = attp[i][j];
            #pragma unroll
            for(int m=1;m<16;m<<=1) v += __shfl_xor(v,m,16);
            attp[i][j]=v;
        }
    if (l15==0){
        #pragma unroll
        for(int i=0;i<2;i++){ int mt = mts[i]; if(mt<7){
            #pragma unroll
            for(int j=0;j<4;j++) sAtt[mt*16 + l4*4 + j] = attp[i][j];
        } }
    }
    __syncthreads();   // B3

    if (w==0){
        float a0 = (lane<F_)? sAtt[lane] : -1e30f;
        float a1 = (lane+64<F_)? sAtt[lane+64] : -1e30f;
        float m = fmaxf(a0,a1);
        #pragma unroll
        for(int s=1;s<64;s<<=1) m = fmaxf(m, __shfl_xor(m,s,64));
        float e0 = (lane<F_)? __expf(a0-m):0.f;
        float e1 = (lane+64<F_)? __expf(a1-m):0.f;
        float s = e0+e1;
        #pragma unroll
        for(int t=1;t<64;t<<=1) s += __shfl_xor(s,t,64);
        float inv = 1.f/s;
        if (lane<FP) sAw[lane] = e0*inv;
        if (lane+64<FP) sAw[lane+64] = e1*inv;
    }
    {
        float rn = __builtin_amdgcn_rcpf(sNorm[hA]);
        #pragma unroll 4
        for (int it=0; it<56; ++it){
            int f = fpA + 2*it;
            sNx[f][hA] = (bf16)((float)sNx[f][hA] * rn);
        }
    }
    __syncthreads();   // B4

    bf16x8 afx[2][4];
    #pragma unroll
    for (int i=0;i<2;i++){
        int mt = mts[i];
        if (mt<7){
            #pragma unroll
            for (int kc=0;kc<4;kc++)
                afx[i][kc] = *(const bf16x8*)(&sNx[mt*16+l15][kc*32+l4*8]);
        }
    }
    {
        bf16x8 bfr8[4];
        #pragma unroll
        for (int kc=0;kc<4;kc++)
            bfr8[kc] = *(const bf16x8*)(mextT + (128+l15)*H_ + kc*32 + l4*8);
        #pragma unroll
        for (int i=0;i<2;i++){
            int mt = mts[i];
            if (mt<7){
                f32x4 acc = {0.f,0.f,0.f,0.f};
                #pragma unroll
                for (int kc=0;kc<4;kc++) acc = mfma16(afx[i][kc], bfr8[kc], acc);
                if (l15==0){
                    #pragma unroll
                    for (int j=0;j<4;j++) sAlpha[mt*16+l4*4+j] = acc[j];
                }
                if (l15==1){
                    #pragma unroll
                    for (int j=0;j<4;j++) sBeta[mt*16+l4*4+j] = acc[j];
                }
            }
        }
    }
    if (tid < 128){
        int h=tid; float acc=0.f;
        #pragma unroll 4
        for(int f=0;f<F_;f++) acc += sAw[f]*(float)sNx[f][h];
        xtb[(size_t)b*H_ + h] = (bf16)(acc * sNorm[h]);
    }
    __syncthreads();   // B5

    // ---- S1 + scores + P.  FULL unroll over i: all uex/inv_ indices static -> registers.
    const float cc = cconst[0];
    unsigned uex[2][7][2];
    float inv_[2][4];
    #pragma unroll
    for (int i=0;i<2;i++){
        int mt = mts[i];
        if (mt < 7){
            f32x4 sc[7];
            #pragma unroll
            for (int gt=0; gt<7; gt++) sc[gt] = (f32x4){0.f,0.f,0.f,0.f};
            #pragma unroll 1
            for (int p=0; p<2; p++){
                #pragma unroll 2
                for (int nt4=0; nt4<4; nt4++){
                    int nt = p*4 + nt4;
                    bf16x8 bw[4];
                    #pragma unroll
                    for (int kc=0;kc<4;kc++)
                        bw[kc] = *(const bf16x8*)(mextT + (nt*16+l15)*H_ + kc*32 + l4*8);
                    f32x4 d = {0.f,0.f,0.f,0.f};
                    #pragma unroll
                    for (int kc=0;kc<4;kc++) d = mfma16(afx[i][kc], bw[kc], d);
                    #pragma unroll
                    for (int j=0;j<4;j++) sP[l4*4+j][nt4*16+l15] = (bf16)d[j];
                }
                bf16x8 afs0 = *(const bf16x8*)&sP[l15][l4*8];
                bf16x8 afs1 = *(const bf16x8*)&sP[l15][32+l4*8];
                #pragma unroll
                for (int gt=0; gt<7; gt++){
                    bf16x8 b0 = *(const bf16x8*)&sNx[gt*16+l15][p*64 + l4*8];
                    bf16x8 b1 = *(const bf16x8*)&sNx[gt*16+l15][p*64 + 32 + l4*8];
                    sc[gt] = mfma16(afs0, b0, sc[gt]);
                    sc[gt] = mfma16(afs1, b1, sc[gt]);
                }
            }
            float aj[4];
            #pragma unroll
            for (int j=0;j<4;j++) aj[j] = sAlpha[mt*16+l4*4+j];
            float rs[4] = {0.f,0.f,0.f,0.f};
            #pragma unroll
            for (int gt=0; gt<7; gt++){
                float bg = sBeta[gt*16+l15];
                int g = gt*16+l15;
                float e[4];
                #pragma unroll
                for (int j=0;j<4;j++){
                    float val = sc[gt][j] + aj[j] + bg + cc;
                    e[j] = (g<F_) ? __expf(sigmoidf_(val)) : 0.f;
                    rs[j] += e[j];
                }
                uex[i][gt][0] = pack2_(e[0],e[1]);
                uex[i][gt][1] = pack2_(e[2],e[3]);
            }
            #pragma unroll
            for (int j=0;j<4;j++){
                float v = rs[j];
                #pragma unroll
                for (int m2=1;m2<16;m2<<=1) v += __shfl_xor(v,m2,16);
                inv_[i][j] = 1.f/v;
            }
        }
    }

    union UP { unsigned u; bf16 v[2]; };
    // stage P0 pass-A (g 0..63)
    if (mts[0] < 7){
        #pragma unroll
        for (int gt=0; gt<4; gt++){
            #pragma unroll
            for (int j2=0; j2<2; j2++){
                UP u; u.u = uex[0][gt][j2];
                sP[l4*4+j2*2  ][gt*16+l15] = (bf16)((float)u.v[0] * inv_[0][j2*2  ]);
                sP[l4*4+j2*2+1][gt*16+l15] = (bf16)((float)u.v[1] * inv_[0][j2*2+1]);
            }
        }
    }

    // ---- V^T = wvT x nx: FULL unroll over i2; pack (v+vb) to bf16 pairs (static regs) ----
    unsigned vpk[2][7][2];
    #pragma unroll
    for (int i2=0;i2<2;i2++){
        int ht = w + 4*i2;
        bf16x8 awv[4];
        #pragma unroll
        for (int kc=0;kc<4;kc++)
            awv[kc] = *(const bf16x8*)(wvT + (ht*16+l15)*H_ + kc*32 + l4*8);
        float vb0 = vb[ht*16+l4*4], vb1 = vb[ht*16+l4*4+1], vb2 = vb[ht*16+l4*4+2], vb3 = vb[ht*16+l4*4+3];
        #pragma unroll
        for (int gt=0; gt<7; gt++){
            f32x4 acc = {0.f,0.f,0.f,0.f};
            #pragma unroll
            for (int kc=0;kc<4;kc++){
                bf16x8 bfr = *(const bf16x8*)(&sNx[gt*16+l15][kc*32+l4*8]);
                acc = mfma16(awv[kc], bfr, acc);
            }
            vpk[i2][gt][0] = pack2_(acc[0]+vb0, acc[1]+vb1);
            vpk[i2][gt][1] = pack2_(acc[2]+vb2, acc[3]+vb3);
        }
    }
    __syncthreads();   // B6: all sNx reads complete

    #pragma unroll
    for (int i2=0;i2<2;i2++){
        int ht = w + 4*i2;
        #pragma unroll
        for (int gt=0; gt<7; gt++){
            UP u0, u1;
            u0.u = vpk[i2][gt][0]; u1.u = vpk[i2][gt][1];
            sVT[ht*16+l4*4  ][gt*16+l15] = u0.v[0];
            sVT[ht*16+l4*4+1][gt*16+l15] = u0.v[1];
            sVT[ht*16+l4*4+2][gt*16+l15] = u1.v[0];
            sVT[ht*16+l4*4+3][gt*16+l15] = u1.v[1];
        }
    }
    __syncthreads();   // B7

    // ---- PV: FULL unroll over i ----
    #pragma unroll
    for (int i=0;i<2;i++){
        int mt = mts[i];
        if (mt >= 7) continue;
        if (i==1){
            #pragma unroll
            for (int gt=0; gt<4; gt++){
                #pragma unroll
                for (int j2=0; j2<2; j2++){
                    UP u; u.u = uex[1][gt][j2];
                    sP[l4*4+j2*2  ][gt*16+l15] = (bf16)((float)u.v[0] * inv_[1][j2*2  ]);
                    sP[l4*4+j2*2+1][gt*16+l15] = (bf16)((float)u.v[1] * inv_[1][j2*2+1]);
                }
            }
        }
        bf16x8 ap0 = *(const bf16x8*)&sP[l15][l4*8];
        bf16x8 ap1 = *(const bf16x8*)&sP[l15][32+l4*8];
        f32x4 acc[8];
        #pragma unroll
        for (int ht=0;ht<8;ht++) acc[ht] = (f32x4){0.f,0.f,0.f,0.f};
        #pragma unroll
        for (int ht=0; ht<8; ht++){
            const bf16* vr = &sVT[ht*16+l15][0];
            int c0 = l4*8, c1 = 32+l4*8;
            acc[ht] = mfma16(ap0, ldb64x2(vr+c0, vr+c0+4), acc[ht]);
            acc[ht] = mfma16(ap1, ldb64x2(vr+c1, vr+c1+4), acc[ht]);
        }
        #pragma unroll
        for (int gt=4; gt<7; gt++){
            #pragma unroll
            for (int j2=0; j2<2; j2++){
                UP u; u.u = uex[i][gt][j2];
                sP[l4*4+j2*2  ][(gt-4)*16+l15] = (bf16)((float)u.v[0] * inv_[i][j2*2  ]);
                sP[l4*4+j2*2+1][(gt-4)*16+l15] = (bf16)((float)u.v[1] * inv_[i][j2*2+1]);
            }
        }
        #pragma unroll
        for (int j=0;j<4;j++) sP[l4*4+j][48+l15] = (bf16)0.f;
        bf16x8 ap2 = *(const bf16x8*)&sP[l15][l4*8];
        bf16x8 ap3 = *(const bf16x8*)&sP[l15][32+l4*8];
        #pragma unroll
        for (int ht=0; ht<8; ht++){
            const bf16* vr = &sVT[ht*16+l15][0];
            int c2 = 64+l4*8;  if (c2 >= 112) c2 = 96;
            int c3 = 96+l4*8;  if (c3 >= 112) c3 = 96;
            acc[ht] = mfma16(ap2, ldb64x2(vr+c2, vr+c2+4), acc[ht]);
            acc[ht] = mfma16(ap3, ldb64x2(vr+c3, vr+c3+4), acc[ht]);
        }
        if (mt < 6){
            #pragma unroll
            for (int ht=0; ht<8; ht++){
                unsigned u = cvtfp8x4_(acc[ht][0]*FP8SC, acc[ht][1]*FP8SC, acc[ht][2]*FP8SC, acc[ht][3]*FP8SC);
                *(unsigned*)(xxb + (size_t)b*KC_ + (mt*8+ht)*256 + lane*4) = u;
            }
        } else if (l4 == 0){
            #pragma unroll
            for (int ht=0; ht<8; ht++){
                unsigned u = cvtfp8x4_(acc[ht][0]*FP8SC, acc[ht][1]*FP8SC, acc[ht][2]*FP8SC, acc[ht][3]*FP8SC);
                *(unsigned*)(xxb + (size_t)b*KC_ + 12288 + ht*64 + l15*4) = u;
            }
        }
    }
}

// ---------------- fp8 split-K GEMM ----------------
__global__ __launch_bounds__(256,4) void k_gemm_fp8(const unsigned char* __restrict__ A,
        const unsigned char* __restrict__ Bt, float* __restrict__ part, int M, int N, int K, int KS)
{
    __shared__ unsigned char sA[128][72];
    __shared__ unsigned char sB[128][72];
    int tid=threadIdx.x, w=tid>>6, lane=tid&63, l15=lane&15, l4=lane>>4;
    int m0 = blockIdx.y*128, n0 = blockIdx.x*128;
    int kbeg = blockIdx.z*KS, kend = kbeg + KS;
    int wr = w>>1, wc = w&1;
    f32x4 acc[4][4];
    #pragma unroll
    for(int mi=0;mi<4;mi++)
        #pragma unroll
        for(int ni=0;ni<4;ni++) acc[mi][ni] = (f32x4){0.f,0.f,0.f,0.f};

    for (int k0=kbeg; k0<kend; k0+=64){
        __syncthreads();
        #pragma unroll
        for (int t2=0;t2<2;t2++){
            int t = tid + t2*256;
            int row=t>>2, col=(t&3)*16;
            *(u32x4*)&sA[row][col] = *(const u32x4*)(A + (size_t)(m0+row)*K + k0 + col);
            *(u32x4*)&sB[row][col] = *(const u32x4*)(Bt + (size_t)(n0+row)*K + k0 + col);
        }
        __syncthreads();
        #pragma unroll
        for(int ks=0;ks<2;ks++){
            long af[4], bfr[4];
            #pragma unroll
            for(int mi=0;mi<4;mi++) af[mi] = *(const long*)&sA[wr*64+mi*16+l15][ks*32+l4*8];
            #pragma unroll
            for(int ni=0;ni<4;ni++) bfr[ni] = *(const long*)&sB[wc*64+ni*16+l15][ks*32+l4*8];
            #pragma unroll
            for(int mi=0;mi<4;mi++)
                #pragma unroll
                for(int ni=0;ni<4;ni++)
                    acc[mi][ni] = mfma8(af[mi], bfr[ni], acc[mi][ni]);
        }
    }
    float* pz = part + (size_t)blockIdx.z*M*N;
    #pragma unroll
    for(int mi=0;mi<4;mi++)
        #pragma unroll
        for(int ni=0;ni<4;ni++){
            int col = n0 + wc*64 + ni*16 + l15;
            #pragma unroll
            for(int j=0;j<4;j++){
                int row = m0 + wr*64 + mi*16 + l4*4 + j;
                pz[(size_t)row*N + col] = acc[mi][ni][j];
            }
        }
}

__global__ void k_c1fin(const float* __restrict__ part, const float* __restrict__ bias,
                        bf16* __restrict__ out){
    const size_t MN = (size_t)B_*512;
    size_t e0 = ((size_t)blockIdx.x*256 + threadIdx.x)*4;
    f32x4 s = *(const f32x4*)(part + e0);
    s += *(const f32x4*)(part + MN + e0);
    s += *(const f32x4*)(part + 2*MN + e0);
    s += *(const f32x4*)(part + 3*MN + e0);
    f32x4 bb = *(const f32x4*)(bias + (e0 & 511));
    const float ds = 1.0f/(FP8SC*FP8SC);
    unsigned long long u = pack4_(eluf_(s[0]*ds+bb[0]), eluf_(s[1]*ds+bb[1]),
                                  eluf_(s[2]*ds+bb[2]), eluf_(s[3]*ds+bb[3]));
    *(unsigned long long*)(out + e0) = u;
}

// ---------------- generic tiled GEMM ----------------
template<int BN, bool ELU>
__global__ __launch_bounds__(256,2) void k_gemm(const bf16* __restrict__ A, const bf16* __restrict__ Bt,
        const float* __restrict__ bias, bf16* __restrict__ out, int M, int N, int K)
{
    __shared__ bf16 sAt[128][72];
    __shared__ bf16 sBt[BN][72];
    int tid=threadIdx.x, w=tid>>6, lane=tid&63, l15=lane&15, l4=lane>>4;
    int m0 = blockIdx.y*128, n0 = blockIdx.x*BN;
    constexpr int MI = (BN==128)?4:2;
    constexpr int NI = (BN==128)?4:BN/16;
    int wr = (BN==128)? (w>>1) : w;
    int wc = (BN==128)? (w&1) : 0;
    f32x4 acc[MI][NI];
    #pragma unroll
    for(int mi=0;mi<MI;mi++)
        #pragma unroll
        for(int ni=0;ni<NI;ni++) acc[mi][ni] = (f32x4){0.f,0.f,0.f,0.f};

    for (int k0=0; k0<K; k0+=64){
        __syncthreads();
        for (int t=tid; t<128*8; t+=256){
            int row=t>>3, col=(t&7)*8;
            *(bf16x8*)&sAt[row][col] = *(const bf16x8*)(A + (size_t)(m0+row)*K + k0 + col);
        }
        for (int t=tid; t<BN*8; t+=256){
            int row=t>>3, col=(t&7)*8;
            *(bf16x8*)&sBt[row][col] = *(const bf16x8*)(Bt + (size_t)(n0+row)*K + k0 + col);
        }
        __syncthreads();
        #pragma unroll
        for(int ks=0;ks<2;ks++){
            bf16x8 af[MI], bfr[NI];
            #pragma unroll
            for(int mi=0;mi<MI;mi++) af[mi] = *(const bf16x8*)&sAt[wr*(MI*16)+mi*16+l15][ks*32+l4*8];
            #pragma unroll
            for(int ni=0;ni<NI;ni++) bfr[ni] = *(const bf16x8*)&sBt[wc*64+ni*16+l15][ks*32+l4*8];
            #pragma unroll
            for(int mi=0;mi<MI;mi++)
                #pragma unroll
                for(int ni=0;ni<NI;ni++)
                    acc[mi][ni] = mfma16(af[mi], bfr[ni], acc[mi][ni]);
        }
    }
    #pragma unroll
    for(int mi=0;mi<MI;mi++)
        #pragma unroll
        for(int ni=0;ni<NI;ni++){
            int col = n0 + wc*64 + ni*16 + l15;
            float bc = bias[col];
            #pragma unroll
            for(int j=0;j<4;j++){
                int row = m0 + wr*(MI*16) + mi*16 + l4*4 + j;
                float v = acc[mi][ni][j] + bc;
                if (ELU) v = eluf_(v);
                out[(size_t)row*N + col] = (bf16)v;
            }
        }
}

// ---------------- control heads ----------------
__global__ void k_heads(const bf16* __restrict__ c5o, const float* __restrict__ clw, const float* __restrict__ clb,
                        const float* __restrict__ ctw, const float* __restrict__ ctb, float* __restrict__ outp){
    int gid = blockIdx.x*4 + (threadIdx.x>>6);
    int lane = threadIdx.x & 63;
    float v = (float)c5o[(size_t)gid*64 + lane];
    float r1 = v*clw[lane], r2 = v*ctw[lane];
    #pragma unroll
    for(int m=1;m<64;m<<=1){ r1 += __shfl_xor(r1,m,64); r2 += __shfl_xor(r2,m,64); }
    if (lane==0){
        float cl = r1 + clb[0];
        outp[gid] = cl;
        outp[B_ + gid] = sigmoidf_(cl);
        outp[(size_t)2*B_ + gid] = r2 + ctb[0];
    }
}

// ---------------- uplift tail ----------------
__global__ void k_utail(const bf16* __restrict__ u3o, const float* __restrict__ u4w, const float* __restrict__ u4b,
                        const float* __restrict__ tlw, const float* __restrict__ tlb,
                        const float* __restrict__ utw, const float* __restrict__ utb, float* __restrict__ outp){
    int row = blockIdx.x*4 + (threadIdx.x>>6);
    int lane = threadIdx.x & 63;
    int j = lane & 15;
    float acc = u4b[j];
    #pragma unroll 4
    for (int h=0; h<32; ++h) acc += (float)u3o[(size_t)row*32+h] * u4w[h*16+j];
    float u4 = eluf_(acc);
    float r1 = u4*tlw[j], r2 = u4*utw[j];
    #pragma unroll
    for(int m=1;m<16;m<<=1){ r1 += __shfl_xor(r1,m,16); r2 += __shfl_xor(r2,m,16); }
    if (lane==0){
        float tl = r1 + tlb[0];
        outp[(size_t)3*B_ + row] = tl;
        outp[(size_t)4*B_ + row] = sigmoidf_(tl);
        outp[(size_t)5*B_ + row] = r2 + utb[0];
    }
}

extern "C" void kernel_launch(void* const* d_in, const int* in_sizes, int n_in,
                              void* d_out, int out_size, void* d_ws, size_t ws_size,
                              hipStream_t stream) {
    const float* feat=(const float*)d_in[0];
    const float* emb =(const float*)d_in[2];
    const float* t_w =(const float*)d_in[3]; const float* t_b=(const float*)d_in[4];
    const float* qw  =(const float*)d_in[5]; const float* qb =(const float*)d_in[6];
    const float* kw  =(const float*)d_in[7]; const float* kb =(const float*)d_in[8];
    const float* vw  =(const float*)d_in[9]; const float* vb =(const float*)d_in[10];
    const float* a1w =(const float*)d_in[11];
    const float* a2w =(const float*)d_in[12]; const float* a2b=(const float*)d_in[13];
    const float* a3w =(const float*)d_in[14];
    const float* c1w =(const float*)d_in[15]; const float* c1b=(const float*)d_in[16];
    const float* c2w =(const float*)d_in[17]; const float* c2b=(const float*)d_in[18];
    const float* c3w =(const float*)d_in[19]; const float* c3b=(const float*)d_in[20];
    const float* c4w =(const float*)d_in[21]; const float* c4b=(const float*)d_in[22];
    const float* c5w =(const float*)d_in[23]; const float* c5b=(const float*)d_in[24];
    const float* clw =(const float*)d_in[25]; const float* clb=(const float*)d_in[26];
    const float* ctw =(const float*)d_in[27]; const float* ctb=(const float*)d_in[28];
    const float* u1w =(const float*)d_in[29]; const float* u1b=(const float*)d_in[30];
    const float* u2w =(const float*)d_in[31]; const float* u2b=(const float*)d_in[32];
    const float* u3w =(const float*)d_in[33]; const float* u3b=(const float*)d_in[34];
    const float* u4w =(const float*)d_in[35]; const float* u4b=(const float*)d_in[36];
    const float* tlw =(const float*)d_in[37]; const float* tlb=(const float*)d_in[38];
    const float* utw =(const float*)d_in[39]; const float* utb=(const float*)d_in[40];
    float* outp = (float*)d_out;

    char* ws = (char*)d_ws;
    size_t off = 0;
    auto alloc = [&](size_t bytes)->char*{ char* p = ws + off; off += (bytes + 255) & ~(size_t)255; return p; };
    unsigned char* xxb = (unsigned char*)alloc((size_t)B_*KC_);          // 104.9 MB fp8
    float* part  = (float*)alloc((size_t)SPLIT_*B_*512*4);               // 67.1 MB
    bf16* xtb    = (bf16*)alloc((size_t)B_*128*2);
    bf16* cbuf1  = (bf16*)alloc((size_t)B_*512*2);
    bf16* mextT  = (bf16*)alloc(144*128*2);
    bf16* wvT    = (bf16*)alloc(128*128*2);
    bf16* wa2t   = (bf16*)alloc(128*128*2);
    unsigned char* c1wtk8 = (unsigned char*)alloc((size_t)512*KC_);
    bf16* c2wt   = (bf16*)alloc((size_t)512*512*2);
    bf16* c3wt   = (bf16*)alloc((size_t)512*256*2);
    bf16* c4wt   = (bf16*)alloc((size_t)256*128*2);
    bf16* c5wt   = (bf16*)alloc((size_t)128*64*2);
    bf16* u1t    = (bf16*)alloc(128*128*2);
    bf16* u2t    = (bf16*)alloc(64*128*2);
    bf16* u3t    = (bf16*)alloc(32*64*2);
    float* sigt  = (float*)alloc(128*4);
    float* cconst= (float*)alloc(4);
    bf16* cbuf2 = (bf16*)(xxb);
    bf16* cbuf3 = (bf16*)(xxb + (16u<<20));
    bf16* cbuf4 = (bf16*)(xxb + (32u<<20));
    bf16* cbuf5 = (bf16*)(xxb + (48u<<20));
    bf16* ubuf1 = (bf16*)(xxb + (64u<<20));
    bf16* ubuf2 = (bf16*)(xxb + (80u<<20));
    bf16* ubuf3 = (bf16*)(xxb + (96u<<20));
    (void)ws_size; (void)in_sizes; (void)n_in; (void)out_size;

    k_prepw<<<10,256,0,stream>>>(qw,qb,kw,kb,t_w,t_b,a1w,mextT,sigt,cconst);
    k_transpose_cvt<<<dim3(4,4),256,0,stream>>>(vw,  wvT, 128,128);
    k_transpose_cvt<<<dim3(4,4),256,0,stream>>>(a2w, wa2t,128,128);
    k_tc_kappa8<<<dim3(16,400),256,0,stream>>>(c1w, c1wtk8);
    k_transpose_cvt<<<dim3(16,16),256,0,stream>>>(c2w, c2wt, 512,512);
    k_transpose_cvt<<<dim3(8,16),256,0,stream>>>(c3w, c3wt, 512,256);
    k_transpose_cvt<<<dim3(4,8),256,0,stream>>>(c4w, c4wt, 256,128);
    k_transpose_cvt<<<dim3(2,4),256,0,stream>>>(c5w, c5wt, 128,64);
    k_transpose_cvt<<<dim3(4,4),256,0,stream>>>(u1w, u1t, 128,128);
    k_transpose_cvt<<<dim3(2,4),256,0,stream>>>(u2w, u2t, 128,64);
    k_transpose_cvt<<<dim3(1,2),256,0,stream>>>(u3w, u3t, 64,32);

    k_attn2<<<B_,256,0,stream>>>(feat,emb,mextT,wa2t,wvT,vb,a2b,a3w,sigt,cconst, xxb, xtb);

    k_gemm_fp8<<<dim3(4,64,SPLIT_),256,0,stream>>>(xxb, c1wtk8, part, B_,512,KC_, KC_/SPLIT_);
    k_c1fin<<<4096,256,0,stream>>>(part, c1b, cbuf1);

    k_gemm<128,true><<<dim3(4,64),256,0,stream>>>(cbuf1, c2wt, c2b, cbuf2, B_,512,512);
    k_gemm<128,true><<<dim3(2,64),256,0,stream>>>(cbuf2, c3wt, c3b, cbuf3, B_,256,512);
    k_gemm<128,true><<<dim3(1,64),256,0,stream>>>(cbuf3, c4wt, c4b, cbuf4, B_,128,256);
    k_gemm<64, true><<<dim3(1,64),256,0,stream>>>(cbuf4, c5wt, c5b, cbuf5, B_,64,128);
    k_heads<<<2048,256,0,stream>>>(cbuf5,clw,clb,ctw,ctb,outp);

    k_gemm<128,true><<<dim3(1,64),256,0,stream>>>(xtb,   u1t, u1b, ubuf1, B_,128,128);
    k_gemm<64, true><<<dim3(1,64),256,0,stream>>>(ubuf1, u2t, u2b, ubuf2, B_,64,128);
    k_gemm<32, true><<<dim3(1,64),256,0,stream>>>(ubuf2, u3t, u3b, ubuf3, B_,32,64);
    k_utail<<<2048,256,0,stream>>>(ubuf3,u4w,u4b,tlw,tlb,utw,utb,outp);
}

// Round 8
// 913.969 us; speedup vs baseline: 2.3189x; 1.0695x over previous
//
#include <hip/hip_runtime.h>
#include <hip/hip_bf16.h>

typedef __bf16 bf16;
typedef __bf16 bf16x8 __attribute__((ext_vector_type(8)));
typedef __bf16 bf16x4 __attribute__((ext_vector_type(4)));
typedef float f32x4 __attribute__((ext_vector_type(4)));
typedef unsigned u32x4 __attribute__((ext_vector_type(4)));

#define DEVI static __device__ __forceinline__

DEVI float sigmoidf_(float x){ return 1.0f/(1.0f+__expf(-x)); }
DEVI float eluf_(float x){ return x>0.f ? x : (__expf(x)-1.f); }
DEVI f32x4 mfma16(bf16x8 a, bf16x8 b, f32x4 c){ return __builtin_amdgcn_mfma_f32_16x16x32_bf16(a,b,c,0,0,0); }
DEVI f32x4 mfma8(long a, long b, f32x4 c){ return __builtin_amdgcn_mfma_f32_16x16x32_fp8_fp8(a,b,c,0,0,0); }
DEVI unsigned pack2_(float a, float b){
    union { bf16 v[2]; unsigned u; } t; t.v[0]=(bf16)a; t.v[1]=(bf16)b; return t.u;
}
DEVI unsigned long long pack4_(float a, float b, float c, float d){
    union { bf16 v[4]; unsigned long long u; } t;
    t.v[0]=(bf16)a; t.v[1]=(bf16)b; t.v[2]=(bf16)c; t.v[3]=(bf16)d; return t.u;
}
DEVI unsigned cvtfp8x4_(float a, float b, float c, float d){
    int v = __builtin_amdgcn_cvt_pk_fp8_f32(a, b, 0, false);
    v = __builtin_amdgcn_cvt_pk_fp8_f32(c, d, v, true);
    return (unsigned)v;
}
DEVI bf16x8 ldb64x2(const bf16* p0, const bf16* p1){
    union { bf16x8 v8; bf16x4 v4[2]; } u;
    u.v4[0] = *(const bf16x4*)p0;
    u.v4[1] = *(const bf16x4*)p1;
    return u.v8;
}

#define B_ 8192
#define F_ 100
#define FP 112
#define H_ 128
#define KC_ 12800   // compact kappa-blocked K: 48*256 + 8*64
#define SPLIT_ 4
#define FP8SC 16.0f

// ---------------- weight prep ----------------
__global__ void k_prepw(const float* __restrict__ qw, const float* __restrict__ qb,
                        const float* __restrict__ kw, const float* __restrict__ kb,
                        const float* __restrict__ tw, const float* __restrict__ tb,
                        const float* __restrict__ a1w,
                        bf16* __restrict__ mextT, float* __restrict__ sigt, float* __restrict__ cconst){
    const float rsc = 0.08838834764831845f;
    int blk = blockIdx.x, tid = threadIdx.x;
    if (blk < 9){
        #pragma unroll 1
        for (int e=0; e<8; ++e){
            int idx = e*256 + tid;
            int n = blk*16 + (idx>>7), h = idx&127;
            float acc = 0.f;
            if (n < 128){
                for (int d=0; d<128; ++d) acc += qw[h*128+d]*kw[n*128+d];
            } else if (n == 128){
                for (int d=0; d<128; ++d) acc += qw[h*128+d]*kb[d];
            } else if (n == 129){
                for (int d=0; d<128; ++d) acc += kw[h*128+d]*qb[d];
            }
            mextT[n*128+h] = (bf16)(acc*rsc);
        }
    } else {
        if (tid < 128){
            float acc = 0.f;
            for (int h=0; h<128; ++h) acc += (tw[h]+tb[h]) * a1w[h*128+tid];
            sigt[tid] = sigmoidf_(acc);
        } else if (tid == 128){
            float acc = 0.f;
            for (int d=0; d<128; ++d) acc += qb[d]*kb[d];
            cconst[0] = acc*rsc;
        }
    }
}

// in [R][C] f32 -> out [C][R] bf16
__global__ void k_transpose_cvt(const float* __restrict__ in, bf16* __restrict__ out, int R, int C){
    __shared__ float t[32][33];
    int c0 = blockIdx.x*32, r0 = blockIdx.y*32;
    int tc = threadIdx.x & 31, tr = threadIdx.x >> 5;
    #pragma unroll
    for (int i=0;i<4;i++){
        int r = tr + i*8;
        t[r][tc] = in[(size_t)(r0+r)*C + c0 + tc];
    }
    __syncthreads();
    #pragma unroll
    for (int i=0;i<4;i++){
        int ro = tr + i*8;
        out[(size_t)(c0+ro)*R + r0 + tc] = (bf16)t[tc][ro];
    }
}

// compact kappa: bijection on [0,12800). In-tile idx = 4*lane + j (lane-linear PV store)
DEVI int kappa_(int k){
    int f = k>>7, h = k&127;
    if (f < 96)
        return (((f>>4)<<3) | (h>>4))*256 + ((f&15)>>2)*64 + (h&15)*4 + (f&3);
    else
        return 12288 + (h>>4)*64 + (h&15)*4 + (f&3);
}
__global__ void k_tc_kappa8(const float* __restrict__ in, unsigned char* __restrict__ out){
    __shared__ float t[32][33];
    const int C = 512;
    int c0 = blockIdx.x*32, r0 = blockIdx.y*32;
    int tc = threadIdx.x & 31, tr = threadIdx.x >> 5;
    #pragma unroll
    for (int i=0;i<4;i++){
        int r = tr + i*8;
        t[r][tc] = in[(size_t)(r0+r)*C + c0 + tc];
    }
    __syncthreads();
    #pragma unroll
    for (int i=0;i<4;i++){
        int ro = tr + i*8;
        float x = t[tc][ro]*FP8SC;
        int v = __builtin_amdgcn_cvt_pk_fp8_f32(x, x, 0, false);
        out[(size_t)(c0+ro)*KC_ + kappa_(r0+tc)] = (unsigned char)v;
    }
}

// ---------------- fused per-batch attention (one block per batch, 4 blocks/CU via LDS) ----------------
// launch_bounds(256,2): min 2 waves/EU -> compiler VGPR budget ~128 (empirical: budget = 512/(2*min)).
// LDS 40960 still caps at 4 blocks/CU; <=128 VGPR also admits 4 waves/EU, so occupancy unchanged.
__global__ __launch_bounds__(256,2) void k_attn2(
    const float* __restrict__ feat, const float* __restrict__ emb,
    const bf16* __restrict__ mextT, const bf16* __restrict__ wa2t,
    const bf16* __restrict__ wvT, const float* __restrict__ vb,
    const float* __restrict__ a2b, const float* __restrict__ a3w,
    const float* __restrict__ sigt_g, const float* __restrict__ cconst,
    unsigned char* __restrict__ xxb, bf16* __restrict__ xtb)
{
    __shared__ char L[40576];
    bf16 (*sNx)[136] = (bf16(*)[136])L;
    bf16 (*sVT)[116] = (bf16(*)[116])L;
    float* sFeat  = (float*)(L+30464);
    float* sNorm  = (float*)(L+30912);
    float* sAtt   = (float*)(L+31424);
    float* sAw    = (float*)(L+31872);
    float* sAlpha = (float*)(L+39680);
    float* sBeta  = (float*)(L+40128);

    int b = blockIdx.x;
    int tid = threadIdx.x, w = tid>>6, lane = tid&63;
    int l15 = lane&15, l4 = lane>>4;
    bf16 (*sP)[72] = (bf16(*)[72])(L + 30464 + w*2304);

    if (tid < FP) sFeat[tid] = (tid<F_) ? feat[(size_t)b*F_+tid] : 0.f;
    __syncthreads();   // B1

    int hA = tid & 127, fpA = tid >> 7;
    float facc = 0.f;
    #pragma unroll 4
    for (int it=0; it<56; ++it){
        int f = fpA + 2*it;
        float v = 0.f;
        if (f < F_) v = sFeat[f] * emb[f*H_ + hA];
        facc += v*v;
        sNx[f][hA] = (bf16)v;
    }
    if (tid >= 128) sNorm[hA] = facc;
    __syncthreads();   // B2
    if (tid < 128) sNorm[hA] = sqrtf(facc + sNorm[hA]);

    const int mts[2] = {w, w+4};

    // ---- att path (raw x_rep) ----
    bf16x8 axf[2][4];
    #pragma unroll
    for (int i=0;i<2;i++){
        int mt = mts[i];
        if (mt<7){
            #pragma unroll
            for (int kc=0;kc<4;kc++)
                axf[i][kc] = *(const bf16x8*)(&sNx[mt*16+l15][kc*32+l4*8]);
        }
    }
    float attp[2][4] = {{0,0,0,0},{0,0,0,0}};
    #pragma unroll 2
    for (int nt=0; nt<8; nt++){
        bf16x8 bfr[4];
        #pragma unroll
        for(int kc=0;kc<4;kc++)
            bfr[kc] = *(const bf16x8*)(wa2t + (nt*16+l15)*H_ + kc*32 + l4*8);
        float a2bc = a2b[nt*16+l15], a3c = a3w[nt*16+l15], sgc = sigt_g[nt*16+l15];
        #pragma unroll
        for(int i=0;i<2;i++){
            int mt = mts[i];
            if (mt < 7){
                f32x4 acc = {0.f,0.f,0.f,0.f};
                #pragma unroll
                for(int kc=0;kc<4;kc++) acc = mfma16(axf[i][kc], bfr[kc], acc);
                #pragma unroll
                for(int j=0;j<4;j++){
                    float u = sigmoidf_(acc[j] + a2bc);
                    float t = sgc + u;
                    t = t>0.f ? t : 0.f;
                    attp[i][j] += t * a3c;
                }
            }
        }
    }
    #pragma unroll
    for(int i=0;i<2;i++)
        #pragma unroll
        for(int j=0;j<4;j++){
            float v = attp[i][j];
            #pragma unroll
            for(int m=1;m<16;m<<=1) v += __shfl_xor(v,m,16);
            attp[i][j]=v;
        }
    if (l15==0){
        #pragma unroll
        for(int i=0;i<2;i++){ int mt = mts[i]; if(mt<7){
            #pragma unroll
            for(int j=0;j<4;j++) sAtt[mt*16 + l4*4 + j] = attp[i][j];
        } }
    }
    __syncthreads();   // B3

    if (w==0){
        float a0 = (lane<F_)? sAtt[lane] : -1e30f;
        float a1 = (lane+64<F_)? sAtt[lane+64] : -1e30f;
        float m = fmaxf(a0,a1);
        #pragma unroll
        for(int s=1;s<64;s<<=1) m = fmaxf(m, __shfl_xor(m,s,64));
        float e0 = (lane<F_)? __expf(a0-m):0.f;
        float e1 = (lane+64<F_)? __expf(a1-m):0.f;
        float s = e0+e1;
        #pragma unroll
        for(int t=1;t<64;t<<=1) s += __shfl_xor(s,t,64);
        float inv = 1.f/s;
        if (lane<FP) sAw[lane] = e0*inv;
        if (lane+64<FP) sAw[lane+64] = e1*inv;
    }
    {
        float rn = __builtin_amdgcn_rcpf(sNorm[hA]);
        #pragma unroll 4
        for (int it=0; it<56; ++it){
            int f = fpA + 2*it;
            sNx[f][hA] = (bf16)((float)sNx[f][hA] * rn);
        }
    }
    __syncthreads();   // B4

    bf16x8 afx[2][4];
    #pragma unroll
    for (int i=0;i<2;i++){
        int mt = mts[i];
        if (mt<7){
            #pragma unroll
            for (int kc=0;kc<4;kc++)
                afx[i][kc] = *(const bf16x8*)(&sNx[mt*16+l15][kc*32+l4*8]);
        }
    }
    {
        bf16x8 bfr8[4];
        #pragma unroll
        for (int kc=0;kc<4;kc++)
            bfr8[kc] = *(const bf16x8*)(mextT + (128+l15)*H_ + kc*32 + l4*8);
        #pragma unroll
        for (int i=0;i<2;i++){
            int mt = mts[i];
            if (mt<7){
                f32x4 acc = {0.f,0.f,0.f,0.f};
                #pragma unroll
                for (int kc=0;kc<4;kc++) acc = mfma16(afx[i][kc], bfr8[kc], acc);
                if (l15==0){
                    #pragma unroll
                    for (int j=0;j<4;j++) sAlpha[mt*16+l4*4+j] = acc[j];
                }
                if (l15==1){
                    #pragma unroll
                    for (int j=0;j<4;j++) sBeta[mt*16+l4*4+j] = acc[j];
                }
            }
        }
    }
    if (tid < 128){
        int h=tid; float acc=0.f;
        #pragma unroll 4
        for(int f=0;f<F_;f++) acc += sAw[f]*(float)sNx[f][h];
        xtb[(size_t)b*H_ + h] = (bf16)(acc * sNorm[h]);
    }
    __syncthreads();   // B5

    // ---- S1 + scores + P ----
    const float cc = cconst[0];
    unsigned uex[2][7][2];
    float inv_[2][4];
    #pragma unroll
    for (int i=0;i<2;i++){
        int mt = mts[i];
        if (mt < 7){
            f32x4 sc[7];
            #pragma unroll
            for (int gt=0; gt<7; gt++) sc[gt] = (f32x4){0.f,0.f,0.f,0.f};
            #pragma unroll 1
            for (int p=0; p<2; p++){
                #pragma unroll 2
                for (int nt4=0; nt4<4; nt4++){
                    int nt = p*4 + nt4;
                    bf16x8 bw[4];
                    #pragma unroll
                    for (int kc=0;kc<4;kc++)
                        bw[kc] = *(const bf16x8*)(mextT + (nt*16+l15)*H_ + kc*32 + l4*8);
                    f32x4 d = {0.f,0.f,0.f,0.f};
                    #pragma unroll
                    for (int kc=0;kc<4;kc++) d = mfma16(afx[i][kc], bw[kc], d);
                    #pragma unroll
                    for (int j=0;j<4;j++) sP[l4*4+j][nt4*16+l15] = (bf16)d[j];
                }
                bf16x8 afs0 = *(const bf16x8*)&sP[l15][l4*8];
                bf16x8 afs1 = *(const bf16x8*)&sP[l15][32+l4*8];
                #pragma unroll
                for (int gt=0; gt<7; gt++){
                    bf16x8 b0 = *(const bf16x8*)&sNx[gt*16+l15][p*64 + l4*8];
                    bf16x8 b1 = *(const bf16x8*)&sNx[gt*16+l15][p*64 + 32 + l4*8];
                    sc[gt] = mfma16(afs0, b0, sc[gt]);
                    sc[gt] = mfma16(afs1, b1, sc[gt]);
                }
            }
            float aj[4];
            #pragma unroll
            for (int j=0;j<4;j++) aj[j] = sAlpha[mt*16+l4*4+j];
            float rs[4] = {0.f,0.f,0.f,0.f};
            #pragma unroll
            for (int gt=0; gt<7; gt++){
                float bg = sBeta[gt*16+l15];
                int g = gt*16+l15;
                float e[4];
                #pragma unroll
                for (int j=0;j<4;j++){
                    float val = sc[gt][j] + aj[j] + bg + cc;
                    e[j] = (g<F_) ? __expf(sigmoidf_(val)) : 0.f;
                    rs[j] += e[j];
                }
                uex[i][gt][0] = pack2_(e[0],e[1]);
                uex[i][gt][1] = pack2_(e[2],e[3]);
            }
            #pragma unroll
            for (int j=0;j<4;j++){
                float v = rs[j];
                #pragma unroll
                for (int m2=1;m2<16;m2<<=1) v += __shfl_xor(v,m2,16);
                inv_[i][j] = 1.f/v;
            }
        }
    }

    union UP { unsigned u; bf16 v[2]; };
    if (mts[0] < 7){
        #pragma unroll
        for (int gt=0; gt<4; gt++){
            #pragma unroll
            for (int j2=0; j2<2; j2++){
                UP u; u.u = uex[0][gt][j2];
                sP[l4*4+j2*2  ][gt*16+l15] = (bf16)((float)u.v[0] * inv_[0][j2*2  ]);
                sP[l4*4+j2*2+1][gt*16+l15] = (bf16)((float)u.v[1] * inv_[0][j2*2+1]);
            }
        }
    }

    // ---- V^T = wvT x nx ----
    unsigned vpk[2][7][2];
    #pragma unroll
    for (int i2=0;i2<2;i2++){
        int ht = w + 4*i2;
        bf16x8 awv[4];
        #pragma unroll
        for (int kc=0;kc<4;kc++)
            awv[kc] = *(const bf16x8*)(wvT + (ht*16+l15)*H_ + kc*32 + l4*8);
        float vb0 = vb[ht*16+l4*4], vb1 = vb[ht*16+l4*4+1], vb2 = vb[ht*16+l4*4+2], vb3 = vb[ht*16+l4*4+3];
        #pragma unroll
        for (int gt=0; gt<7; gt++){
            f32x4 acc = {0.f,0.f,0.f,0.f};
            #pragma unroll
            for (int kc=0;kc<4;kc++){
                bf16x8 bfr = *(const bf16x8*)(&sNx[gt*16+l15][kc*32+l4*8]);
                acc = mfma16(awv[kc], bfr, acc);
            }
            vpk[i2][gt][0] = pack2_(acc[0]+vb0, acc[1]+vb1);
            vpk[i2][gt][1] = pack2_(acc[2]+vb2, acc[3]+vb3);
        }
    }
    __syncthreads();   // B6

    #pragma unroll
    for (int i2=0;i2<2;i2++){
        int ht = w + 4*i2;
        #pragma unroll
        for (int gt=0; gt<7; gt++){
            UP u0, u1;
            u0.u = vpk[i2][gt][0]; u1.u = vpk[i2][gt][1];
            sVT[ht*16+l4*4  ][gt*16+l15] = u0.v[0];
            sVT[ht*16+l4*4+1][gt*16+l15] = u0.v[1];
            sVT[ht*16+l4*4+2][gt*16+l15] = u1.v[0];
            sVT[ht*16+l4*4+3][gt*16+l15] = u1.v[1];
        }
    }
    __syncthreads();   // B7

    // ---- PV ----
    #pragma unroll
    for (int i=0;i<2;i++){
        int mt = mts[i];
        if (mt >= 7) continue;
        if (i==1){
            #pragma unroll
            for (int gt=0; gt<4; gt++){
                #pragma unroll
                for (int j2=0; j2<2; j2++){
                    UP u; u.u = uex[1][gt][j2];
                    sP[l4*4+j2*2  ][gt*16+l15] = (bf16)((float)u.v[0] * inv_[1][j2*2  ]);
                    sP[l4*4+j2*2+1][gt*16+l15] = (bf16)((float)u.v[1] * inv_[1][j2*2+1]);
                }
            }
        }
        bf16x8 ap0 = *(const bf16x8*)&sP[l15][l4*8];
        bf16x8 ap1 = *(const bf16x8*)&sP[l15][32+l4*8];
        f32x4 acc[8];
        #pragma unroll
        for (int ht=0;ht<8;ht++) acc[ht] = (f32x4){0.f,0.f,0.f,0.f};
        #pragma unroll
        for (int ht=0; ht<8; ht++){
            const bf16* vr = &sVT[ht*16+l15][0];
            int c0 = l4*8, c1 = 32+l4*8;
            acc[ht] = mfma16(ap0, ldb64x2(vr+c0, vr+c0+4), acc[ht]);
            acc[ht] = mfma16(ap1, ldb64x2(vr+c1, vr+c1+4), acc[ht]);
        }
        #pragma unroll
        for (int gt=4; gt<7; gt++){
            #pragma unroll
            for (int j2=0; j2<2; j2++){
                UP u; u.u = uex[i][gt][j2];
                sP[l4*4+j2*2  ][(gt-4)*16+l15] = (bf16)((float)u.v[0] * inv_[i][j2*2  ]);
                sP[l4*4+j2*2+1][(gt-4)*16+l15] = (bf16)((float)u.v[1] * inv_[i][j2*2+1]);
            }
        }
        #pragma unroll
        for (int j=0;j<4;j++) sP[l4*4+j][48+l15] = (bf16)0.f;
        bf16x8 ap2 = *(const bf16x8*)&sP[l15][l4*8];
        bf16x8 ap3 = *(const bf16x8*)&sP[l15][32+l4*8];
        #pragma unroll
        for (int ht=0; ht<8; ht++){
            const bf16* vr = &sVT[ht*16+l15][0];
            int c2 = 64+l4*8;  if (c2 >= 112) c2 = 96;
            int c3 = 96+l4*8;  if (c3 >= 112) c3 = 96;
            acc[ht] = mfma16(ap2, ldb64x2(vr+c2, vr+c2+4), acc[ht]);
            acc[ht] = mfma16(ap3, ldb64x2(vr+c3, vr+c3+4), acc[ht]);
        }
        if (mt < 6){
            #pragma unroll
            for (int ht=0; ht<8; ht++){
                unsigned u = cvtfp8x4_(acc[ht][0]*FP8SC, acc[ht][1]*FP8SC, acc[ht][2]*FP8SC, acc[ht][3]*FP8SC);
                *(unsigned*)(xxb + (size_t)b*KC_ + (mt*8+ht)*256 + lane*4) = u;
            }
        } else if (l4 == 0){
            #pragma unroll
            for (int ht=0; ht<8; ht++){
                unsigned u = cvtfp8x4_(acc[ht][0]*FP8SC, acc[ht][1]*FP8SC, acc[ht][2]*FP8SC, acc[ht][3]*FP8SC);
                *(unsigned*)(xxb + (size_t)b*KC_ + 12288 + ht*64 + l15*4) = u;
            }
        }
    }
}

// ---------------- fp8 split-K GEMM ----------------
// launch_bounds(256,2): VGPR budget ~128 so the 64-reg accumulator stays in registers.
__global__ __launch_bounds__(256,2) void k_gemm_fp8(const unsigned char* __restrict__ A,
        const unsigned char* __restrict__ Bt, float* __restrict__ part, int M, int N, int K, int KS)
{
    __shared__ unsigned char sA[128][72];
    __shared__ unsigned char sB[128][72];
    int tid=threadIdx.x, w=tid>>6, lane=tid&63, l15=lane&15, l4=lane>>4;
    int m0 = blockIdx.y*128, n0 = blockIdx.x*128;
    int kbeg = blockIdx.z*KS, kend = kbeg + KS;
    int wr = w>>1, wc = w&1;
    f32x4 acc[4][4];
    #pragma unroll
    for(int mi=0;mi<4;mi++)
        #pragma unroll
        for(int ni=0;ni<4;ni++) acc[mi][ni] = (f32x4){0.f,0.f,0.f,0.f};

    for (int k0=kbeg; k0<kend; k0+=64){
        __syncthreads();
        #pragma unroll
        for (int t2=0;t2<2;t2++){
            int t = tid + t2*256;
            int row=t>>2, col=(t&3)*16;
            *(u32x4*)&sA[row][col] = *(const u32x4*)(A + (size_t)(m0+row)*K + k0 + col);
            *(u32x4*)&sB[row][col] = *(const u32x4*)(Bt + (size_t)(n0+row)*K + k0 + col);
        }
        __syncthreads();
        #pragma unroll
        for(int ks=0;ks<2;ks++){
            long af[4], bfr[4];
            #pragma unroll
            for(int mi=0;mi<4;mi++) af[mi] = *(const long*)&sA[wr*64+mi*16+l15][ks*32+l4*8];
            #pragma unroll
            for(int ni=0;ni<4;ni++) bfr[ni] = *(const long*)&sB[wc*64+ni*16+l15][ks*32+l4*8];
            #pragma unroll
            for(int mi=0;mi<4;mi++)
                #pragma unroll
                for(int ni=0;ni<4;ni++)
                    acc[mi][ni] = mfma8(af[mi], bfr[ni], acc[mi][ni]);
        }
    }
    float* pz = part + (size_t)blockIdx.z*M*N;
    #pragma unroll
    for(int mi=0;mi<4;mi++)
        #pragma unroll
        for(int ni=0;ni<4;ni++){
            int col = n0 + wc*64 + ni*16 + l15;
            #pragma unroll
            for(int j=0;j<4;j++){
                int row = m0 + wr*64 + mi*16 + l4*4 + j;
                pz[(size_t)row*N + col] = acc[mi][ni][j];
            }
        }
}

__global__ void k_c1fin(const float* __restrict__ part, const float* __restrict__ bias,
                        bf16* __restrict__ out){
    const size_t MN = (size_t)B_*512;
    size_t e0 = ((size_t)blockIdx.x*256 + threadIdx.x)*4;
    f32x4 s = *(const f32x4*)(part + e0);
    s += *(const f32x4*)(part + MN + e0);
    s += *(const f32x4*)(part + 2*MN + e0);
    s += *(const f32x4*)(part + 3*MN + e0);
    f32x4 bb = *(const f32x4*)(bias + (e0 & 511));
    const float ds = 1.0f/(FP8SC*FP8SC);
    unsigned long long u = pack4_(eluf_(s[0]*ds+bb[0]), eluf_(s[1]*ds+bb[1]),
                                  eluf_(s[2]*ds+bb[2]), eluf_(s[3]*ds+bb[3]));
    *(unsigned long long*)(out + e0) = u;
}

// ---------------- generic tiled GEMM ----------------
template<int BN, bool ELU>
__global__ __launch_bounds__(256,2) void k_gemm(const bf16* __restrict__ A, const bf16* __restrict__ Bt,
        const float* __restrict__ bias, bf16* __restrict__ out, int M, int N, int K)
{
    __shared__ bf16 sAt[128][72];
    __shared__ bf16 sBt[BN][72];
    int tid=threadIdx.x, w=tid>>6, lane=tid&63, l15=lane&15, l4=lane>>4;
    int m0 = blockIdx.y*128, n0 = blockIdx.x*BN;
    constexpr int MI = (BN==128)?4:2;
    constexpr int NI = (BN==128)?4:BN/16;
    int wr = (BN==128)? (w>>1) : w;
    int wc = (BN==128)? (w&1) : 0;
    f32x4 acc[MI][NI];
    #pragma unroll
    for(int mi=0;mi<MI;mi++)
        #pragma unroll
        for(int ni=0;ni<NI;ni++) acc[mi][ni] = (f32x4){0.f,0.f,0.f,0.f};

    for (int k0=0; k0<K; k0+=64){
        __syncthreads();
        for (int t=tid; t<128*8; t+=256){
            int row=t>>3, col=(t&7)*8;
            *(bf16x8*)&sAt[row][col] = *(const bf16x8*)(A + (size_t)(m0+row)*K + k0 + col);
        }
        for (int t=tid; t<BN*8; t+=256){
            int row=t>>3, col=(t&7)*8;
            *(bf16x8*)&sBt[row][col] = *(const bf16x8*)(Bt + (size_t)(n0+row)*K + k0 + col);
        }
        __syncthreads();
        #pragma unroll
        for(int ks=0;ks<2;ks++){
            bf16x8 af[MI], bfr[NI];
            #pragma unroll
            for(int mi=0;mi<MI;mi++) af[mi] = *(const bf16x8*)&sAt[wr*(MI*16)+mi*16+l15][ks*32+l4*8];
            #pragma unroll
            for(int ni=0;ni<NI;ni++) bfr[ni] = *(const bf16x8*)&sBt[wc*64+ni*16+l15][ks*32+l4*8];
            #pragma unroll
            for(int mi=0;mi<MI;mi++)
                #pragma unroll
                for(int ni=0;ni<NI;ni++)
                    acc[mi][ni] = mfma16(af[mi], bfr[ni], acc[mi][ni]);
        }
    }
    #pragma unroll
    for(int mi=0;mi<MI;mi++)
        #pragma unroll
        for(int ni=0;ni<NI;ni++){
            int col = n0 + wc*64 + ni*16 + l15;
            float bc = bias[col];
            #pragma unroll
            for(int j=0;j<4;j++){
                int row = m0 + wr*(MI*16) + mi*16 + l4*4 + j;
                float v = acc[mi][ni][j] + bc;
                if (ELU) v = eluf_(v);
                out[(size_t)row*N + col] = (bf16)v;
            }
        }
}

// ---------------- control heads ----------------
__global__ void k_heads(const bf16* __restrict__ c5o, const float* __restrict__ clw, const float* __restrict__ clb,
                        const float* __restrict__ ctw, const float* __restrict__ ctb, float* __restrict__ outp){
    int gid = blockIdx.x*4 + (threadIdx.x>>6);
    int lane = threadIdx.x & 63;
    float v = (float)c5o[(size_t)gid*64 + lane];
    float r1 = v*clw[lane], r2 = v*ctw[lane];
    #pragma unroll
    for(int m=1;m<64;m<<=1){ r1 += __shfl_xor(r1,m,64); r2 += __shfl_xor(r2,m,64); }
    if (lane==0){
        float cl = r1 + clb[0];
        outp[gid] = cl;
        outp[B_ + gid] = sigmoidf_(cl);
        outp[(size_t)2*B_ + gid] = r2 + ctb[0];
    }
}

// ---------------- uplift tail ----------------
__global__ void k_utail(const bf16* __restrict__ u3o, const float* __restrict__ u4w, const float* __restrict__ u4b,
                        const float* __restrict__ tlw, const float* __restrict__ tlb,
                        const float* __restrict__ utw, const float* __restrict__ utb, float* __restrict__ outp){
    int row = blockIdx.x*4 + (threadIdx.x>>6);
    int lane = threadIdx.x & 63;
    int j = lane & 15;
    float acc = u4b[j];
    #pragma unroll 4
    for (int h=0; h<32; ++h) acc += (float)u3o[(size_t)row*32+h] * u4w[h*16+j];
    float u4 = eluf_(acc);
    float r1 = u4*tlw[j], r2 = u4*utw[j];
    #pragma unroll
    for(int m=1;m<16;m<<=1){ r1 += __shfl_xor(r1,m,16); r2 += __shfl_xor(r2,m,16); }
    if (lane==0){
        float tl = r1 + tlb[0];
        outp[(size_t)3*B_ + row] = tl;
        outp[(size_t)4*B_ + row] = sigmoidf_(tl);
        outp[(size_t)5*B_ + row] = r2 + utb[0];
    }
}

extern "C" void kernel_launch(void* const* d_in, const int* in_sizes, int n_in,
                              void* d_out, int out_size, void* d_ws, size_t ws_size,
                              hipStream_t stream) {
    const float* feat=(const float*)d_in[0];
    const float* emb =(const float*)d_in[2];
    const float* t_w =(const float*)d_in[3]; const float* t_b=(const float*)d_in[4];
    const float* qw  =(const float*)d_in[5]; const float* qb =(const float*)d_in[6];
    const float* kw  =(const float*)d_in[7]; const float* kb =(const float*)d_in[8];
    const float* vw  =(const float*)d_in[9]; const float* vb =(const float*)d_in[10];
    const float* a1w =(const float*)d_in[11];
    const float* a2w =(const float*)d_in[12]; const float* a2b=(const float*)d_in[13];
    const float* a3w =(const float*)d_in[14];
    const float* c1w =(const float*)d_in[15]; const float* c1b=(const float*)d_in[16];
    const float* c2w =(const float*)d_in[17]; const float* c2b=(const float*)d_in[18];
    const float* c3w =(const float*)d_in[19]; const float* c3b=(const float*)d_in[20];
    const float* c4w =(const float*)d_in[21]; const float* c4b=(const float*)d_in[22];
    const float* c5w =(const float*)d_in[23]; const float* c5b=(const float*)d_in[24];
    const float* clw =(const float*)d_in[25]; const float* clb=(const float*)d_in[26];
    const float* ctw =(const float*)d_in[27]; const float* ctb=(const float*)d_in[28];
    const float* u1w =(const float*)d_in[29]; const float* u1b=(const float*)d_in[30];
    const float* u2w =(const float*)d_in[31]; const float* u2b=(const float*)d_in[32];
    const float* u3w =(const float*)d_in[33]; const float* u3b=(const float*)d_in[34];
    const float* u4w =(const float*)d_in[35]; const float* u4b=(const float*)d_in[36];
    const float* tlw =(const float*)d_in[37]; const float* tlb=(const float*)d_in[38];
    const float* utw =(const float*)d_in[39]; const float* utb=(const float*)d_in[40];
    float* outp = (float*)d_out;

    char* ws = (char*)d_ws;
    size_t off = 0;
    auto alloc = [&](size_t bytes)->char*{ char* p = ws + off; off += (bytes + 255) & ~(size_t)255; return p; };
    unsigned char* xxb = (unsigned char*)alloc((size_t)B_*KC_);          // 104.9 MB fp8
    float* part  = (float*)alloc((size_t)SPLIT_*B_*512*4);               // 67.1 MB
    bf16* xtb    = (bf16*)alloc((size_t)B_*128*2);
    bf16* cbuf1  = (bf16*)alloc((size_t)B_*512*2);
    bf16* mextT  = (bf16*)alloc(144*128*2);
    bf16* wvT    = (bf16*)alloc(128*128*2);
    bf16* wa2t   = (bf16*)alloc(128*128*2);
    unsigned char* c1wtk8 = (unsigned char*)alloc((size_t)512*KC_);
    bf16* c2wt   = (bf16*)alloc((size_t)512*512*2);
    bf16* c3wt   = (bf16*)alloc((size_t)512*256*2);
    bf16* c4wt   = (bf16*)alloc((size_t)256*128*2);
    bf16* c5wt   = (bf16*)alloc((size_t)128*64*2);
    bf16* u1t    = (bf16*)alloc(128*128*2);
    bf16* u2t    = (bf16*)alloc(64*128*2);
    bf16* u3t    = (bf16*)alloc(32*64*2);
    float* sigt  = (float*)alloc(128*4);
    float* cconst= (float*)alloc(4);
    bf16* cbuf2 = (bf16*)(xxb);
    bf16* cbuf3 = (bf16*)(xxb + (16u<<20));
    bf16* cbuf4 = (bf16*)(xxb + (32u<<20));
    bf16* cbuf5 = (bf16*)(xxb + (48u<<20));
    bf16* ubuf1 = (bf16*)(xxb + (64u<<20));
    bf16* ubuf2 = (bf16*)(xxb + (80u<<20));
    bf16* ubuf3 = (bf16*)(xxb + (96u<<20));
    (void)ws_size; (void)in_sizes; (void)n_in; (void)out_size;

    k_prepw<<<10,256,0,stream>>>(qw,qb,kw,kb,t_w,t_b,a1w,mextT,sigt,cconst);
    k_transpose_cvt<<<dim3(4,4),256,0,stream>>>(vw,  wvT, 128,128);
    k_transpose_cvt<<<dim3(4,4),256,0,stream>>>(a2w, wa2t,128,128);
    k_tc_kappa8<<<dim3(16,400),256,0,stream>>>(c1w, c1wtk8);
    k_transpose_cvt<<<dim3(16,16),256,0,stream>>>(c2w, c2wt, 512,512);
    k_transpose_cvt<<<dim3(8,16),256,0,stream>>>(c3w, c3wt, 512,256);
    k_transpose_cvt<<<dim3(4,8),256,0,stream>>>(c4w, c4wt, 256,128);
    k_transpose_cvt<<<dim3(2,4),256,0,stream>>>(c5w, c5wt, 128,64);
    k_transpose_cvt<<<dim3(4,4),256,0,stream>>>(u1w, u1t, 128,128);
    k_transpose_cvt<<<dim3(2,4),256,0,stream>>>(u2w, u2t, 128,64);
    k_transpose_cvt<<<dim3(1,2),256,0,stream>>>(u3w, u3t, 64,32);

    k_attn2<<<B_,256,0,stream>>>(feat,emb,mextT,wa2t,wvT,vb,a2b,a3w,sigt,cconst, xxb, xtb);

    k_gemm_fp8<<<dim3(4,64,SPLIT_),256,0,stream>>>(xxb, c1wtk8, part, B_,512,KC_, KC_/SPLIT_);
    k_c1fin<<<4096,256,0,stream>>>(part, c1b, cbuf1);

    k_gemm<128,true><<<dim3(4,64),256,0,stream>>>(cbuf1, c2wt, c2b, cbuf2, B_,512,512);
    k_gemm<128,true><<<dim3(2,64),256,0,stream>>>(cbuf2, c3wt, c3b, cbuf3, B_,256,512);
    k_gemm<128,true><<<dim3(1,64),256,0,stream>>>(cbuf3, c4wt, c4b, cbuf4, B_,128,256);
    k_gemm<64, true><<<dim3(1,64),256,0,stream>>>(cbuf4, c5wt, c5b, cbuf5, B_,64,128);
    k_heads<<<2048,256,0,stream>>>(cbuf5,clw,clb,ctw,ctb,outp);

    k_gemm<128,true><<<dim3(1,64),256,0,stream>>>(xtb,   u1t, u1b, ubuf1, B_,128,128);
    k_gemm<64, true><<<dim3(1,64),256,0,stream>>>(ubuf1, u2t, u2b, ubuf2, B_,64,128);
    k_gemm<32, true><<<dim3(1,64),256,0,stream>>>(ubuf2, u3t, u3b, ubuf3, B_,32,64);
    k_utail<<<2048,256,0,stream>>>(ubuf3,u4w,u4b,tlw,tlb,utw,utb,outp);
}

// Round 9
// 906.170 us; speedup vs baseline: 2.3388x; 1.0086x over previous
//
#include <hip/hip_runtime.h>
#include <hip/hip_bf16.h>

typedef __bf16 bf16;
typedef __bf16 bf16x8 __attribute__((ext_vector_type(8)));
typedef __bf16 bf16x4 __attribute__((ext_vector_type(4)));
typedef float f32x4 __attribute__((ext_vector_type(4)));
typedef unsigned u32x4 __attribute__((ext_vector_type(4)));

#define DEVI static __device__ __forceinline__

DEVI float sigmoidf_(float x){ return 1.0f/(1.0f+__expf(-x)); }
DEVI float eluf_(float x){ return x>0.f ? x : (__expf(x)-1.f); }
DEVI f32x4 mfma16(bf16x8 a, bf16x8 b, f32x4 c){ return __builtin_amdgcn_mfma_f32_16x16x32_bf16(a,b,c,0,0,0); }
DEVI f32x4 mfma8(long a, long b, f32x4 c){ return __builtin_amdgcn_mfma_f32_16x16x32_fp8_fp8(a,b,c,0,0,0); }
DEVI unsigned pack2_(float a, float b){
    union { bf16 v[2]; unsigned u; } t; t.v[0]=(bf16)a; t.v[1]=(bf16)b; return t.u;
}
DEVI unsigned long long pack4_(float a, float b, float c, float d){
    union { bf16 v[4]; unsigned long long u; } t;
    t.v[0]=(bf16)a; t.v[1]=(bf16)b; t.v[2]=(bf16)c; t.v[3]=(bf16)d; return t.u;
}
DEVI unsigned cvtfp8x4_(float a, float b, float c, float d){
    int v = __builtin_amdgcn_cvt_pk_fp8_f32(a, b, 0, false);
    v = __builtin_amdgcn_cvt_pk_fp8_f32(c, d, v, true);
    return (unsigned)v;
}
DEVI bf16x8 ldb64x2(const bf16* p0, const bf16* p1){
    union { bf16x8 v8; bf16x4 v4[2]; } u;
    u.v4[0] = *(const bf16x4*)p0;
    u.v4[1] = *(const bf16x4*)p1;
    return u.v8;
}

#define B_ 8192
#define F_ 100
#define FP 112
#define H_ 128
#define KC_ 12800   // compact kappa-blocked K: 48*256 + 8*64
#define SPLIT_ 4
#define FP8SC 16.0f

// ---------------- weight prep ----------------
__global__ void k_prepw(const float* __restrict__ qw, const float* __restrict__ qb,
                        const float* __restrict__ kw, const float* __restrict__ kb,
                        const float* __restrict__ tw, const float* __restrict__ tb,
                        const float* __restrict__ a1w,
                        bf16* __restrict__ mextT, float* __restrict__ sigt, float* __restrict__ cconst){
    const float rsc = 0.08838834764831845f;
    int blk = blockIdx.x, tid = threadIdx.x;
    if (blk < 9){
        #pragma unroll 1
        for (int e=0; e<8; ++e){
            int idx = e*256 + tid;
            int n = blk*16 + (idx>>7), h = idx&127;
            float acc = 0.f;
            if (n < 128){
                for (int d=0; d<128; ++d) acc += qw[h*128+d]*kw[n*128+d];
            } else if (n == 128){
                for (int d=0; d<128; ++d) acc += qw[h*128+d]*kb[d];
            } else if (n == 129){
                for (int d=0; d<128; ++d) acc += kw[h*128+d]*qb[d];
            }
            mextT[n*128+h] = (bf16)(acc*rsc);
        }
    } else {
        if (tid < 128){
            float acc = 0.f;
            for (int h=0; h<128; ++h) acc += (tw[h]+tb[h]) * a1w[h*128+tid];
            sigt[tid] = sigmoidf_(acc);
        } else if (tid == 128){
            float acc = 0.f;
            for (int d=0; d<128; ++d) acc += qb[d]*kb[d];
            cconst[0] = acc*rsc;
        }
    }
}

// in [R][C] f32 -> out [C][R] bf16
__global__ void k_transpose_cvt(const float* __restrict__ in, bf16* __restrict__ out, int R, int C){
    __shared__ float t[32][33];
    int c0 = blockIdx.x*32, r0 = blockIdx.y*32;
    int tc = threadIdx.x & 31, tr = threadIdx.x >> 5;
    #pragma unroll
    for (int i=0;i<4;i++){
        int r = tr + i*8;
        t[r][tc] = in[(size_t)(r0+r)*C + c0 + tc];
    }
    __syncthreads();
    #pragma unroll
    for (int i=0;i<4;i++){
        int ro = tr + i*8;
        out[(size_t)(c0+ro)*R + r0 + tc] = (bf16)t[tc][ro];
    }
}

// compact kappa: bijection on [0,12800). In-tile idx = 4*lane + j (lane-linear PV store)
DEVI int kappa_(int k){
    int f = k>>7, h = k&127;
    if (f < 96)
        return (((f>>4)<<3) | (h>>4))*256 + ((f&15)>>2)*64 + (h&15)*4 + (f&3);
    else
        return 12288 + (h>>4)*64 + (h&15)*4 + (f&3);
}
__global__ void k_tc_kappa8(const float* __restrict__ in, unsigned char* __restrict__ out){
    __shared__ float t[32][33];
    const int C = 512;
    int c0 = blockIdx.x*32, r0 = blockIdx.y*32;
    int tc = threadIdx.x & 31, tr = threadIdx.x >> 5;
    #pragma unroll
    for (int i=0;i<4;i++){
        int r = tr + i*8;
        t[r][tc] = in[(size_t)(r0+r)*C + c0 + tc];
    }
    __syncthreads();
    #pragma unroll
    for (int i=0;i<4;i++){
        int ro = tr + i*8;
        float x = t[tc][ro]*FP8SC;
        int v = __builtin_amdgcn_cvt_pk_fp8_f32(x, x, 0, false);
        out[(size_t)(c0+ro)*KC_ + kappa_(r0+tc)] = (unsigned char)v;
    }
}

// ---------------- fused per-batch attention (one block per batch, 3 blocks/CU) ----------------
// LDS layout (49536 B total):
//   [0,30464)       sNx[112][136] bf16  UNION  sVT[128][116] bf16 (29696)
//   [30720,48128)   sP[4][16][136] bf16 (full-width per-wave; single-pass S1/e/PV)
//                   sFeat/sAtt/sAw f32 alias the first 1.4 KB (dead before sP use)
//   [48128,49536)   sNorm[128], sAlpha[112], sBeta[112] f32
__global__ __launch_bounds__(256,2) void k_attn2(
    const float* __restrict__ feat, const float* __restrict__ emb,
    const bf16* __restrict__ mextT, const bf16* __restrict__ wa2t,
    const bf16* __restrict__ wvT, const float* __restrict__ vb,
    const float* __restrict__ a2b, const float* __restrict__ a3w,
    const float* __restrict__ sigt_g, const float* __restrict__ cconst,
    unsigned char* __restrict__ xxb, bf16* __restrict__ xtb)
{
    __shared__ char L[49536];
    bf16 (*sNx)[136] = (bf16(*)[136])L;
    bf16 (*sVT)[116] = (bf16(*)[116])L;
    float* sFeat  = (float*)(L+30720);
    float* sAtt   = (float*)(L+31168);
    float* sAw    = (float*)(L+31616);
    float* sNorm  = (float*)(L+48128);
    float* sAlpha = (float*)(L+48640);
    float* sBeta  = (float*)(L+49088);

    int b = blockIdx.x;
    int tid = threadIdx.x, w = tid>>6, lane = tid&63;
    int l15 = lane&15, l4 = lane>>4;
    bf16 (*sP)[136] = (bf16(*)[136])(L + 30720 + w*4352);

    if (tid < FP) sFeat[tid] = (tid<F_) ? feat[(size_t)b*F_+tid] : 0.f;
    __syncthreads();   // B1

    int hA = tid & 127, fpA = tid >> 7;
    float facc = 0.f;
    #pragma unroll 4
    for (int it=0; it<56; ++it){
        int f = fpA + 2*it;
        float v = 0.f;
        if (f < F_) v = sFeat[f] * emb[f*H_ + hA];
        facc += v*v;
        sNx[f][hA] = (bf16)v;
    }
    if (tid >= 128) sNorm[hA] = facc;
    __syncthreads();   // B2
    if (tid < 128) sNorm[hA] = sqrtf(facc + sNorm[hA]);

    const int mts[2] = {w, w+4};

    // ---- att path (raw x_rep) ----
    bf16x8 axf[2][4];
    #pragma unroll
    for (int i=0;i<2;i++){
        int mt = mts[i];
        if (mt<7){
            #pragma unroll
            for (int kc=0;kc<4;kc++)
                axf[i][kc] = *(const bf16x8*)(&sNx[mt*16+l15][kc*32+l4*8]);
        }
    }
    float attp[2][4] = {{0,0,0,0},{0,0,0,0}};
    #pragma unroll 2
    for (int nt=0; nt<8; nt++){
        bf16x8 bfr[4];
        #pragma unroll
        for(int kc=0;kc<4;kc++)
            bfr[kc] = *(const bf16x8*)(wa2t + (nt*16+l15)*H_ + kc*32 + l4*8);
        float a2bc = a2b[nt*16+l15], a3c = a3w[nt*16+l15], sgc = sigt_g[nt*16+l15];
        #pragma unroll
        for(int i=0;i<2;i++){
            int mt = mts[i];
            if (mt < 7){
                f32x4 acc = {0.f,0.f,0.f,0.f};
                #pragma unroll
                for(int kc=0;kc<4;kc++) acc = mfma16(axf[i][kc], bfr[kc], acc);
                #pragma unroll
                for(int j=0;j<4;j++){
                    float u = sigmoidf_(acc[j] + a2bc);
                    float t = sgc + u;
                    t = t>0.f ? t : 0.f;
                    attp[i][j] += t * a3c;
                }
            }
        }
    }
    #pragma unroll
    for(int i=0;i<2;i++)
        #pragma unroll
        for(int j=0;j<4;j++){
            float v = attp[i][j];
            #pragma unroll
            for(int m=1;m<16;m<<=1) v += __shfl_xor(v,m,16);
            attp[i][j]=v;
        }
    if (l15==0){
        #pragma unroll
        for(int i=0;i<2;i++){ int mt = mts[i]; if(mt<7){
            #pragma unroll
            for(int j=0;j<4;j++) sAtt[mt*16 + l4*4 + j] = attp[i][j];
        } }
    }
    __syncthreads();   // B3

    if (w==0){
        float a0 = (lane<F_)? sAtt[lane] : -1e30f;
        float a1 = (lane+64<F_)? sAtt[lane+64] : -1e30f;
        float m = fmaxf(a0,a1);
        #pragma unroll
        for(int s=1;s<64;s<<=1) m = fmaxf(m, __shfl_xor(m,s,64));
        float e0 = (lane<F_)? __expf(a0-m):0.f;
        float e1 = (lane+64<F_)? __expf(a1-m):0.f;
        float s = e0+e1;
        #pragma unroll
        for(int t=1;t<64;t<<=1) s += __shfl_xor(s,t,64);
        float inv = 1.f/s;
        if (lane<FP) sAw[lane] = e0*inv;
        if (lane+64<FP) sAw[lane+64] = e1*inv;
    }
    {
        float rn = __builtin_amdgcn_rcpf(sNorm[hA]);
        #pragma unroll 4
        for (int it=0; it<56; ++it){
            int f = fpA + 2*it;
            sNx[f][hA] = (bf16)((float)sNx[f][hA] * rn);
        }
    }
    __syncthreads();   // B4

    // ---- alpha/beta (normalized nx) + xt ----
    {
        bf16x8 bfr8[4];
        #pragma unroll
        for (int kc=0;kc<4;kc++)
            bfr8[kc] = *(const bf16x8*)(mextT + (128+l15)*H_ + kc*32 + l4*8);
        #pragma unroll
        for (int i=0;i<2;i++){
            int mt = mts[i];
            if (mt<7){
                f32x4 acc = {0.f,0.f,0.f,0.f};
                #pragma unroll
                for (int kc=0;kc<4;kc++){
                    bf16x8 a = *(const bf16x8*)(&sNx[mt*16+l15][kc*32+l4*8]);
                    acc = mfma16(a, bfr8[kc], acc);
                }
                if (l15==0){
                    #pragma unroll
                    for (int j=0;j<4;j++) sAlpha[mt*16+l4*4+j] = acc[j];
                }
                if (l15==1){
                    #pragma unroll
                    for (int j=0;j<4;j++) sBeta[mt*16+l4*4+j] = acc[j];
                }
            }
        }
    }
    if (tid < 128){
        int h=tid; float acc=0.f;
        #pragma unroll 4
        for(int f=0;f<F_;f++) acc += sAw[f]*(float)sNx[f][h];
        xtb[(size_t)b*H_ + h] = (bf16)(acc * sNorm[h]);
    }
    __syncthreads();   // B5 (alpha/beta cross-wave; sP region now free)

    // ---- S1 (full-width staged) + scores + unnormalized e ----
    const float cc = cconst[0];
    unsigned uex1[7][2];      // e for i=1 kept packed in regs (sP busy with e0)
    float inv_[2][4];
    #pragma unroll
    for (int i=0;i<2;i++){
        int mt = mts[i];
        if (mt < 7){
            bf16x8 afxi[4];
            #pragma unroll
            for (int kc=0;kc<4;kc++)
                afxi[kc] = *(const bf16x8*)(&sNx[mt*16+l15][kc*32+l4*8]);
            // stage S1 full width (cols 0..127)
            #pragma unroll 2
            for (int nt=0; nt<8; nt++){
                bf16x8 bw[4];
                #pragma unroll
                for (int kc=0;kc<4;kc++)
                    bw[kc] = *(const bf16x8*)(mextT + (nt*16+l15)*H_ + kc*32 + l4*8);
                f32x4 d = {0.f,0.f,0.f,0.f};
                #pragma unroll
                for (int kc=0;kc<4;kc++) d = mfma16(afxi[kc], bw[kc], d);
                #pragma unroll
                for (int j=0;j<4;j++) sP[l4*4+j][nt*16+l15] = (bf16)d[j];
            }
            bf16x8 afs[4];
            #pragma unroll
            for (int q=0;q<4;q++)
                afs[q] = *(const bf16x8*)&sP[l15][q*32 + l4*8];
            f32x4 sc[7];
            #pragma unroll
            for (int gt=0; gt<7; gt++){
                f32x4 a = {0.f,0.f,0.f,0.f};
                #pragma unroll
                for (int kc=0;kc<4;kc++){
                    bf16x8 bb = *(const bf16x8*)(&sNx[gt*16+l15][kc*32 + l4*8]);
                    a = mfma16(afs[kc], bb, a);
                }
                sc[gt] = a;
            }
            float aj[4];
            #pragma unroll
            for (int j=0;j<4;j++) aj[j] = sAlpha[mt*16+l4*4+j];
            float rs[4] = {0.f,0.f,0.f,0.f};
            #pragma unroll
            for (int gt=0; gt<7; gt++){
                float bg = sBeta[gt*16+l15];
                int g = gt*16+l15;
                float e[4];
                #pragma unroll
                for (int j=0;j<4;j++){
                    float val = sc[gt][j] + aj[j] + bg + cc;
                    e[j] = (g<F_) ? __expf(sigmoidf_(val)) : 0.f;
                    rs[j] += e[j];
                }
                if (i==0){
                    #pragma unroll
                    for (int j=0;j<4;j++) sP[l4*4+j][gt*16+l15] = (bf16)e[j];
                } else {
                    uex1[gt][0] = pack2_(e[0],e[1]);
                    uex1[gt][1] = pack2_(e[2],e[3]);
                }
            }
            if (i==0){
                #pragma unroll
                for (int j=0;j<4;j++) sP[l4*4+j][112+l15] = (bf16)0.f;  // zero pad cols 112..127
            }
            #pragma unroll
            for (int j=0;j<4;j++){
                float v = rs[j];
                #pragma unroll
                for (int m2=1;m2<16;m2<<=1) v += __shfl_xor(v,m2,16);
                inv_[i][j] = 1.f/v;
            }
        }
    }

    // ---- V^T = wvT x nx (into packed regs; nx still live) ----
    unsigned vpk[2][7][2];
    #pragma unroll
    for (int i2=0;i2<2;i2++){
        int ht = w + 4*i2;
        bf16x8 awv[4];
        #pragma unroll
        for (int kc=0;kc<4;kc++)
            awv[kc] = *(const bf16x8*)(wvT + (ht*16+l15)*H_ + kc*32 + l4*8);
        float vb0 = vb[ht*16+l4*4], vb1 = vb[ht*16+l4*4+1], vb2 = vb[ht*16+l4*4+2], vb3 = vb[ht*16+l4*4+3];
        #pragma unroll
        for (int gt=0; gt<7; gt++){
            f32x4 acc = {0.f,0.f,0.f,0.f};
            #pragma unroll
            for (int kc=0;kc<4;kc++){
                bf16x8 bfr = *(const bf16x8*)(&sNx[gt*16+l15][kc*32+l4*8]);
                acc = mfma16(awv[kc], bfr, acc);
            }
            vpk[i2][gt][0] = pack2_(acc[0]+vb0, acc[1]+vb1);
            vpk[i2][gt][1] = pack2_(acc[2]+vb2, acc[3]+vb3);
        }
    }
    __syncthreads();   // B6: all sNx reads complete

    union UP { unsigned u; bf16 v[2]; };
    #pragma unroll
    for (int i2=0;i2<2;i2++){
        int ht = w + 4*i2;
        #pragma unroll
        for (int gt=0; gt<7; gt++){
            UP u0, u1;
            u0.u = vpk[i2][gt][0]; u1.u = vpk[i2][gt][1];
            sVT[ht*16+l4*4  ][gt*16+l15] = u0.v[0];
            sVT[ht*16+l4*4+1][gt*16+l15] = u0.v[1];
            sVT[ht*16+l4*4+2][gt*16+l15] = u1.v[0];
            sVT[ht*16+l4*4+3][gt*16+l15] = u1.v[1];
        }
    }
    __syncthreads();   // B7

    // ---- PV: single pass, normalization deferred to epilogue ----
    #pragma unroll
    for (int i=0;i<2;i++){
        int mt = mts[i];
        if (mt >= 7) continue;
        if (i==1){
            #pragma unroll
            for (int gt=0; gt<7; gt++){
                UP u0, u1;
                u0.u = uex1[gt][0]; u1.u = uex1[gt][1];
                sP[l4*4  ][gt*16+l15] = u0.v[0];
                sP[l4*4+1][gt*16+l15] = u0.v[1];
                sP[l4*4+2][gt*16+l15] = u1.v[0];
                sP[l4*4+3][gt*16+l15] = u1.v[1];
            }
            #pragma unroll
            for (int j=0;j<4;j++) sP[l4*4+j][112+l15] = (bf16)0.f;
        }
        bf16x8 ap[4];
        #pragma unroll
        for (int q=0;q<4;q++)
            ap[q] = *(const bf16x8*)&sP[l15][q*32 + l4*8];
        float fs[4];
        #pragma unroll
        for (int j=0;j<4;j++) fs[j] = inv_[i][j]*FP8SC;
        #pragma unroll
        for (int ht=0; ht<8; ht++){
            const bf16* vr = &sVT[ht*16+l15][0];
            f32x4 acc = {0.f,0.f,0.f,0.f};
            #pragma unroll
            for (int q=0;q<4;q++){
                int c = q*32 + l4*8;
                if (c >= 112) c = 96;     // A (e) is zero for k>=112; keep B read in-row
                acc = mfma16(ap[q], ldb64x2(vr+c, vr+c+4), acc);
            }
            unsigned u = cvtfp8x4_(acc[0]*fs[0], acc[1]*fs[1], acc[2]*fs[2], acc[3]*fs[3]);
            if (mt < 6){
                *(unsigned*)(xxb + (size_t)b*KC_ + (mt*8+ht)*256 + lane*4) = u;
            } else if (l4 == 0){
                *(unsigned*)(xxb + (size_t)b*KC_ + 12288 + ht*64 + l15*4) = u;
            }
        }
    }
}

// ---------------- fp8 split-K GEMM ----------------
__global__ __launch_bounds__(256,2) void k_gemm_fp8(const unsigned char* __restrict__ A,
        const unsigned char* __restrict__ Bt, float* __restrict__ part, int M, int N, int K, int KS)
{
    __shared__ unsigned char sA[128][72];
    __shared__ unsigned char sB[128][72];
    int tid=threadIdx.x, w=tid>>6, lane=tid&63, l15=lane&15, l4=lane>>4;
    int m0 = blockIdx.y*128, n0 = blockIdx.x*128;
    int kbeg = blockIdx.z*KS, kend = kbeg + KS;
    int wr = w>>1, wc = w&1;
    f32x4 acc[4][4];
    #pragma unroll
    for(int mi=0;mi<4;mi++)
        #pragma unroll
        for(int ni=0;ni<4;ni++) acc[mi][ni] = (f32x4){0.f,0.f,0.f,0.f};

    for (int k0=kbeg; k0<kend; k0+=64){
        __syncthreads();
        #pragma unroll
        for (int t2=0;t2<2;t2++){
            int t = tid + t2*256;
            int row=t>>2, col=(t&3)*16;
            *(u32x4*)&sA[row][col] = *(const u32x4*)(A + (size_t)(m0+row)*K + k0 + col);
            *(u32x4*)&sB[row][col] = *(const u32x4*)(Bt + (size_t)(n0+row)*K + k0 + col);
        }
        __syncthreads();
        #pragma unroll
        for(int ks=0;ks<2;ks++){
            long af[4], bfr[4];
            #pragma unroll
            for(int mi=0;mi<4;mi++) af[mi] = *(const long*)&sA[wr*64+mi*16+l15][ks*32+l4*8];
            #pragma unroll
            for(int ni=0;ni<4;ni++) bfr[ni] = *(const long*)&sB[wc*64+ni*16+l15][ks*32+l4*8];
            #pragma unroll
            for(int mi=0;mi<4;mi++)
                #pragma unroll
                for(int ni=0;ni<4;ni++)
                    acc[mi][ni] = mfma8(af[mi], bfr[ni], acc[mi][ni]);
        }
    }
    float* pz = part + (size_t)blockIdx.z*M*N;
    #pragma unroll
    for(int mi=0;mi<4;mi++)
        #pragma unroll
        for(int ni=0;ni<4;ni++){
            int col = n0 + wc*64 + ni*16 + l15;
            #pragma unroll
            for(int j=0;j<4;j++){
                int row = m0 + wr*64 + mi*16 + l4*4 + j;
                pz[(size_t)row*N + col] = acc[mi][ni][j];
            }
        }
}

__global__ void k_c1fin(const float* __restrict__ part, const float* __restrict__ bias,
                        bf16* __restrict__ out){
    const size_t MN = (size_t)B_*512;
    size_t e0 = ((size_t)blockIdx.x*256 + threadIdx.x)*4;
    f32x4 s = *(const f32x4*)(part + e0);
    s += *(const f32x4*)(part + MN + e0);
    s += *(const f32x4*)(part + 2*MN + e0);
    s += *(const f32x4*)(part + 3*MN + e0);
    f32x4 bb = *(const f32x4*)(bias + (e0 & 511));
    const float ds = 1.0f/(FP8SC*FP8SC);
    unsigned long long u = pack4_(eluf_(s[0]*ds+bb[0]), eluf_(s[1]*ds+bb[1]),
                                  eluf_(s[2]*ds+bb[2]), eluf_(s[3]*ds+bb[3]));
    *(unsigned long long*)(out + e0) = u;
}

// ---------------- generic tiled GEMM ----------------
template<int BN, bool ELU>
__global__ __launch_bounds__(256,2) void k_gemm(const bf16* __restrict__ A, const bf16* __restrict__ Bt,
        const float* __restrict__ bias, bf16* __restrict__ out, int M, int N, int K)
{
    __shared__ bf16 sAt[128][72];
    __shared__ bf16 sBt[BN][72];
    int tid=threadIdx.x, w=tid>>6, lane=tid&63, l15=lane&15, l4=lane>>4;
    int m0 = blockIdx.y*128, n0 = blockIdx.x*BN;
    constexpr int MI = (BN==128)?4:2;
    constexpr int NI = (BN==128)?4:BN/16;
    int wr = (BN==128)? (w>>1) : w;
    int wc = (BN==128)? (w&1) : 0;
    f32x4 acc[MI][NI];
    #pragma unroll
    for(int mi=0;mi<MI;mi++)
        #pragma unroll
        for(int ni=0;ni<NI;ni++) acc[mi][ni] = (f32x4){0.f,0.f,0.f,0.f};

    for (int k0=0; k0<K; k0+=64){
        __syncthreads();
        for (int t=tid; t<128*8; t+=256){
            int row=t>>3, col=(t&7)*8;
            *(bf16x8*)&sAt[row][col] = *(const bf16x8*)(A + (size_t)(m0+row)*K + k0 + col);
        }
        for (int t=tid; t<BN*8; t+=256){
            int row=t>>3, col=(t&7)*8;
            *(bf16x8*)&sBt[row][col] = *(const bf16x8*)(Bt + (size_t)(n0+row)*K + k0 + col);
        }
        __syncthreads();
        #pragma unroll
        for(int ks=0;ks<2;ks++){
            bf16x8 af[MI], bfr[NI];
            #pragma unroll
            for(int mi=0;mi<MI;mi++) af[mi] = *(const bf16x8*)&sAt[wr*(MI*16)+mi*16+l15][ks*32+l4*8];
            #pragma unroll
            for(int ni=0;ni<NI;ni++) bfr[ni] = *(const bf16x8*)&sBt[wc*64+ni*16+l15][ks*32+l4*8];
            #pragma unroll
            for(int mi=0;mi<MI;mi++)
                #pragma unroll
                for(int ni=0;ni<NI;ni++)
                    acc[mi][ni] = mfma16(af[mi], bfr[ni], acc[mi][ni]);
        }
    }
    #pragma unroll
    for(int mi=0;mi<MI;mi++)
        #pragma unroll
        for(int ni=0;ni<NI;ni++){
            int col = n0 + wc*64 + ni*16 + l15;
            float bc = bias[col];
            #pragma unroll
            for(int j=0;j<4;j++){
                int row = m0 + wr*(MI*16) + mi*16 + l4*4 + j;
                float v = acc[mi][ni][j] + bc;
                if (ELU) v = eluf_(v);
                out[(size_t)row*N + col] = (bf16)v;
            }
        }
}

// ---------------- control heads ----------------
__global__ void k_heads(const bf16* __restrict__ c5o, const float* __restrict__ clw, const float* __restrict__ clb,
                        const float* __restrict__ ctw, const float* __restrict__ ctb, float* __restrict__ outp){
    int gid = blockIdx.x*4 + (threadIdx.x>>6);
    int lane = threadIdx.x & 63;
    float v = (float)c5o[(size_t)gid*64 + lane];
    float r1 = v*clw[lane], r2 = v*ctw[lane];
    #pragma unroll
    for(int m=1;m<64;m<<=1){ r1 += __shfl_xor(r1,m,64); r2 += __shfl_xor(r2,m,64); }
    if (lane==0){
        float cl = r1 + clb[0];
        outp[gid] = cl;
        outp[B_ + gid] = sigmoidf_(cl);
        outp[(size_t)2*B_ + gid] = r2 + ctb[0];
    }
}

// ---------------- uplift tail ----------------
__global__ void k_utail(const bf16* __restrict__ u3o, const float* __restrict__ u4w, const float* __restrict__ u4b,
                        const float* __restrict__ tlw, const float* __restrict__ tlb,
                        const float* __restrict__ utw, const float* __restrict__ utb, float* __restrict__ outp){
    int row = blockIdx.x*4 + (threadIdx.x>>6);
    int lane = threadIdx.x & 63;
    int j = lane & 15;
    float acc = u4b[j];
    #pragma unroll 4
    for (int h=0; h<32; ++h) acc += (float)u3o[(size_t)row*32+h] * u4w[h*16+j];
    float u4 = eluf_(acc);
    float r1 = u4*tlw[j], r2 = u4*utw[j];
    #pragma unroll
    for(int m=1;m<16;m<<=1){ r1 += __shfl_xor(r1,m,16); r2 += __shfl_xor(r2,m,16); }
    if (lane==0){
        float tl = r1 + tlb[0];
        outp[(size_t)3*B_ + row] = tl;
        outp[(size_t)4*B_ + row] = sigmoidf_(tl);
        outp[(size_t)5*B_ + row] = r2 + utb[0];
    }
}

extern "C" void kernel_launch(void* const* d_in, const int* in_sizes, int n_in,
                              void* d_out, int out_size, void* d_ws, size_t ws_size,
                              hipStream_t stream) {
    const float* feat=(const float*)d_in[0];
    const float* emb =(const float*)d_in[2];
    const float* t_w =(const float*)d_in[3]; const float* t_b=(const float*)d_in[4];
    const float* qw  =(const float*)d_in[5]; const float* qb =(const float*)d_in[6];
    const float* kw  =(const float*)d_in[7]; const float* kb =(const float*)d_in[8];
    const float* vw  =(const float*)d_in[9]; const float* vb =(const float*)d_in[10];
    const float* a1w =(const float*)d_in[11];
    const float* a2w =(const float*)d_in[12]; const float* a2b=(const float*)d_in[13];
    const float* a3w =(const float*)d_in[14];
    const float* c1w =(const float*)d_in[15]; const float* c1b=(const float*)d_in[16];
    const float* c2w =(const float*)d_in[17]; const float* c2b=(const float*)d_in[18];
    const float* c3w =(const float*)d_in[19]; const float* c3b=(const float*)d_in[20];
    const float* c4w =(const float*)d_in[21]; const float* c4b=(const float*)d_in[22];
    const float* c5w =(const float*)d_in[23]; const float* c5b=(const float*)d_in[24];
    const float* clw =(const float*)d_in[25]; const float* clb=(const float*)d_in[26];
    const float* ctw =(const float*)d_in[27]; const float* ctb=(const float*)d_in[28];
    const float* u1w =(const float*)d_in[29]; const float* u1b=(const float*)d_in[30];
    const float* u2w =(const float*)d_in[31]; const float* u2b=(const float*)d_in[32];
    const float* u3w =(const float*)d_in[33]; const float* u3b=(const float*)d_in[34];
    const float* u4w =(const float*)d_in[35]; const float* u4b=(const float*)d_in[36];
    const float* tlw =(const float*)d_in[37]; const float* tlb=(const float*)d_in[38];
    const float* utw =(const float*)d_in[39]; const float* utb=(const float*)d_in[40];
    float* outp = (float*)d_out;

    char* ws = (char*)d_ws;
    size_t off = 0;
    auto alloc = [&](size_t bytes)->char*{ char* p = ws + off; off += (bytes + 255) & ~(size_t)255; return p; };
    unsigned char* xxb = (unsigned char*)alloc((size_t)B_*KC_);          // 104.9 MB fp8
    float* part  = (float*)alloc((size_t)SPLIT_*B_*512*4);               // 67.1 MB
    bf16* xtb    = (bf16*)alloc((size_t)B_*128*2);
    bf16* cbuf1  = (bf16*)alloc((size_t)B_*512*2);
    bf16* mextT  = (bf16*)alloc(144*128*2);
    bf16* wvT    = (bf16*)alloc(128*128*2);
    bf16* wa2t   = (bf16*)alloc(128*128*2);
    unsigned char* c1wtk8 = (unsigned char*)alloc((size_t)512*KC_);
    bf16* c2wt   = (bf16*)alloc((size_t)512*512*2);
    bf16* c3wt   = (bf16*)alloc((size_t)512*256*2);
    bf16* c4wt   = (bf16*)alloc((size_t)256*128*2);
    bf16* c5wt   = (bf16*)alloc((size_t)128*64*2);
    bf16* u1t    = (bf16*)alloc(128*128*2);
    bf16* u2t    = (bf16*)alloc(64*128*2);
    bf16* u3t    = (bf16*)alloc(32*64*2);
    float* sigt  = (float*)alloc(128*4);
    float* cconst= (float*)alloc(4);
    bf16* cbuf2 = (bf16*)(xxb);
    bf16* cbuf3 = (bf16*)(xxb + (16u<<20));
    bf16* cbuf4 = (bf16*)(xxb + (32u<<20));
    bf16* cbuf5 = (bf16*)(xxb + (48u<<20));
    bf16* ubuf1 = (bf16*)(xxb + (64u<<20));
    bf16* ubuf2 = (bf16*)(xxb + (80u<<20));
    bf16* ubuf3 = (bf16*)(xxb + (96u<<20));
    (void)ws_size; (void)in_sizes; (void)n_in; (void)out_size;

    k_prepw<<<10,256,0,stream>>>(qw,qb,kw,kb,t_w,t_b,a1w,mextT,sigt,cconst);
    k_transpose_cvt<<<dim3(4,4),256,0,stream>>>(vw,  wvT, 128,128);
    k_transpose_cvt<<<dim3(4,4),256,0,stream>>>(a2w, wa2t,128,128);
    k_tc_kappa8<<<dim3(16,400),256,0,stream>>>(c1w, c1wtk8);
    k_transpose_cvt<<<dim3(16,16),256,0,stream>>>(c2w, c2wt, 512,512);
    k_transpose_cvt<<<dim3(8,16),256,0,stream>>>(c3w, c3wt, 512,256);
    k_transpose_cvt<<<dim3(4,8),256,0,stream>>>(c4w, c4wt, 256,128);
    k_transpose_cvt<<<dim3(2,4),256,0,stream>>>(c5w, c5wt, 128,64);
    k_transpose_cvt<<<dim3(4,4),256,0,stream>>>(u1w, u1t, 128,128);
    k_transpose_cvt<<<dim3(2,4),256,0,stream>>>(u2w, u2t, 128,64);
    k_transpose_cvt<<<dim3(1,2),256,0,stream>>>(u3w, u3t, 64,32);

    k_attn2<<<B_,256,0,stream>>>(feat,emb,mextT,wa2t,wvT,vb,a2b,a3w,sigt,cconst, xxb, xtb);

    k_gemm_fp8<<<dim3(4,64,SPLIT_),256,0,stream>>>(xxb, c1wtk8, part, B_,512,KC_, KC_/SPLIT_);
    k_c1fin<<<4096,256,0,stream>>>(part, c1b, cbuf1);

    k_gemm<128,true><<<dim3(4,64),256,0,stream>>>(cbuf1, c2wt, c2b, cbuf2, B_,512,512);
    k_gemm<128,true><<<dim3(2,64),256,0,stream>>>(cbuf2, c3wt, c3b, cbuf3, B_,256,512);
    k_gemm<128,true><<<dim3(1,64),256,0,stream>>>(cbuf3, c4wt, c4b, cbuf4, B_,128,256);
    k_gemm<64, true><<<dim3(1,64),256,0,stream>>>(cbuf4, c5wt, c5b, cbuf5, B_,64,128);
    k_heads<<<2048,256,0,stream>>>(cbuf5,clw,clb,ctw,ctb,outp);

    k_gemm<128,true><<<dim3(1,64),256,0,stream>>>(xtb,   u1t, u1b, ubuf1, B_,128,128);
    k_gemm<64, true><<<dim3(1,64),256,0,stream>>>(ubuf1, u2t, u2b, ubuf2, B_,64,128);
    k_gemm<32, true><<<dim3(1,64),256,0,stream>>>(ubuf2, u3t, u3b, ubuf3, B_,32,64);
    k_utail<<<2048,256,0,stream>>>(ubuf3,u4w,u4b,tlw,tlb,utw,utb,outp);
}

// Round 10
// 846.916 us; speedup vs baseline: 2.5025x; 1.0700x over previous
//
#include <hip/hip_runtime.h>
#include <hip/hip_bf16.h>

typedef __bf16 bf16;
typedef __bf16 bf16x8 __attribute__((ext_vector_type(8)));
typedef __bf16 bf16x4 __attribute__((ext_vector_type(4)));
typedef float f32x4 __attribute__((ext_vector_type(4)));
typedef unsigned u32x4 __attribute__((ext_vector_type(4)));

#define DEVI static __device__ __forceinline__

DEVI float sigmoidf_(float x){ return 1.0f/(1.0f+__expf(-x)); }
DEVI float eluf_(float x){ return x>0.f ? x : (__expf(x)-1.f); }
DEVI f32x4 mfma16(bf16x8 a, bf16x8 b, f32x4 c){ return __builtin_amdgcn_mfma_f32_16x16x32_bf16(a,b,c,0,0,0); }
DEVI f32x4 mfma8(long a, long b, f32x4 c){ return __builtin_amdgcn_mfma_f32_16x16x32_fp8_fp8(a,b,c,0,0,0); }
DEVI unsigned pack2_(float a, float b){
    union { bf16 v[2]; unsigned u; } t; t.v[0]=(bf16)a; t.v[1]=(bf16)b; return t.u;
}
DEVI unsigned long long pack4_(float a, float b, float c, float d){
    union { bf16 v[4]; unsigned long long u; } t;
    t.v[0]=(bf16)a; t.v[1]=(bf16)b; t.v[2]=(bf16)c; t.v[3]=(bf16)d; return t.u;
}
DEVI unsigned cvtfp8x4_(float a, float b, float c, float d){
    int v = __builtin_amdgcn_cvt_pk_fp8_f32(a, b, 0, false);
    v = __builtin_amdgcn_cvt_pk_fp8_f32(c, d, v, true);
    return (unsigned)v;
}
DEVI bf16x8 ldb64x2(const bf16* p0, const bf16* p1){
    union { bf16x8 v8; bf16x4 v4[2]; } u;
    u.v4[0] = *(const bf16x4*)p0;
    u.v4[1] = *(const bf16x4*)p1;
    return u.v8;
}

#define B_ 8192
#define F_ 100
#define FP 112
#define H_ 128
#define KC_ 12800   // compact kappa-blocked K: 48*256 + 8*64
#define SPLIT_ 4
#define FP8SC 16.0f

// ---------------- weight prep ----------------
__global__ void k_prepw(const float* __restrict__ qw, const float* __restrict__ qb,
                        const float* __restrict__ kw, const float* __restrict__ kb,
                        const float* __restrict__ tw, const float* __restrict__ tb,
                        const float* __restrict__ a1w,
                        bf16* __restrict__ mextT, float* __restrict__ sigt, float* __restrict__ cconst){
    const float rsc = 0.08838834764831845f;
    int blk = blockIdx.x, tid = threadIdx.x;
    if (blk < 9){
        #pragma unroll 1
        for (int e=0; e<8; ++e){
            int idx = e*256 + tid;
            int n = blk*16 + (idx>>7), h = idx&127;
            float acc = 0.f;
            if (n < 128){
                for (int d=0; d<128; ++d) acc += qw[h*128+d]*kw[n*128+d];
            } else if (n == 128){
                for (int d=0; d<128; ++d) acc += qw[h*128+d]*kb[d];
            } else if (n == 129){
                for (int d=0; d<128; ++d) acc += kw[h*128+d]*qb[d];
            }
            mextT[n*128+h] = (bf16)(acc*rsc);
        }
    } else {
        if (tid < 128){
            float acc = 0.f;
            for (int h=0; h<128; ++h) acc += (tw[h]+tb[h]) * a1w[h*128+tid];
            sigt[tid] = sigmoidf_(acc);
        } else if (tid == 128){
            float acc = 0.f;
            for (int d=0; d<128; ++d) acc += qb[d]*kb[d];
            cconst[0] = acc*rsc;
        }
    }
}

// in [R][C] f32 -> out [C][R] bf16
__global__ void k_transpose_cvt(const float* __restrict__ in, bf16* __restrict__ out, int R, int C){
    __shared__ float t[32][33];
    int c0 = blockIdx.x*32, r0 = blockIdx.y*32;
    int tc = threadIdx.x & 31, tr = threadIdx.x >> 5;
    #pragma unroll
    for (int i=0;i<4;i++){
        int r = tr + i*8;
        t[r][tc] = in[(size_t)(r0+r)*C + c0 + tc];
    }
    __syncthreads();
    #pragma unroll
    for (int i=0;i<4;i++){
        int ro = tr + i*8;
        out[(size_t)(c0+ro)*R + r0 + tc] = (bf16)t[tc][ro];
    }
}

// compact kappa: bijection on [0,12800). In-tile idx = 4*lane + j (lane-linear PV store)
DEVI int kappa_(int k){
    int f = k>>7, h = k&127;
    if (f < 96)
        return (((f>>4)<<3) | (h>>4))*256 + ((f&15)>>2)*64 + (h&15)*4 + (f&3);
    else
        return 12288 + (h>>4)*64 + (h&15)*4 + (f&3);
}
__global__ void k_tc_kappa8(const float* __restrict__ in, unsigned char* __restrict__ out){
    __shared__ float t[32][33];
    const int C = 512;
    int c0 = blockIdx.x*32, r0 = blockIdx.y*32;
    int tc = threadIdx.x & 31, tr = threadIdx.x >> 5;
    #pragma unroll
    for (int i=0;i<4;i++){
        int r = tr + i*8;
        t[r][tc] = in[(size_t)(r0+r)*C + c0 + tc];
    }
    __syncthreads();
    #pragma unroll
    for (int i=0;i<4;i++){
        int ro = tr + i*8;
        float x = t[tc][ro]*FP8SC;
        int v = __builtin_amdgcn_cvt_pk_fp8_f32(x, x, 0, false);
        out[(size_t)(c0+ro)*KC_ + kappa_(r0+tc)] = (unsigned char)v;
    }
}

// ---------------- flat GEMM for interaction-attention scores ----------------
// att[b,f] = sum_n relu(sigt[n] + sig( (x_rep[b,f,:]@a2w)[n] + a2b[n] )) * a3w[n]
// M = B*112 rows, K=128, N=128. A built on the fly: A[(b,f)][h] = feat[b,f]*emb[f,h].
__global__ __launch_bounds__(256,2) void k_gatt(
    const float* __restrict__ feat, const float* __restrict__ emb,
    const bf16* __restrict__ wa2t, const float* __restrict__ a2b,
    const float* __restrict__ a3w, const float* __restrict__ sigt,
    float* __restrict__ attg)
{
    __shared__ bf16 sAt[128][72];
    __shared__ bf16 sBt[128][72];
    __shared__ float sRed[2][128];
    int tid=threadIdx.x, w=tid>>6, lane=tid&63, l15=lane&15, l4=lane>>4;
    int m0 = blockIdx.x*128;
    int wr = w>>1, wc = w&1;
    f32x4 acc[4][4];
    #pragma unroll
    for(int mi=0;mi<4;mi++)
        #pragma unroll
        for(int ni=0;ni<4;ni++) acc[mi][ni] = (f32x4){0.f,0.f,0.f,0.f};

    #pragma unroll 1
    for (int k0=0; k0<128; k0+=64){
        __syncthreads();
        #pragma unroll
        for (int t4=0; t4<4; t4++){
            int t = tid + t4*256;
            int row=t>>3, col=(t&7)*8;
            int gr = m0+row;
            int bb = gr/112, ff = gr - bb*112;
            bf16x8 o;
            if (ff < F_){
                float fv = feat[(size_t)bb*F_ + ff];
                const float* ep = emb + ff*H_ + k0 + col;
                f32x4 e0 = *(const f32x4*)ep;
                f32x4 e1 = *(const f32x4*)(ep+4);
                o[0]=(bf16)(fv*e0[0]); o[1]=(bf16)(fv*e0[1]); o[2]=(bf16)(fv*e0[2]); o[3]=(bf16)(fv*e0[3]);
                o[4]=(bf16)(fv*e1[0]); o[5]=(bf16)(fv*e1[1]); o[6]=(bf16)(fv*e1[2]); o[7]=(bf16)(fv*e1[3]);
            } else {
                #pragma unroll
                for (int e=0;e<8;e++) o[e]=(bf16)0.f;
            }
            *(bf16x8*)&sAt[row][col] = o;
            *(bf16x8*)&sBt[row][col] = *(const bf16x8*)(wa2t + row*H_ + k0 + col);
        }
        __syncthreads();
        #pragma unroll
        for(int ks=0;ks<2;ks++){
            bf16x8 af[4], bfr[4];
            #pragma unroll
            for(int mi=0;mi<4;mi++) af[mi] = *(const bf16x8*)&sAt[wr*64+mi*16+l15][ks*32+l4*8];
            #pragma unroll
            for(int ni=0;ni<4;ni++) bfr[ni] = *(const bf16x8*)&sBt[wc*64+ni*16+l15][ks*32+l4*8];
            #pragma unroll
            for(int mi=0;mi<4;mi++)
                #pragma unroll
                for(int ni=0;ni<4;ni++)
                    acc[mi][ni] = mfma16(af[mi], bfr[ni], acc[mi][ni]);
        }
    }
    // epilogue: pointwise + reduce over n
    float sg[4], ab[4], a3[4];
    #pragma unroll
    for (int ni=0;ni<4;ni++){
        int n = wc*64 + ni*16 + l15;
        sg[ni]=sigt[n]; ab[ni]=a2b[n]; a3[ni]=a3w[n];
    }
    #pragma unroll
    for (int mi=0;mi<4;mi++){
        float sj[4] = {0.f,0.f,0.f,0.f};
        #pragma unroll
        for (int ni=0;ni<4;ni++){
            #pragma unroll
            for (int j=0;j<4;j++){
                float u = sigmoidf_(acc[mi][ni][j] + ab[ni]);
                float t = sg[ni] + u;
                t = t>0.f ? t : 0.f;
                sj[j] += t*a3[ni];
            }
        }
        #pragma unroll
        for (int j=0;j<4;j++){
            float v = sj[j];
            #pragma unroll
            for (int m=1;m<16;m<<=1) v += __shfl_xor(v,m,16);
            sj[j]=v;
        }
        if (l15==0){
            #pragma unroll
            for (int j=0;j<4;j++) sRed[wc][wr*64+mi*16+l4*4+j] = sj[j];
        }
    }
    __syncthreads();
    if (tid < 128) attg[(size_t)m0 + tid] = sRed[0][tid] + sRed[1][tid];
}

// ---------------- fused per-batch attention: 512 thr, 8 waves, 1 tile/wave ----------------
// LDS layout (66560 B; 2 blocks/CU):
//   [0,30464)       sNx[112][136] bf16  UNION  sVT[128][116] bf16 (29696)
//   [30720,65536)   sP[8][16][136] bf16 (per-wave slot, used post-B5)
//                   pre-B5 aliases: sFeat@30720, sAw@31232, sNorm@31744, normP@32256
//   [65536,66432)   sAlpha[112], sBeta[112] f32
__global__ __launch_bounds__(512,2) void k_attn2(
    const float* __restrict__ feat, const float* __restrict__ emb,
    const bf16* __restrict__ mextT, const bf16* __restrict__ wvT,
    const float* __restrict__ vb, const float* __restrict__ cconst,
    const float* __restrict__ attg,
    unsigned char* __restrict__ xxb, bf16* __restrict__ xtb)
{
    __shared__ char L[66560];
    bf16 (*sNx)[136] = (bf16(*)[136])L;
    bf16 (*sVT)[116] = (bf16(*)[116])L;
    float* sFeat  = (float*)(L+30720);
    float* sAw    = (float*)(L+31232);
    float* sNorm  = (float*)(L+31744);
    float* normP  = (float*)(L+32256);   // [3][128]
    float* sAlpha = (float*)(L+65536);
    float* sBeta  = (float*)(L+65984);

    int b = blockIdx.x;
    int tid = threadIdx.x, w = tid>>6, lane = tid&63;
    int l15 = lane&15, l4 = lane>>4;
    bf16 (*sP)[136] = (bf16(*)[136])(L + 30720 + w*4352);

    if (tid < FP) sFeat[tid] = (tid<F_) ? feat[(size_t)b*F_+tid] : 0.f;
    // wave0: softmax over precomputed att (independent of sFeat)
    if (w==0){
        const float* ag = attg + (size_t)b*FP;
        float a0 = (lane<F_)? ag[lane] : -1e30f;
        float a1 = (lane+64<F_)? ag[lane+64] : -1e30f;
        float m = fmaxf(a0,a1);
        #pragma unroll
        for(int s=1;s<64;s<<=1) m = fmaxf(m, __shfl_xor(m,s,64));
        float e0 = (lane<F_)? __expf(a0-m):0.f;
        float e1 = (lane+64<F_)? __expf(a1-m):0.f;
        float s = e0+e1;
        #pragma unroll
        for(int t=1;t<64;t<<=1) s += __shfl_xor(s,t,64);
        float inv = 1.f/s;
        if (lane<FP) sAw[lane] = e0*inv;
        if (lane+64<FP) sAw[lane+64] = e1*inv;
    }
    __syncthreads();   // B1

    // phase A: x_rep + 4-way column sums of squares
    int hA = tid & 127, fpA = tid >> 7;
    float facc = 0.f;
    #pragma unroll 4
    for (int it=0; it<28; ++it){
        int f = fpA + 4*it;
        float v = 0.f;
        if (f < F_) v = sFeat[f] * emb[f*H_ + hA];
        facc += v*v;
        sNx[f][hA] = (bf16)v;
    }
    if (fpA > 0) normP[(fpA-1)*128 + hA] = facc;
    __syncthreads();   // B2
    if (fpA == 0) sNorm[hA] = sqrtf(facc + normP[hA] + normP[128+hA] + normP[256+hA]);
    __syncthreads();   // B3

    // rescale x_rep -> nx in place
    {
        float rn = __builtin_amdgcn_rcpf(sNorm[hA]);
        #pragma unroll 4
        for (int it=0; it<28; ++it){
            int f = fpA + 4*it;
            sNx[f][hA] = (bf16)((float)sNx[f][hA] * rn);
        }
    }
    __syncthreads();   // B4

    int mt = w;   // this wave's f-tile (w==7 idle in mt-phases)

    // alpha/beta + xt
    if (mt < 7){
        bf16x8 bfr8[4];
        #pragma unroll
        for (int kc=0;kc<4;kc++)
            bfr8[kc] = *(const bf16x8*)(mextT + (128+l15)*H_ + kc*32 + l4*8);
        f32x4 acc = {0.f,0.f,0.f,0.f};
        #pragma unroll
        for (int kc=0;kc<4;kc++){
            bf16x8 a = *(const bf16x8*)(&sNx[mt*16+l15][kc*32+l4*8]);
            acc = mfma16(a, bfr8[kc], acc);
        }
        if (l15==0){
            #pragma unroll
            for (int j=0;j<4;j++) sAlpha[mt*16+l4*4+j] = acc[j];
        }
        if (l15==1){
            #pragma unroll
            for (int j=0;j<4;j++) sBeta[mt*16+l4*4+j] = acc[j];
        }
    }
    if (tid < 128){
        int h=tid; float acc=0.f;
        #pragma unroll 4
        for(int f=0;f<F_;f++) acc += sAw[f]*(float)sNx[f][h];
        xtb[(size_t)b*H_ + h] = (bf16)(acc * sNorm[h]);
    }
    __syncthreads();   // B5

    // S1 (staged in own sP) + scores + unnormalized e (stored in own sP)
    const float cc = cconst[0];
    float inv_[4];
    if (mt < 7){
        bf16x8 afxi[4];
        #pragma unroll
        for (int kc=0;kc<4;kc++)
            afxi[kc] = *(const bf16x8*)(&sNx[mt*16+l15][kc*32+l4*8]);
        #pragma unroll 2
        for (int nt=0; nt<8; nt++){
            bf16x8 bw[4];
            #pragma unroll
            for (int kc=0;kc<4;kc++)
                bw[kc] = *(const bf16x8*)(mextT + (nt*16+l15)*H_ + kc*32 + l4*8);
            f32x4 d = {0.f,0.f,0.f,0.f};
            #pragma unroll
            for (int kc=0;kc<4;kc++) d = mfma16(afxi[kc], bw[kc], d);
            #pragma unroll
            for (int j=0;j<4;j++) sP[l4*4+j][nt*16+l15] = (bf16)d[j];
        }
        bf16x8 afs[4];
        #pragma unroll
        for (int q=0;q<4;q++)
            afs[q] = *(const bf16x8*)&sP[l15][q*32 + l4*8];
        f32x4 sc[7];
        #pragma unroll
        for (int gt=0; gt<7; gt++){
            f32x4 a = {0.f,0.f,0.f,0.f};
            #pragma unroll
            for (int kc=0;kc<4;kc++){
                bf16x8 bb = *(const bf16x8*)(&sNx[gt*16+l15][kc*32 + l4*8]);
                a = mfma16(afs[kc], bb, a);
            }
            sc[gt] = a;
        }
        float aj[4];
        #pragma unroll
        for (int j=0;j<4;j++) aj[j] = sAlpha[mt*16+l4*4+j];
        float rs[4] = {0.f,0.f,0.f,0.f};
        #pragma unroll
        for (int gt=0; gt<7; gt++){
            float bg = sBeta[gt*16+l15];
            int g = gt*16+l15;
            float e[4];
            #pragma unroll
            for (int j=0;j<4;j++){
                float val = sc[gt][j] + aj[j] + bg + cc;
                e[j] = (g<F_) ? __expf(sigmoidf_(val)) : 0.f;
                rs[j] += e[j];
                sP[l4*4+j][gt*16+l15] = (bf16)e[j];
            }
        }
        #pragma unroll
        for (int j=0;j<4;j++) sP[l4*4+j][112+l15] = (bf16)0.f;
        #pragma unroll
        for (int j=0;j<4;j++){
            float v = rs[j];
            #pragma unroll
            for (int m2=1;m2<16;m2<<=1) v += __shfl_xor(v,m2,16);
            inv_[j] = 1.f/v;
        }
    }

    // V^T row-tile (ht = w, all 8 waves): compute into packed regs
    unsigned vpk[7][2];
    {
        int ht = w;
        bf16x8 awv[4];
        #pragma unroll
        for (int kc=0;kc<4;kc++)
            awv[kc] = *(const bf16x8*)(wvT + (ht*16+l15)*H_ + kc*32 + l4*8);
        float vb0 = vb[ht*16+l4*4], vb1 = vb[ht*16+l4*4+1], vb2 = vb[ht*16+l4*4+2], vb3 = vb[ht*16+l4*4+3];
        #pragma unroll
        for (int gt=0; gt<7; gt++){
            f32x4 acc = {0.f,0.f,0.f,0.f};
            #pragma unroll
            for (int kc=0;kc<4;kc++){
                bf16x8 bfr = *(const bf16x8*)(&sNx[gt*16+l15][kc*32+l4*8]);
                acc = mfma16(awv[kc], bfr, acc);
            }
            vpk[gt][0] = pack2_(acc[0]+vb0, acc[1]+vb1);
            vpk[gt][1] = pack2_(acc[2]+vb2, acc[3]+vb3);
        }
    }
    __syncthreads();   // B6: all sNx reads complete

    union UP { unsigned u; bf16 v[2]; };
    {
        int ht = w;
        #pragma unroll
        for (int gt=0; gt<7; gt++){
            UP u0, u1;
            u0.u = vpk[gt][0]; u1.u = vpk[gt][1];
            sVT[ht*16+l4*4  ][gt*16+l15] = u0.v[0];
            sVT[ht*16+l4*4+1][gt*16+l15] = u0.v[1];
            sVT[ht*16+l4*4+2][gt*16+l15] = u1.v[0];
            sVT[ht*16+l4*4+3][gt*16+l15] = u1.v[1];
        }
    }
    __syncthreads();   // B7

    // PV: normalization deferred to epilogue
    if (mt < 7){
        bf16x8 ap[4];
        #pragma unroll
        for (int q=0;q<4;q++)
            ap[q] = *(const bf16x8*)&sP[l15][q*32 + l4*8];
        float fs[4];
        #pragma unroll
        for (int j=0;j<4;j++) fs[j] = inv_[j]*FP8SC;
        #pragma unroll
        for (int ht=0; ht<8; ht++){
            const bf16* vr = &sVT[ht*16+l15][0];
            f32x4 acc = {0.f,0.f,0.f,0.f};
            #pragma unroll
            for (int q=0;q<4;q++){
                int c = q*32 + l4*8;
                if (c >= 112) c = 96;     // e is zero for k>=112; keep B read in-row
                acc = mfma16(ap[q], ldb64x2(vr+c, vr+c+4), acc);
            }
            unsigned u = cvtfp8x4_(acc[0]*fs[0], acc[1]*fs[1], acc[2]*fs[2], acc[3]*fs[3]);
            if (mt < 6){
                *(unsigned*)(xxb + (size_t)b*KC_ + (mt*8+ht)*256 + lane*4) = u;
            } else if (l4 == 0){
                *(unsigned*)(xxb + (size_t)b*KC_ + 12288 + ht*64 + l15*4) = u;
            }
        }
    }
}

// ---------------- fp8 split-K GEMM ----------------
__global__ __launch_bounds__(256,2) void k_gemm_fp8(const unsigned char* __restrict__ A,
        const unsigned char* __restrict__ Bt, float* __restrict__ part, int M, int N, int K, int KS)
{
    __shared__ unsigned char sA[128][72];
    __shared__ unsigned char sB[128][72];
    int tid=threadIdx.x, w=tid>>6, lane=tid&63, l15=lane&15, l4=lane>>4;
    int m0 = blockIdx.y*128, n0 = blockIdx.x*128;
    int kbeg = blockIdx.z*KS, kend = kbeg + KS;
    int wr = w>>1, wc = w&1;
    f32x4 acc[4][4];
    #pragma unroll
    for(int mi=0;mi<4;mi++)
        #pragma unroll
        for(int ni=0;ni<4;ni++) acc[mi][ni] = (f32x4){0.f,0.f,0.f,0.f};

    for (int k0=kbeg; k0<kend; k0+=64){
        __syncthreads();
        #pragma unroll
        for (int t2=0;t2<2;t2++){
            int t = tid + t2*256;
            int row=t>>2, col=(t&3)*16;
            *(u32x4*)&sA[row][col] = *(const u32x4*)(A + (size_t)(m0+row)*K + k0 + col);
            *(u32x4*)&sB[row][col] = *(const u32x4*)(Bt + (size_t)(n0+row)*K + k0 + col);
        }
        __syncthreads();
        #pragma unroll
        for(int ks=0;ks<2;ks++){
            long af[4], bfr[4];
            #pragma unroll
            for(int mi=0;mi<4;mi++) af[mi] = *(const long*)&sA[wr*64+mi*16+l15][ks*32+l4*8];
            #pragma unroll
            for(int ni=0;ni<4;ni++) bfr[ni] = *(const long*)&sB[wc*64+ni*16+l15][ks*32+l4*8];
            #pragma unroll
            for(int mi=0;mi<4;mi++)
                #pragma unroll
                for(int ni=0;ni<4;ni++)
                    acc[mi][ni] = mfma8(af[mi], bfr[ni], acc[mi][ni]);
        }
    }
    float* pz = part + (size_t)blockIdx.z*M*N;
    #pragma unroll
    for(int mi=0;mi<4;mi++)
        #pragma unroll
        for(int ni=0;ni<4;ni++){
            int col = n0 + wc*64 + ni*16 + l15;
            #pragma unroll
            for(int j=0;j<4;j++){
                int row = m0 + wr*64 + mi*16 + l4*4 + j;
                pz[(size_t)row*N + col] = acc[mi][ni][j];
            }
        }
}

__global__ void k_c1fin(const float* __restrict__ part, const float* __restrict__ bias,
                        bf16* __restrict__ out){
    const size_t MN = (size_t)B_*512;
    size_t e0 = ((size_t)blockIdx.x*256 + threadIdx.x)*4;
    f32x4 s = *(const f32x4*)(part + e0);
    s += *(const f32x4*)(part + MN + e0);
    s += *(const f32x4*)(part + 2*MN + e0);
    s += *(const f32x4*)(part + 3*MN + e0);
    f32x4 bb = *(const f32x4*)(bias + (e0 & 511));
    const float ds = 1.0f/(FP8SC*FP8SC);
    unsigned long long u = pack4_(eluf_(s[0]*ds+bb[0]), eluf_(s[1]*ds+bb[1]),
                                  eluf_(s[2]*ds+bb[2]), eluf_(s[3]*ds+bb[3]));
    *(unsigned long long*)(out + e0) = u;
}

// ---------------- generic tiled GEMM ----------------
template<int BN, bool ELU>
__global__ __launch_bounds__(256,2) void k_gemm(const bf16* __restrict__ A, const bf16* __restrict__ Bt,
        const float* __restrict__ bias, bf16* __restrict__ out, int M, int N, int K)
{
    __shared__ bf16 sAt[128][72];
    __shared__ bf16 sBt[BN][72];
    int tid=threadIdx.x, w=tid>>6, lane=tid&63, l15=lane&15, l4=lane>>4;
    int m0 = blockIdx.y*128, n0 = blockIdx.x*BN;
    constexpr int MI = (BN==128)?4:2;
    constexpr int NI = (BN==128)?4:BN/16;
    int wr = (BN==128)? (w>>1) : w;
    int wc = (BN==128)? (w&1) : 0;
    f32x4 acc[MI][NI];
    #pragma unroll
    for(int mi=0;mi<MI;mi++)
        #pragma unroll
        for(int ni=0;ni<NI;ni++) acc[mi][ni] = (f32x4){0.f,0.f,0.f,0.f};

    for (int k0=0; k0<K; k0+=64){
        __syncthreads();
        for (int t=tid; t<128*8; t+=256){
            int row=t>>3, col=(t&7)*8;
            *(bf16x8*)&sAt[row][col] = *(const bf16x8*)(A + (size_t)(m0+row)*K + k0 + col);
        }
        for (int t=tid; t<BN*8; t+=256){
            int row=t>>3, col=(t&7)*8;
            *(bf16x8*)&sBt[row][col] = *(const bf16x8*)(Bt + (size_t)(n0+row)*K + k0 + col);
        }
        __syncthreads();
        #pragma unroll
        for(int ks=0;ks<2;ks++){
            bf16x8 af[MI], bfr[NI];
            #pragma unroll
            for(int mi=0;mi<MI;mi++) af[mi] = *(const bf16x8*)&sAt[wr*(MI*16)+mi*16+l15][ks*32+l4*8];
            #pragma unroll
            for(int ni=0;ni<NI;ni++) bfr[ni] = *(const bf16x8*)&sBt[wc*64+ni*16+l15][ks*32+l4*8];
            #pragma unroll
            for(int mi=0;mi<MI;mi++)
                #pragma unroll
                for(int ni=0;ni<NI;ni++)
                    acc[mi][ni] = mfma16(af[mi], bfr[ni], acc[mi][ni]);
        }
    }
    #pragma unroll
    for(int mi=0;mi<MI;mi++)
        #pragma unroll
        for(int ni=0;ni<NI;ni++){
            int col = n0 + wc*64 + ni*16 + l15;
            float bc = bias[col];
            #pragma unroll
            for(int j=0;j<4;j++){
                int row = m0 + wr*(MI*16) + mi*16 + l4*4 + j;
                float v = acc[mi][ni][j] + bc;
                if (ELU) v = eluf_(v);
                out[(size_t)row*N + col] = (bf16)v;
            }
        }
}

// ---------------- control heads ----------------
__global__ void k_heads(const bf16* __restrict__ c5o, const float* __restrict__ clw, const float* __restrict__ clb,
                        const float* __restrict__ ctw, const float* __restrict__ ctb, float* __restrict__ outp){
    int gid = blockIdx.x*4 + (threadIdx.x>>6);
    int lane = threadIdx.x & 63;
    float v = (float)c5o[(size_t)gid*64 + lane];
    float r1 = v*clw[lane], r2 = v*ctw[lane];
    #pragma unroll
    for(int m=1;m<64;m<<=1){ r1 += __shfl_xor(r1,m,64); r2 += __shfl_xor(r2,m,64); }
    if (lane==0){
        float cl = r1 + clb[0];
        outp[gid] = cl;
        outp[B_ + gid] = sigmoidf_(cl);
        outp[(size_t)2*B_ + gid] = r2 + ctb[0];
    }
}

// ---------------- uplift tail ----------------
__global__ void k_utail(const bf16* __restrict__ u3o, const float* __restrict__ u4w, const float* __restrict__ u4b,
                        const float* __restrict__ tlw, const float* __restrict__ tlb,
                        const float* __restrict__ utw, const float* __restrict__ utb, float* __restrict__ outp){
    int row = blockIdx.x*4 + (threadIdx.x>>6);
    int lane = threadIdx.x & 63;
    int j = lane & 15;
    float acc = u4b[j];
    #pragma unroll 4
    for (int h=0; h<32; ++h) acc += (float)u3o[(size_t)row*32+h] * u4w[h*16+j];
    float u4 = eluf_(acc);
    float r1 = u4*tlw[j], r2 = u4*utw[j];
    #pragma unroll
    for(int m=1;m<16;m<<=1){ r1 += __shfl_xor(r1,m,16); r2 += __shfl_xor(r2,m,16); }
    if (lane==0){
        float tl = r1 + tlb[0];
        outp[(size_t)3*B_ + row] = tl;
        outp[(size_t)4*B_ + row] = sigmoidf_(tl);
        outp[(size_t)5*B_ + row] = r2 + utb[0];
    }
}

extern "C" void kernel_launch(void* const* d_in, const int* in_sizes, int n_in,
                              void* d_out, int out_size, void* d_ws, size_t ws_size,
                              hipStream_t stream) {
    const float* feat=(const float*)d_in[0];
    const float* emb =(const float*)d_in[2];
    const float* t_w =(const float*)d_in[3]; const float* t_b=(const float*)d_in[4];
    const float* qw  =(const float*)d_in[5]; const float* qb =(const float*)d_in[6];
    const float* kw  =(const float*)d_in[7]; const float* kb =(const float*)d_in[8];
    const float* vw  =(const float*)d_in[9]; const float* vb =(const float*)d_in[10];
    const float* a1w =(const float*)d_in[11];
    const float* a2w =(const float*)d_in[12]; const float* a2b=(const float*)d_in[13];
    const float* a3w =(const float*)d_in[14];
    const float* c1w =(const float*)d_in[15]; const float* c1b=(const float*)d_in[16];
    const float* c2w =(const float*)d_in[17]; const float* c2b=(const float*)d_in[18];
    const float* c3w =(const float*)d_in[19]; const float* c3b=(const float*)d_in[20];
    const float* c4w =(const float*)d_in[21]; const float* c4b=(const float*)d_in[22];
    const float* c5w =(const float*)d_in[23]; const float* c5b=(const float*)d_in[24];
    const float* clw =(const float*)d_in[25]; const float* clb=(const float*)d_in[26];
    const float* ctw =(const float*)d_in[27]; const float* ctb=(const float*)d_in[28];
    const float* u1w =(const float*)d_in[29]; const float* u1b=(const float*)d_in[30];
    const float* u2w =(const float*)d_in[31]; const float* u2b=(const float*)d_in[32];
    const float* u3w =(const float*)d_in[33]; const float* u3b=(const float*)d_in[34];
    const float* u4w =(const float*)d_in[35]; const float* u4b=(const float*)d_in[36];
    const float* tlw =(const float*)d_in[37]; const float* tlb=(const float*)d_in[38];
    const float* utw =(const float*)d_in[39]; const float* utb=(const float*)d_in[40];
    float* outp = (float*)d_out;

    char* ws = (char*)d_ws;
    size_t off = 0;
    auto alloc = [&](size_t bytes)->char*{ char* p = ws + off; off += (bytes + 255) & ~(size_t)255; return p; };
    unsigned char* xxb = (unsigned char*)alloc((size_t)B_*KC_);          // 104.9 MB fp8
    float* part  = (float*)alloc((size_t)SPLIT_*B_*512*4);               // 67.1 MB
    float* attg  = (float*)alloc((size_t)B_*FP*4);                       // 3.7 MB
    bf16* xtb    = (bf16*)alloc((size_t)B_*128*2);
    bf16* cbuf1  = (bf16*)alloc((size_t)B_*512*2);
    bf16* mextT  = (bf16*)alloc(144*128*2);
    bf16* wvT    = (bf16*)alloc(128*128*2);
    bf16* wa2t   = (bf16*)alloc(128*128*2);
    unsigned char* c1wtk8 = (unsigned char*)alloc((size_t)512*KC_);
    bf16* c2wt   = (bf16*)alloc((size_t)512*512*2);
    bf16* c3wt   = (bf16*)alloc((size_t)512*256*2);
    bf16* c4wt   = (bf16*)alloc((size_t)256*128*2);
    bf16* c5wt   = (bf16*)alloc((size_t)128*64*2);
    bf16* u1t    = (bf16*)alloc(128*128*2);
    bf16* u2t    = (bf16*)alloc(64*128*2);
    bf16* u3t    = (bf16*)alloc(32*64*2);
    float* sigt  = (float*)alloc(128*4);
    float* cconst= (float*)alloc(4);
    bf16* cbuf2 = (bf16*)(xxb);
    bf16* cbuf3 = (bf16*)(xxb + (16u<<20));
    bf16* cbuf4 = (bf16*)(xxb + (32u<<20));
    bf16* cbuf5 = (bf16*)(xxb + (48u<<20));
    bf16* ubuf1 = (bf16*)(xxb + (64u<<20));
    bf16* ubuf2 = (bf16*)(xxb + (80u<<20));
    bf16* ubuf3 = (bf16*)(xxb + (96u<<20));
    (void)ws_size; (void)in_sizes; (void)n_in; (void)out_size;

    k_prepw<<<10,256,0,stream>>>(qw,qb,kw,kb,t_w,t_b,a1w,mextT,sigt,cconst);
    k_transpose_cvt<<<dim3(4,4),256,0,stream>>>(vw,  wvT, 128,128);
    k_transpose_cvt<<<dim3(4,4),256,0,stream>>>(a2w, wa2t,128,128);
    k_tc_kappa8<<<dim3(16,400),256,0,stream>>>(c1w, c1wtk8);
    k_transpose_cvt<<<dim3(16,16),256,0,stream>>>(c2w, c2wt, 512,512);
    k_transpose_cvt<<<dim3(8,16),256,0,stream>>>(c3w, c3wt, 512,256);
    k_transpose_cvt<<<dim3(4,8),256,0,stream>>>(c4w, c4wt, 256,128);
    k_transpose_cvt<<<dim3(2,4),256,0,stream>>>(c5w, c5wt, 128,64);
    k_transpose_cvt<<<dim3(4,4),256,0,stream>>>(u1w, u1t, 128,128);
    k_transpose_cvt<<<dim3(2,4),256,0,stream>>>(u2w, u2t, 128,64);
    k_transpose_cvt<<<dim3(1,2),256,0,stream>>>(u3w, u3t, 64,32);

    k_gatt<<<7168,256,0,stream>>>(feat, emb, wa2t, a2b, a3w, sigt, attg);

    k_attn2<<<B_,512,0,stream>>>(feat,emb,mextT,wvT,vb,cconst,attg, xxb, xtb);

    k_gemm_fp8<<<dim3(4,64,SPLIT_),256,0,stream>>>(xxb, c1wtk8, part, B_,512,KC_, KC_/SPLIT_);
    k_c1fin<<<4096,256,0,stream>>>(part, c1b, cbuf1);

    k_gemm<128,true><<<dim3(4,64),256,0,stream>>>(cbuf1, c2wt, c2b, cbuf2, B_,512,512);
    k_gemm<128,true><<<dim3(2,64),256,0,stream>>>(cbuf2, c3wt, c3b, cbuf3, B_,256,512);
    k_gemm<128,true><<<dim3(1,64),256,0,stream>>>(cbuf3, c4wt, c4b, cbuf4, B_,128,256);
    k_gemm<64, true><<<dim3(1,64),256,0,stream>>>(cbuf4, c5wt, c5b, cbuf5, B_,64,128);
    k_heads<<<2048,256,0,stream>>>(cbuf5,clw,clb,ctw,ctb,outp);

    k_gemm<128,true><<<dim3(1,64),256,0,stream>>>(xtb,   u1t, u1b, ubuf1, B_,128,128);
    k_gemm<64, true><<<dim3(1,64),256,0,stream>>>(ubuf1, u2t, u2b, ubuf2, B_,64,128);
    k_gemm<32, true><<<dim3(1,64),256,0,stream>>>(ubuf2, u3t, u3b, ubuf3, B_,32,64);
    k_utail<<<2048,256,0,stream>>>(ubuf3,u4w,u4b,tlw,tlb,utw,utb,outp);
}

// Round 11
// 839.325 us; speedup vs baseline: 2.5251x; 1.0090x over previous
//
#include <hip/hip_runtime.h>
#include <hip/hip_bf16.h>

typedef __bf16 bf16;
typedef __bf16 bf16x8 __attribute__((ext_vector_type(8)));
typedef __bf16 bf16x4 __attribute__((ext_vector_type(4)));
typedef float f32x4 __attribute__((ext_vector_type(4)));
typedef unsigned u32x4 __attribute__((ext_vector_type(4)));

#define DEVI static __device__ __forceinline__

DEVI float sigmoidf_(float x){ return 1.0f/(1.0f+__expf(-x)); }
DEVI float eluf_(float x){ return x>0.f ? x : (__expf(x)-1.f); }
DEVI f32x4 mfma16(bf16x8 a, bf16x8 b, f32x4 c){ return __builtin_amdgcn_mfma_f32_16x16x32_bf16(a,b,c,0,0,0); }
DEVI f32x4 mfma8(long a, long b, f32x4 c){ return __builtin_amdgcn_mfma_f32_16x16x32_fp8_fp8(a,b,c,0,0,0); }
DEVI unsigned pack2_(float a, float b){
    union { bf16 v[2]; unsigned u; } t; t.v[0]=(bf16)a; t.v[1]=(bf16)b; return t.u;
}
DEVI unsigned long long pack4_(float a, float b, float c, float d){
    union { bf16 v[4]; unsigned long long u; } t;
    t.v[0]=(bf16)a; t.v[1]=(bf16)b; t.v[2]=(bf16)c; t.v[3]=(bf16)d; return t.u;
}
DEVI unsigned cvtfp8x4_(float a, float b, float c, float d){
    int v = __builtin_amdgcn_cvt_pk_fp8_f32(a, b, 0, false);
    v = __builtin_amdgcn_cvt_pk_fp8_f32(c, d, v, true);
    return (unsigned)v;
}
DEVI bf16x8 ldb64x2(const bf16* p0, const bf16* p1){
    union { bf16x8 v8; bf16x4 v4[2]; } u;
    u.v4[0] = *(const bf16x4*)p0;
    u.v4[1] = *(const bf16x4*)p1;
    return u.v8;
}

#define B_ 8192
#define F_ 100
#define FP 112
#define H_ 128
#define KC_ 12800   // compact kappa-blocked K: 48*256 + 8*64
#define SPLIT_ 4
#define FP8SC 16.0f

// ---------------- weight prep ----------------
__global__ void k_prepw(const float* __restrict__ qw, const float* __restrict__ qb,
                        const float* __restrict__ kw, const float* __restrict__ kb,
                        const float* __restrict__ tw, const float* __restrict__ tb,
                        const float* __restrict__ a1w,
                        bf16* __restrict__ mextT, float* __restrict__ sigt, float* __restrict__ cconst){
    const float rsc = 0.08838834764831845f;
    int blk = blockIdx.x, tid = threadIdx.x;
    if (blk < 9){
        #pragma unroll 1
        for (int e=0; e<8; ++e){
            int idx = e*256 + tid;
            int n = blk*16 + (idx>>7), h = idx&127;
            float acc = 0.f;
            if (n < 128){
                for (int d=0; d<128; ++d) acc += qw[h*128+d]*kw[n*128+d];
            } else if (n == 128){
                for (int d=0; d<128; ++d) acc += qw[h*128+d]*kb[d];
            } else if (n == 129){
                for (int d=0; d<128; ++d) acc += kw[h*128+d]*qb[d];
            }
            mextT[n*128+h] = (bf16)(acc*rsc);
        }
    } else {
        if (tid < 128){
            float acc = 0.f;
            for (int h=0; h<128; ++h) acc += (tw[h]+tb[h]) * a1w[h*128+tid];
            sigt[tid] = sigmoidf_(acc);
        } else if (tid == 128){
            float acc = 0.f;
            for (int d=0; d<128; ++d) acc += qb[d]*kb[d];
            cconst[0] = acc*rsc;
        }
    }
}

// in [R][C] f32 -> out [C][R] bf16
__global__ void k_transpose_cvt(const float* __restrict__ in, bf16* __restrict__ out, int R, int C){
    __shared__ float t[32][33];
    int c0 = blockIdx.x*32, r0 = blockIdx.y*32;
    int tc = threadIdx.x & 31, tr = threadIdx.x >> 5;
    #pragma unroll
    for (int i=0;i<4;i++){
        int r = tr + i*8;
        t[r][tc] = in[(size_t)(r0+r)*C + c0 + tc];
    }
    __syncthreads();
    #pragma unroll
    for (int i=0;i<4;i++){
        int ro = tr + i*8;
        out[(size_t)(c0+ro)*R + r0 + tc] = (bf16)t[tc][ro];
    }
}

// compact kappa: bijection on [0,12800). In-tile idx = 4*lane + j (lane-linear PV store)
DEVI int kappa_(int k){
    int f = k>>7, h = k&127;
    if (f < 96)
        return (((f>>4)<<3) | (h>>4))*256 + ((f&15)>>2)*64 + (h&15)*4 + (f&3);
    else
        return 12288 + (h>>4)*64 + (h&15)*4 + (f&3);
}
__global__ void k_tc_kappa8(const float* __restrict__ in, unsigned char* __restrict__ out){
    __shared__ float t[32][33];
    const int C = 512;
    int c0 = blockIdx.x*32, r0 = blockIdx.y*32;
    int tc = threadIdx.x & 31, tr = threadIdx.x >> 5;
    #pragma unroll
    for (int i=0;i<4;i++){
        int r = tr + i*8;
        t[r][tc] = in[(size_t)(r0+r)*C + c0 + tc];
    }
    __syncthreads();
    #pragma unroll
    for (int i=0;i<4;i++){
        int ro = tr + i*8;
        float x = t[tc][ro]*FP8SC;
        int v = __builtin_amdgcn_cvt_pk_fp8_f32(x, x, 0, false);
        out[(size_t)(c0+ro)*KC_ + kappa_(r0+tc)] = (unsigned char)v;
    }
}

// ---------------- flat GEMM for interaction-attention scores ----------------
__global__ __launch_bounds__(256,2) void k_gatt(
    const float* __restrict__ feat, const float* __restrict__ emb,
    const bf16* __restrict__ wa2t, const float* __restrict__ a2b,
    const float* __restrict__ a3w, const float* __restrict__ sigt,
    float* __restrict__ attg)
{
    __shared__ bf16 sAt[128][72];
    __shared__ bf16 sBt[128][72];
    __shared__ float sRed[2][128];
    int tid=threadIdx.x, w=tid>>6, lane=tid&63, l15=lane&15, l4=lane>>4;
    int m0 = blockIdx.x*128;
    int wr = w>>1, wc = w&1;
    f32x4 acc[4][4];
    #pragma unroll
    for(int mi=0;mi<4;mi++)
        #pragma unroll
        for(int ni=0;ni<4;ni++) acc[mi][ni] = (f32x4){0.f,0.f,0.f,0.f};

    #pragma unroll 1
    for (int k0=0; k0<128; k0+=64){
        __syncthreads();
        #pragma unroll
        for (int t4=0; t4<4; t4++){
            int t = tid + t4*256;
            int row=t>>3, col=(t&7)*8;
            int gr = m0+row;
            int bb = gr/112, ff = gr - bb*112;
            bf16x8 o;
            if (ff < F_){
                float fv = feat[(size_t)bb*F_ + ff];
                const float* ep = emb + ff*H_ + k0 + col;
                f32x4 e0 = *(const f32x4*)ep;
                f32x4 e1 = *(const f32x4*)(ep+4);
                o[0]=(bf16)(fv*e0[0]); o[1]=(bf16)(fv*e0[1]); o[2]=(bf16)(fv*e0[2]); o[3]=(bf16)(fv*e0[3]);
                o[4]=(bf16)(fv*e1[0]); o[5]=(bf16)(fv*e1[1]); o[6]=(bf16)(fv*e1[2]); o[7]=(bf16)(fv*e1[3]);
            } else {
                #pragma unroll
                for (int e=0;e<8;e++) o[e]=(bf16)0.f;
            }
            *(bf16x8*)&sAt[row][col] = o;
            *(bf16x8*)&sBt[row][col] = *(const bf16x8*)(wa2t + row*H_ + k0 + col);
        }
        __syncthreads();
        #pragma unroll
        for(int ks=0;ks<2;ks++){
            bf16x8 af[4], bfr[4];
            #pragma unroll
            for(int mi=0;mi<4;mi++) af[mi] = *(const bf16x8*)&sAt[wr*64+mi*16+l15][ks*32+l4*8];
            #pragma unroll
            for(int ni=0;ni<4;ni++) bfr[ni] = *(const bf16x8*)&sBt[wc*64+ni*16+l15][ks*32+l4*8];
            #pragma unroll
            for(int mi=0;mi<4;mi++)
                #pragma unroll
                for(int ni=0;ni<4;ni++)
                    acc[mi][ni] = mfma16(af[mi], bfr[ni], acc[mi][ni]);
        }
    }
    float sg[4], ab[4], a3[4];
    #pragma unroll
    for (int ni=0;ni<4;ni++){
        int n = wc*64 + ni*16 + l15;
        sg[ni]=sigt[n]; ab[ni]=a2b[n]; a3[ni]=a3w[n];
    }
    #pragma unroll
    for (int mi=0;mi<4;mi++){
        float sj[4] = {0.f,0.f,0.f,0.f};
        #pragma unroll
        for (int ni=0;ni<4;ni++){
            #pragma unroll
            for (int j=0;j<4;j++){
                float u = sigmoidf_(acc[mi][ni][j] + ab[ni]);
                float t = sg[ni] + u;
                t = t>0.f ? t : 0.f;
                sj[j] += t*a3[ni];
            }
        }
        #pragma unroll
        for (int j=0;j<4;j++){
            float v = sj[j];
            #pragma unroll
            for (int m=1;m<16;m<<=1) v += __shfl_xor(v,m,16);
            sj[j]=v;
        }
        if (l15==0){
            #pragma unroll
            for (int j=0;j<4;j++) sRed[wc][wr*64+mi*16+l4*4+j] = sj[j];
        }
    }
    __syncthreads();
    if (tid < 128) attg[(size_t)m0 + tid] = sRed[0][tid] + sRed[1][tid];
}

// ---------------- fused per-batch attention: 512 thr, slim sP -> 3 blocks/CU ----------------
// LDS (52608 B):
//   [0,30464)       sNx[112][136] bf16  UNION  sVT[128][116] bf16
//   [30720,49152)   sP[8][16][72] bf16 (per-wave slot; two-pass scores/PV)
//                   pre-B5 aliases: sFeat@30720, sAw@31232, normP[8][128]@31744
//   [49152,50560)   sNorm[128], sAlpha[112], sBeta[112]
//   [50560,52608)   xtP[4][128]
__global__ __launch_bounds__(512,3) void k_attn2(
    const float* __restrict__ feat, const float* __restrict__ emb,
    const bf16* __restrict__ mextT, const bf16* __restrict__ wvT,
    const float* __restrict__ vb, const float* __restrict__ cconst,
    const float* __restrict__ attg,
    unsigned char* __restrict__ xxb, bf16* __restrict__ xtb)
{
    __shared__ char L[52608];
    bf16 (*sNx)[136] = (bf16(*)[136])L;
    bf16 (*sVT)[116] = (bf16(*)[116])L;
    float* sFeat  = (float*)(L+30720);
    float* sAw    = (float*)(L+31232);
    float* normP  = (float*)(L+31744);   // [8][128]
    float* sNorm  = (float*)(L+49152);
    float* sAlpha = (float*)(L+49664);
    float* sBeta  = (float*)(L+50112);
    float* xtP    = (float*)(L+50560);   // [4][128]

    int b = blockIdx.x;
    int tid = threadIdx.x, w = tid>>6, lane = tid&63;
    int l15 = lane&15, l4 = lane>>4;
    bf16 (*sP)[72] = (bf16(*)[72])(L + 30720 + w*2304);

    if (tid < FP) sFeat[tid] = (tid<F_) ? feat[(size_t)b*F_+tid] : 0.f;
    if (w==0){
        const float* ag = attg + (size_t)b*FP;
        float a0 = (lane<F_)? ag[lane] : -1e30f;
        float a1 = (lane+64<F_)? ag[lane+64] : -1e30f;
        float m = fmaxf(a0,a1);
        #pragma unroll
        for(int s=1;s<64;s<<=1) m = fmaxf(m, __shfl_xor(m,s,64));
        float e0 = (lane<F_)? __expf(a0-m):0.f;
        float e1 = (lane+64<F_)? __expf(a1-m):0.f;
        float s = e0+e1;
        #pragma unroll
        for(int t=1;t<64;t<<=1) s += __shfl_xor(s,t,64);
        float inv = 1.f/s;
        if (lane<FP) sAw[lane] = e0*inv;
        if (lane+64<FP) sAw[lane+64] = e1*inv;
    }
    __syncthreads();   // B1

    // pass1: column sums of squares only (no LDS staging)
    int hp = (tid&63)*2, gg = tid>>6;
    {
        float fa0=0.f, fa1=0.f;
        #pragma unroll 4
        for (int it=0; it<13; ++it){
            int f = gg + 8*it;
            if (f < F_){
                float2 e2 = *(const float2*)(emb + f*H_ + hp);
                float v0 = sFeat[f]*e2.x, v1 = sFeat[f]*e2.y;
                fa0 += v0*v0; fa1 += v1*v1;
            }
        }
        *(float2*)(normP + gg*128 + hp) = make_float2(fa0, fa1);
    }
    __syncthreads();   // B2
    if (tid < 128){
        float s = 0.f;
        #pragma unroll
        for (int g2=0; g2<8; ++g2) s += normP[g2*128 + tid];
        sNorm[tid] = sqrtf(s);
    }
    __syncthreads();   // B3

    // pass2: write nx pre-scaled (re-read emb from L2), zero pad rows
    {
        float rn0 = __builtin_amdgcn_rcpf(sNorm[hp]);
        float rn1 = __builtin_amdgcn_rcpf(sNorm[hp+1]);
        #pragma unroll 4
        for (int it=0; it<13; ++it){
            int f = gg + 8*it;
            if (f < F_){
                float2 e2 = *(const float2*)(emb + f*H_ + hp);
                *(unsigned*)(&sNx[f][hp]) = pack2_(sFeat[f]*e2.x*rn0, sFeat[f]*e2.y*rn1);
            }
        }
        for (int z=tid; z<768; z+=512){
            int f = 100 + (z>>6), hz = (z&63)*2;
            *(unsigned*)(&sNx[f][hz]) = 0u;
        }
    }
    __syncthreads();   // B4

    int mt = w;   // this wave's f-tile (w==7 idle in mt-phases)

    // alpha/beta (wave w<7) + xt partials (all threads)
    if (mt < 7){
        bf16x8 bfr8[4];
        #pragma unroll
        for (int kc=0;kc<4;kc++)
            bfr8[kc] = *(const bf16x8*)(mextT + (128+l15)*H_ + kc*32 + l4*8);
        f32x4 acc = {0.f,0.f,0.f,0.f};
        #pragma unroll
        for (int kc=0;kc<4;kc++){
            bf16x8 a = *(const bf16x8*)(&sNx[mt*16+l15][kc*32+l4*8]);
            acc = mfma16(a, bfr8[kc], acc);
        }
        if (l15==0){
            #pragma unroll
            for (int j=0;j<4;j++) sAlpha[mt*16+l4*4+j] = acc[j];
        }
        if (l15==1){
            #pragma unroll
            for (int j=0;j<4;j++) sBeta[mt*16+l4*4+j] = acc[j];
        }
    }
    {
        int g4 = tid>>7, h = tid&127;
        float acc=0.f;
        #pragma unroll 5
        for (int it=0; it<25; ++it){
            int f = g4 + 4*it;
            acc += sAw[f]*(float)sNx[f][h];
        }
        xtP[g4*128+h] = acc;
    }
    __syncthreads();   // B5
    if (tid < 128)
        xtb[(size_t)b*H_+tid] = (bf16)((xtP[tid]+xtP[128+tid]+xtP[256+tid]+xtP[384+tid]) * sNorm[tid]);

    // ---- S1 (two-pass, per-wave 16x72 slot) + scores + e ----
    const float cc = cconst[0];
    unsigned uexB[3][2];   // e for gt 4..6 (pass-B), packed
    float inv_[4];
    if (mt < 7){
        bf16x8 afxi[4];
        #pragma unroll
        for (int kc=0;kc<4;kc++)
            afxi[kc] = *(const bf16x8*)(&sNx[mt*16+l15][kc*32+l4*8]);
        f32x4 sc[7];
        #pragma unroll
        for (int gt=0; gt<7; gt++) sc[gt] = (f32x4){0.f,0.f,0.f,0.f};
        #pragma unroll 1
        for (int p=0; p<2; p++){
            #pragma unroll 2
            for (int nt4=0; nt4<4; nt4++){
                int nt = p*4 + nt4;
                bf16x8 bw[4];
                #pragma unroll
                for (int kc=0;kc<4;kc++)
                    bw[kc] = *(const bf16x8*)(mextT + (nt*16+l15)*H_ + kc*32 + l4*8);
                f32x4 d = {0.f,0.f,0.f,0.f};
                #pragma unroll
                for (int kc=0;kc<4;kc++) d = mfma16(afxi[kc], bw[kc], d);
                #pragma unroll
                for (int j=0;j<4;j++) sP[l4*4+j][nt4*16+l15] = (bf16)d[j];
            }
            bf16x8 afs0 = *(const bf16x8*)&sP[l15][l4*8];
            bf16x8 afs1 = *(const bf16x8*)&sP[l15][32+l4*8];
            #pragma unroll
            for (int gt=0; gt<7; gt++){
                bf16x8 b0 = *(const bf16x8*)&sNx[gt*16+l15][p*64 + l4*8];
                bf16x8 b1 = *(const bf16x8*)&sNx[gt*16+l15][p*64 + 32 + l4*8];
                sc[gt] = mfma16(afs0, b0, sc[gt]);
                sc[gt] = mfma16(afs1, b1, sc[gt]);
            }
        }
        float aj[4];
        #pragma unroll
        for (int j=0;j<4;j++) aj[j] = sAlpha[mt*16+l4*4+j];
        float rs[4] = {0.f,0.f,0.f,0.f};
        #pragma unroll
        for (int gt=0; gt<7; gt++){
            float bg = sBeta[gt*16+l15];
            int g = gt*16+l15;
            float e[4];
            #pragma unroll
            for (int j=0;j<4;j++){
                float val = sc[gt][j] + aj[j] + bg + cc;
                e[j] = (g<F_) ? __expf(sigmoidf_(val)) : 0.f;
                rs[j] += e[j];
            }
            if (gt < 4){
                #pragma unroll
                for (int j=0;j<4;j++) sP[l4*4+j][gt*16+l15] = (bf16)e[j];
            } else {
                uexB[gt-4][0] = pack2_(e[0],e[1]);
                uexB[gt-4][1] = pack2_(e[2],e[3]);
            }
        }
        #pragma unroll
        for (int j=0;j<4;j++){
            float v = rs[j];
            #pragma unroll
            for (int m2=1;m2<16;m2<<=1) v += __shfl_xor(v,m2,16);
            inv_[j] = 1.f/v;
        }
    }

    // ---- V^T row-tile (all 8 waves) ----
    unsigned vpk[7][2];
    {
        int ht = w;
        bf16x8 awv[4];
        #pragma unroll
        for (int kc=0;kc<4;kc++)
            awv[kc] = *(const bf16x8*)(wvT + (ht*16+l15)*H_ + kc*32 + l4*8);
        float vb0 = vb[ht*16+l4*4], vb1 = vb[ht*16+l4*4+1], vb2 = vb[ht*16+l4*4+2], vb3 = vb[ht*16+l4*4+3];
        #pragma unroll
        for (int gt=0; gt<7; gt++){
            f32x4 acc = {0.f,0.f,0.f,0.f};
            #pragma unroll
            for (int kc=0;kc<4;kc++){
                bf16x8 bfr = *(const bf16x8*)(&sNx[gt*16+l15][kc*32+l4*8]);
                acc = mfma16(awv[kc], bfr, acc);
            }
            vpk[gt][0] = pack2_(acc[0]+vb0, acc[1]+vb1);
            vpk[gt][1] = pack2_(acc[2]+vb2, acc[3]+vb3);
        }
    }
    __syncthreads();   // B6: all sNx reads complete

    union UP { unsigned u; bf16 v[2]; };
    {
        int ht = w;
        #pragma unroll
        for (int gt=0; gt<7; gt++){
            UP u0, u1;
            u0.u = vpk[gt][0]; u1.u = vpk[gt][1];
            sVT[ht*16+l4*4  ][gt*16+l15] = u0.v[0];
            sVT[ht*16+l4*4+1][gt*16+l15] = u0.v[1];
            sVT[ht*16+l4*4+2][gt*16+l15] = u1.v[0];
            sVT[ht*16+l4*4+3][gt*16+l15] = u1.v[1];
        }
    }
    __syncthreads();   // B7

    // ---- PV: two passes over g; normalization deferred to epilogue ----
    if (mt < 7){
        bf16x8 ap0 = *(const bf16x8*)&sP[l15][l4*8];
        bf16x8 ap1 = *(const bf16x8*)&sP[l15][32+l4*8];
        f32x4 acc8[8];
        #pragma unroll
        for (int ht=0;ht<8;ht++) acc8[ht] = (f32x4){0.f,0.f,0.f,0.f};
        #pragma unroll
        for (int ht=0; ht<8; ht++){
            const bf16* vr = &sVT[ht*16+l15][0];
            int c0 = l4*8, c1 = 32+l4*8;
            acc8[ht] = mfma16(ap0, ldb64x2(vr+c0, vr+c0+4), acc8[ht]);
            acc8[ht] = mfma16(ap1, ldb64x2(vr+c1, vr+c1+4), acc8[ht]);
        }
        // restage pass-B e (gt 4..6 + zero tile)
        #pragma unroll
        for (int gt=4; gt<7; gt++){
            #pragma unroll
            for (int j2=0; j2<2; j2++){
                UP u; u.u = uexB[gt-4][j2];
                sP[l4*4+j2*2  ][(gt-4)*16+l15] = u.v[0];
                sP[l4*4+j2*2+1][(gt-4)*16+l15] = u.v[1];
            }
        }
        #pragma unroll
        for (int j=0;j<4;j++) sP[l4*4+j][48+l15] = (bf16)0.f;
        bf16x8 ap2 = *(const bf16x8*)&sP[l15][l4*8];
        bf16x8 ap3 = *(const bf16x8*)&sP[l15][32+l4*8];
        #pragma unroll
        for (int ht=0; ht<8; ht++){
            const bf16* vr = &sVT[ht*16+l15][0];
            int c2 = 64+l4*8;
            int c3 = 96+l4*8;  if (c3 >= 112) c3 = 96;
            acc8[ht] = mfma16(ap2, ldb64x2(vr+c2, vr+c2+4), acc8[ht]);
            acc8[ht] = mfma16(ap3, ldb64x2(vr+c3, vr+c3+4), acc8[ht]);
        }
        float fs[4];
        #pragma unroll
        for (int j=0;j<4;j++) fs[j] = inv_[j]*FP8SC;
        #pragma unroll
        for (int ht=0; ht<8; ht++){
            unsigned u = cvtfp8x4_(acc8[ht][0]*fs[0], acc8[ht][1]*fs[1], acc8[ht][2]*fs[2], acc8[ht][3]*fs[3]);
            if (mt < 6){
                *(unsigned*)(xxb + (size_t)b*KC_ + (mt*8+ht)*256 + lane*4) = u;
            } else if (l4 == 0){
                *(unsigned*)(xxb + (size_t)b*KC_ + 12288 + ht*64 + l15*4) = u;
            }
        }
    }
}

// ---------------- fp8 split-K GEMM ----------------
__global__ __launch_bounds__(256,2) void k_gemm_fp8(const unsigned char* __restrict__ A,
        const unsigned char* __restrict__ Bt, float* __restrict__ part, int M, int N, int K, int KS)
{
    __shared__ unsigned char sA[128][72];
    __shared__ unsigned char sB[128][72];
    int tid=threadIdx.x, w=tid>>6, lane=tid&63, l15=lane&15, l4=lane>>4;
    int m0 = blockIdx.y*128, n0 = blockIdx.x*128;
    int kbeg = blockIdx.z*KS, kend = kbeg + KS;
    int wr = w>>1, wc = w&1;
    f32x4 acc[4][4];
    #pragma unroll
    for(int mi=0;mi<4;mi++)
        #pragma unroll
        for(int ni=0;ni<4;ni++) acc[mi][ni] = (f32x4){0.f,0.f,0.f,0.f};

    for (int k0=kbeg; k0<kend; k0+=64){
        __syncthreads();
        #pragma unroll
        for (int t2=0;t2<2;t2++){
            int t = tid + t2*256;
            int row=t>>2, col=(t&3)*16;
            *(u32x4*)&sA[row][col] = *(const u32x4*)(A + (size_t)(m0+row)*K + k0 + col);
            *(u32x4*)&sB[row][col] = *(const u32x4*)(Bt + (size_t)(n0+row)*K + k0 + col);
        }
        __syncthreads();
        #pragma unroll
        for(int ks=0;ks<2;ks++){
            long af[4], bfr[4];
            #pragma unroll
            for(int mi=0;mi<4;mi++) af[mi] = *(const long*)&sA[wr*64+mi*16+l15][ks*32+l4*8];
            #pragma unroll
            for(int ni=0;ni<4;ni++) bfr[ni] = *(const long*)&sB[wc*64+ni*16+l15][ks*32+l4*8];
            #pragma unroll
            for(int mi=0;mi<4;mi++)
                #pragma unroll
                for(int ni=0;ni<4;ni++)
                    acc[mi][ni] = mfma8(af[mi], bfr[ni], acc[mi][ni]);
        }
    }
    float* pz = part + (size_t)blockIdx.z*M*N;
    #pragma unroll
    for(int mi=0;mi<4;mi++)
        #pragma unroll
        for(int ni=0;ni<4;ni++){
            int col = n0 + wc*64 + ni*16 + l15;
            #pragma unroll
            for(int j=0;j<4;j++){
                int row = m0 + wr*64 + mi*16 + l4*4 + j;
                pz[(size_t)row*N + col] = acc[mi][ni][j];
            }
        }
}

__global__ void k_c1fin(const float* __restrict__ part, const float* __restrict__ bias,
                        bf16* __restrict__ out){
    const size_t MN = (size_t)B_*512;
    size_t e0 = ((size_t)blockIdx.x*256 + threadIdx.x)*4;
    f32x4 s = *(const f32x4*)(part + e0);
    s += *(const f32x4*)(part + MN + e0);
    s += *(const f32x4*)(part + 2*MN + e0);
    s += *(const f32x4*)(part + 3*MN + e0);
    f32x4 bb = *(const f32x4*)(bias + (e0 & 511));
    const float ds = 1.0f/(FP8SC*FP8SC);
    unsigned long long u = pack4_(eluf_(s[0]*ds+bb[0]), eluf_(s[1]*ds+bb[1]),
                                  eluf_(s[2]*ds+bb[2]), eluf_(s[3]*ds+bb[3]));
    *(unsigned long long*)(out + e0) = u;
}

// ---------------- generic tiled GEMM ----------------
template<int BN, bool ELU>
__global__ __launch_bounds__(256,2) void k_gemm(const bf16* __restrict__ A, const bf16* __restrict__ Bt,
        const float* __restrict__ bias, bf16* __restrict__ out, int M, int N, int K)
{
    __shared__ bf16 sAt[128][72];
    __shared__ bf16 sBt[BN][72];
    int tid=threadIdx.x, w=tid>>6, lane=tid&63, l15=lane&15, l4=lane>>4;
    int m0 = blockIdx.y*128, n0 = blockIdx.x*BN;
    constexpr int MI = (BN==128)?4:2;
    constexpr int NI = (BN==128)?4:BN/16;
    int wr = (BN==128)? (w>>1) : w;
    int wc = (BN==128)? (w&1) : 0;
    f32x4 acc[MI][NI];
    #pragma unroll
    for(int mi=0;mi<MI;mi++)
        #pragma unroll
        for(int ni=0;ni<NI;ni++) acc[mi][ni] = (f32x4){0.f,0.f,0.f,0.f};

    for (int k0=0; k0<K; k0+=64){
        __syncthreads();
        for (int t=tid; t<128*8; t+=256){
            int row=t>>3, col=(t&7)*8;
            *(bf16x8*)&sAt[row][col] = *(const bf16x8*)(A + (size_t)(m0+row)*K + k0 + col);
        }
        for (int t=tid; t<BN*8; t+=256){
            int row=t>>3, col=(t&7)*8;
            *(bf16x8*)&sBt[row][col] = *(const bf16x8*)(Bt + (size_t)(n0+row)*K + k0 + col);
        }
        __syncthreads();
        #pragma unroll
        for(int ks=0;ks<2;ks++){
            bf16x8 af[MI], bfr[NI];
            #pragma unroll
            for(int mi=0;mi<MI;mi++) af[mi] = *(const bf16x8*)&sAt[wr*(MI*16)+mi*16+l15][ks*32+l4*8];
            #pragma unroll
            for(int ni=0;ni<NI;ni++) bfr[ni] = *(const bf16x8*)&sBt[wc*64+ni*16+l15][ks*32+l4*8];
            #pragma unroll
            for(int mi=0;mi<MI;mi++)
                #pragma unroll
                for(int ni=0;ni<NI;ni++)
                    acc[mi][ni] = mfma16(af[mi], bfr[ni], acc[mi][ni]);
        }
    }
    #pragma unroll
    for(int mi=0;mi<MI;mi++)
        #pragma unroll
        for(int ni=0;ni<NI;ni++){
            int col = n0 + wc*64 + ni*16 + l15;
            float bc = bias[col];
            #pragma unroll
            for(int j=0;j<4;j++){
                int row = m0 + wr*(MI*16) + mi*16 + l4*4 + j;
                float v = acc[mi][ni][j] + bc;
                if (ELU) v = eluf_(v);
                out[(size_t)row*N + col] = (bf16)v;
            }
        }
}

// ---------------- control heads ----------------
__global__ void k_heads(const bf16* __restrict__ c5o, const float* __restrict__ clw, const float* __restrict__ clb,
                        const float* __restrict__ ctw, const float* __restrict__ ctb, float* __restrict__ outp){
    int gid = blockIdx.x*4 + (threadIdx.x>>6);
    int lane = threadIdx.x & 63;
    float v = (float)c5o[(size_t)gid*64 + lane];
    float r1 = v*clw[lane], r2 = v*ctw[lane];
    #pragma unroll
    for(int m=1;m<64;m<<=1){ r1 += __shfl_xor(r1,m,64); r2 += __shfl_xor(r2,m,64); }
    if (lane==0){
        float cl = r1 + clb[0];
        outp[gid] = cl;
        outp[B_ + gid] = sigmoidf_(cl);
        outp[(size_t)2*B_ + gid] = r2 + ctb[0];
    }
}

// ---------------- uplift tail ----------------
__global__ void k_utail(const bf16* __restrict__ u3o, const float* __restrict__ u4w, const float* __restrict__ u4b,
                        const float* __restrict__ tlw, const float* __restrict__ tlb,
                        const float* __restrict__ utw, const float* __restrict__ utb, float* __restrict__ outp){
    int row = blockIdx.x*4 + (threadIdx.x>>6);
    int lane = threadIdx.x & 63;
    int j = lane & 15;
    float acc = u4b[j];
    #pragma unroll 4
    for (int h=0; h<32; ++h) acc += (float)u3o[(size_t)row*32+h] * u4w[h*16+j];
    float u4 = eluf_(acc);
    float r1 = u4*tlw[j], r2 = u4*utw[j];
    #pragma unroll
    for(int m=1;m<16;m<<=1){ r1 += __shfl_xor(r1,m,16); r2 += __shfl_xor(r2,m,16); }
    if (lane==0){
        float tl = r1 + tlb[0];
        outp[(size_t)3*B_ + row] = tl;
        outp[(size_t)4*B_ + row] = sigmoidf_(tl);
        outp[(size_t)5*B_ + row] = r2 + utb[0];
    }
}

extern "C" void kernel_launch(void* const* d_in, const int* in_sizes, int n_in,
                              void* d_out, int out_size, void* d_ws, size_t ws_size,
                              hipStream_t stream) {
    const float* feat=(const float*)d_in[0];
    const float* emb =(const float*)d_in[2];
    const float* t_w =(const float*)d_in[3]; const float* t_b=(const float*)d_in[4];
    const float* qw  =(const float*)d_in[5]; const float* qb =(const float*)d_in[6];
    const float* kw  =(const float*)d_in[7]; const float* kb =(const float*)d_in[8];
    const float* vw  =(const float*)d_in[9]; const float* vb =(const float*)d_in[10];
    const float* a1w =(const float*)d_in[11];
    const float* a2w =(const float*)d_in[12]; const float* a2b=(const float*)d_in[13];
    const float* a3w =(const float*)d_in[14];
    const float* c1w =(const float*)d_in[15]; const float* c1b=(const float*)d_in[16];
    const float* c2w =(const float*)d_in[17]; const float* c2b=(const float*)d_in[18];
    const float* c3w =(const float*)d_in[19]; const float* c3b=(const float*)d_in[20];
    const float* c4w =(const float*)d_in[21]; const float* c4b=(const float*)d_in[22];
    const float* c5w =(const float*)d_in[23]; const float* c5b=(const float*)d_in[24];
    const float* clw =(const float*)d_in[25]; const float* clb=(const float*)d_in[26];
    const float* ctw =(const float*)d_in[27]; const float* ctb=(const float*)d_in[28];
    const float* u1w =(const float*)d_in[29]; const float* u1b=(const float*)d_in[30];
    const float* u2w =(const float*)d_in[31]; const float* u2b=(const float*)d_in[32];
    const float* u3w =(const float*)d_in[33]; const float* u3b=(const float*)d_in[34];
    const float* u4w =(const float*)d_in[35]; const float* u4b=(const float*)d_in[36];
    const float* tlw =(const float*)d_in[37]; const float* tlb=(const float*)d_in[38];
    const float* utw =(const float*)d_in[39]; const float* utb=(const float*)d_in[40];
    float* outp = (float*)d_out;

    char* ws = (char*)d_ws;
    size_t off = 0;
    auto alloc = [&](size_t bytes)->char*{ char* p = ws + off; off += (bytes + 255) & ~(size_t)255; return p; };
    unsigned char* xxb = (unsigned char*)alloc((size_t)B_*KC_);          // 104.9 MB fp8
    float* part  = (float*)alloc((size_t)SPLIT_*B_*512*4);               // 67.1 MB
    float* attg  = (float*)alloc((size_t)B_*FP*4);                       // 3.7 MB
    bf16* xtb    = (bf16*)alloc((size_t)B_*128*2);
    bf16* cbuf1  = (bf16*)alloc((size_t)B_*512*2);
    bf16* mextT  = (bf16*)alloc(144*128*2);
    bf16* wvT    = (bf16*)alloc(128*128*2);
    bf16* wa2t   = (bf16*)alloc(128*128*2);
    unsigned char* c1wtk8 = (unsigned char*)alloc((size_t)512*KC_);
    bf16* c2wt   = (bf16*)alloc((size_t)512*512*2);
    bf16* c3wt   = (bf16*)alloc((size_t)512*256*2);
    bf16* c4wt   = (bf16*)alloc((size_t)256*128*2);
    bf16* c5wt   = (bf16*)alloc((size_t)128*64*2);
    bf16* u1t    = (bf16*)alloc(128*128*2);
    bf16* u2t    = (bf16*)alloc(64*128*2);
    bf16* u3t    = (bf16*)alloc(32*64*2);
    float* sigt  = (float*)alloc(128*4);
    float* cconst= (float*)alloc(4);
    bf16* cbuf2 = (bf16*)(xxb);
    bf16* cbuf3 = (bf16*)(xxb + (16u<<20));
    bf16* cbuf4 = (bf16*)(xxb + (32u<<20));
    bf16* cbuf5 = (bf16*)(xxb + (48u<<20));
    bf16* ubuf1 = (bf16*)(xxb + (64u<<20));
    bf16* ubuf2 = (bf16*)(xxb + (80u<<20));
    bf16* ubuf3 = (bf16*)(xxb + (96u<<20));
    (void)ws_size; (void)in_sizes; (void)n_in; (void)out_size;

    k_prepw<<<10,256,0,stream>>>(qw,qb,kw,kb,t_w,t_b,a1w,mextT,sigt,cconst);
    k_transpose_cvt<<<dim3(4,4),256,0,stream>>>(vw,  wvT, 128,128);
    k_transpose_cvt<<<dim3(4,4),256,0,stream>>>(a2w, wa2t,128,128);
    k_tc_kappa8<<<dim3(16,400),256,0,stream>>>(c1w, c1wtk8);
    k_transpose_cvt<<<dim3(16,16),256,0,stream>>>(c2w, c2wt, 512,512);
    k_transpose_cvt<<<dim3(8,16),256,0,stream>>>(c3w, c3wt, 512,256);
    k_transpose_cvt<<<dim3(4,8),256,0,stream>>>(c4w, c4wt, 256,128);
    k_transpose_cvt<<<dim3(2,4),256,0,stream>>>(c5w, c5wt, 128,64);
    k_transpose_cvt<<<dim3(4,4),256,0,stream>>>(u1w, u1t, 128,128);
    k_transpose_cvt<<<dim3(2,4),256,0,stream>>>(u2w, u2t, 128,64);
    k_transpose_cvt<<<dim3(1,2),256,0,stream>>>(u3w, u3t, 64,32);

    k_gatt<<<7168,256,0,stream>>>(feat, emb, wa2t, a2b, a3w, sigt, attg);

    k_attn2<<<B_,512,0,stream>>>(feat,emb,mextT,wvT,vb,cconst,attg, xxb, xtb);

    k_gemm_fp8<<<dim3(4,64,SPLIT_),256,0,stream>>>(xxb, c1wtk8, part, B_,512,KC_, KC_/SPLIT_);
    k_c1fin<<<4096,256,0,stream>>>(part, c1b, cbuf1);

    k_gemm<128,true><<<dim3(4,64),256,0,stream>>>(cbuf1, c2wt, c2b, cbuf2, B_,512,512);
    k_gemm<128,true><<<dim3(2,64),256,0,stream>>>(cbuf2, c3wt, c3b, cbuf3, B_,256,512);
    k_gemm<128,true><<<dim3(1,64),256,0,stream>>>(cbuf3, c4wt, c4b, cbuf4, B_,128,256);
    k_gemm<64, true><<<dim3(1,64),256,0,stream>>>(cbuf4, c5wt, c5b, cbuf5, B_,64,128);
    k_heads<<<2048,256,0,stream>>>(cbuf5,clw,clb,ctw,ctb,outp);

    k_gemm<128,true><<<dim3(1,64),256,0,stream>>>(xtb,   u1t, u1b, ubuf1, B_,128,128);
    k_gemm<64, true><<<dim3(1,64),256,0,stream>>>(ubuf1, u2t, u2b, ubuf2, B_,64,128);
    k_gemm<32, true><<<dim3(1,64),256,0,stream>>>(ubuf2, u3t, u3b, ubuf3, B_,32,64);
    k_utail<<<2048,256,0,stream>>>(ubuf3,u4w,u4b,tlw,tlb,utw,utb,outp);
}

// Round 12
// 728.153 us; speedup vs baseline: 2.9106x; 1.1527x over previous
//
#include <hip/hip_runtime.h>
#include <hip/hip_bf16.h>

typedef __bf16 bf16;
typedef __bf16 bf16x8 __attribute__((ext_vector_type(8)));
typedef __bf16 bf16x4 __attribute__((ext_vector_type(4)));
typedef float f32x4 __attribute__((ext_vector_type(4)));
typedef unsigned u32x4 __attribute__((ext_vector_type(4)));

#define DEVI static __device__ __forceinline__

DEVI float sigmoidf_(float x){ return 1.0f/(1.0f+__expf(-x)); }
DEVI float eluf_(float x){ return x>0.f ? x : (__expf(x)-1.f); }
DEVI f32x4 mfma16(bf16x8 a, bf16x8 b, f32x4 c){ return __builtin_amdgcn_mfma_f32_16x16x32_bf16(a,b,c,0,0,0); }
DEVI f32x4 mfma8(long a, long b, f32x4 c){ return __builtin_amdgcn_mfma_f32_16x16x32_fp8_fp8(a,b,c,0,0,0); }
DEVI unsigned pack2_(float a, float b){
    union { bf16 v[2]; unsigned u; } t; t.v[0]=(bf16)a; t.v[1]=(bf16)b; return t.u;
}
DEVI unsigned long long pack4_(float a, float b, float c, float d){
    union { bf16 v[4]; unsigned long long u; } t;
    t.v[0]=(bf16)a; t.v[1]=(bf16)b; t.v[2]=(bf16)c; t.v[3]=(bf16)d; return t.u;
}
DEVI unsigned cvtfp8x4_(float a, float b, float c, float d){
    int v = __builtin_amdgcn_cvt_pk_fp8_f32(a, b, 0, false);
    v = __builtin_amdgcn_cvt_pk_fp8_f32(c, d, v, true);
    return (unsigned)v;
}
DEVI bf16x8 ldb64x2(const bf16* p0, const bf16* p1){
    union { bf16x8 v8; bf16x4 v4[2]; } u;
    u.v4[0] = *(const bf16x4*)p0;
    u.v4[1] = *(const bf16x4*)p1;
    return u.v8;
}

#define B_ 8192
#define F_ 100
#define FP 112
#define H_ 128
#define KC_ 12800
#define SPLIT_ 4
#define FP8SC 16.0f

// XOR swizzle: spread row-major columns across banks (write & read use same map)
#define SWZ(r,bc) ((bc) ^ (((r)&7)<<4))

// ---------------- mega weight prep ----------------
DEVI void dotrans_(float (*t)[33], const float* in, bf16* out, int R, int C, int bx, int by, int tid){
    int c0 = bx*32, r0 = by*32;
    int tc = tid & 31, tr = tid >> 5;
    #pragma unroll
    for (int i=0;i<4;i++){
        int r = tr + i*8;
        t[r][tc] = in[(size_t)(r0+r)*C + c0 + tc];
    }
    __syncthreads();
    #pragma unroll
    for (int i=0;i<4;i++){
        int ro = tr + i*8;
        out[(size_t)(c0+ro)*R + r0 + tc] = (bf16)t[tc][ro];
    }
}

__global__ void k_prep_all(const float* __restrict__ qw, const float* __restrict__ qb,
                           const float* __restrict__ kw, const float* __restrict__ kb,
                           const float* __restrict__ tw, const float* __restrict__ tb,
                           const float* __restrict__ a1w, const float* __restrict__ vw,
                           const float* __restrict__ a2w, const float* __restrict__ c2w,
                           const float* __restrict__ c3w,
                           bf16* __restrict__ mextT, float* __restrict__ sigt, float* __restrict__ cconst,
                           bf16* __restrict__ wvT, bf16* __restrict__ wa2t,
                           bf16* __restrict__ c2wt, bf16* __restrict__ c3wt){
    __shared__ float t[32][33];
    const float rsc = 0.08838834764831845f;
    int blk = blockIdx.x, tid = threadIdx.x;
    if (blk < 9){
        #pragma unroll 1
        for (int e=0; e<8; ++e){
            int idx = e*256 + tid;
            int n = blk*16 + (idx>>7), h = idx&127;
            float acc = 0.f;
            if (n < 128){
                for (int d=0; d<128; ++d) acc += qw[h*128+d]*kw[n*128+d];
            } else if (n == 128){
                for (int d=0; d<128; ++d) acc += qw[h*128+d]*kb[d];
            } else if (n == 129){
                for (int d=0; d<128; ++d) acc += kw[h*128+d]*qb[d];
            }
            mextT[n*128+h] = (bf16)(acc*rsc);
        }
    } else if (blk == 9){
        if (tid < 128){
            float acc = 0.f;
            for (int h=0; h<128; ++h) acc += (tw[h]+tb[h]) * a1w[h*128+tid];
            sigt[tid] = sigmoidf_(acc);
        } else if (tid == 128){
            float acc = 0.f;
            for (int d=0; d<128; ++d) acc += qb[d]*kb[d];
            cconst[0] = acc*rsc;
        }
    } else if (blk < 26){
        int i = blk-10; dotrans_(t, vw, wvT, 128,128, i&3, i>>2, tid);
    } else if (blk < 42){
        int i = blk-26; dotrans_(t, a2w, wa2t, 128,128, i&3, i>>2, tid);
    } else if (blk < 298){
        int i = blk-42; dotrans_(t, c2w, c2wt, 512,512, i&15, i>>4, tid);
    } else {
        int i = blk-298; dotrans_(t, c3w, c3wt, 512,256, i&7, i>>3, tid);
    }
}

// compact kappa: bijection on [0,12800)
DEVI int kappa_(int k){
    int f = k>>7, h = k&127;
    if (f < 96)
        return (((f>>4)<<3) | (h>>4))*256 + ((f&15)>>2)*64 + (h&15)*4 + (f&3);
    else
        return 12288 + (h>>4)*64 + (h&15)*4 + (f&3);
}
__global__ void k_tc_kappa8(const float* __restrict__ in, unsigned char* __restrict__ out){
    __shared__ float t[32][33];
    const int C = 512;
    int c0 = blockIdx.x*32, r0 = blockIdx.y*32;
    int tc = threadIdx.x & 31, tr = threadIdx.x >> 5;
    #pragma unroll
    for (int i=0;i<4;i++){
        int r = tr + i*8;
        t[r][tc] = in[(size_t)(r0+r)*C + c0 + tc];
    }
    __syncthreads();
    #pragma unroll
    for (int i=0;i<4;i++){
        int ro = tr + i*8;
        float x = t[tc][ro]*FP8SC;
        int v = __builtin_amdgcn_cvt_pk_fp8_f32(x, x, 0, false);
        out[(size_t)(c0+ro)*KC_ + kappa_(r0+tc)] = (unsigned char)v;
    }
}

// ---------------- flat GEMM for interaction-attention scores ----------------
__global__ __launch_bounds__(256,2) void k_gatt(
    const float* __restrict__ feat, const float* __restrict__ emb,
    const bf16* __restrict__ wa2t, const float* __restrict__ a2b,
    const float* __restrict__ a3w, const float* __restrict__ sigt,
    float* __restrict__ attg)
{
    __shared__ bf16 sAt[128][72];
    __shared__ bf16 sBt[128][72];
    __shared__ float sRed[2][128];
    int tid=threadIdx.x, w=tid>>6, lane=tid&63, l15=lane&15, l4=lane>>4;
    int m0 = blockIdx.x*128;
    int wr = w>>1, wc = w&1;
    f32x4 acc[4][4];
    #pragma unroll
    for(int mi=0;mi<4;mi++)
        #pragma unroll
        for(int ni=0;ni<4;ni++) acc[mi][ni] = (f32x4){0.f,0.f,0.f,0.f};

    #pragma unroll 1
    for (int k0=0; k0<128; k0+=64){
        __syncthreads();
        #pragma unroll
        for (int t4=0; t4<4; t4++){
            int t = tid + t4*256;
            int row=t>>3, col=(t&7)*8;
            int gr = m0+row;
            int bb = gr/112, ff = gr - bb*112;
            bf16x8 o;
            if (ff < F_){
                float fv = feat[(size_t)bb*F_ + ff];
                const float* ep = emb + ff*H_ + k0 + col;
                f32x4 e0 = *(const f32x4*)ep;
                f32x4 e1 = *(const f32x4*)(ep+4);
                o[0]=(bf16)(fv*e0[0]); o[1]=(bf16)(fv*e0[1]); o[2]=(bf16)(fv*e0[2]); o[3]=(bf16)(fv*e0[3]);
                o[4]=(bf16)(fv*e1[0]); o[5]=(bf16)(fv*e1[1]); o[6]=(bf16)(fv*e1[2]); o[7]=(bf16)(fv*e1[3]);
            } else {
                #pragma unroll
                for (int e=0;e<8;e++) o[e]=(bf16)0.f;
            }
            *(bf16x8*)&sAt[row][col] = o;
            *(bf16x8*)&sBt[row][col] = *(const bf16x8*)(wa2t + row*H_ + k0 + col);
        }
        __syncthreads();
        #pragma unroll
        for(int ks=0;ks<2;ks++){
            bf16x8 af[4], bfr[4];
            #pragma unroll
            for(int mi=0;mi<4;mi++) af[mi] = *(const bf16x8*)&sAt[wr*64+mi*16+l15][ks*32+l4*8];
            #pragma unroll
            for(int ni=0;ni<4;ni++) bfr[ni] = *(const bf16x8*)&sBt[wc*64+ni*16+l15][ks*32+l4*8];
            #pragma unroll
            for(int mi=0;mi<4;mi++)
                #pragma unroll
                for(int ni=0;ni<4;ni++)
                    acc[mi][ni] = mfma16(af[mi], bfr[ni], acc[mi][ni]);
        }
    }
    float sg[4], ab[4], a3[4];
    #pragma unroll
    for (int ni=0;ni<4;ni++){
        int n = wc*64 + ni*16 + l15;
        sg[ni]=sigt[n]; ab[ni]=a2b[n]; a3[ni]=a3w[n];
    }
    #pragma unroll
    for (int mi=0;mi<4;mi++){
        float sj[4] = {0.f,0.f,0.f,0.f};
        #pragma unroll
        for (int ni=0;ni<4;ni++){
            #pragma unroll
            for (int j=0;j<4;j++){
                float u = sigmoidf_(acc[mi][ni][j] + ab[ni]);
                float t = sg[ni] + u;
                t = t>0.f ? t : 0.f;
                sj[j] += t*a3[ni];
            }
        }
        #pragma unroll
        for (int j=0;j<4;j++){
            float v = sj[j];
            #pragma unroll
            for (int m=1;m<16;m<<=1) v += __shfl_xor(v,m,16);
            sj[j]=v;
        }
        if (l15==0){
            #pragma unroll
            for (int j=0;j<4;j++) sRed[wc][wr*64+mi*16+l4*4+j] = sj[j];
        }
    }
    __syncthreads();
    if (tid < 128) attg[(size_t)m0 + tid] = sRed[0][tid] + sRed[1][tid];
}

// ---------------- fused per-batch attention: 512 thr; all weights in LDS/regs ----------------
// LDS (81792 B, 2 blocks/CU):
//   [0,33280)       sMext 130x128 bf16, stride 256B, SWZ
//   [33280,61952)   sNx 112x128 bf16 (stride 256B, SWZ)  UNION  sVT 128x112 (stride 224B, SWZ)
//   [61952,80384)   sP[8][16][72] bf16; pre-B5b aliases: sFeat/sAw/normP/xtP
//   [80384,81792)   sNorm[128], sAlpha[112], sBeta[112]
__global__ __launch_bounds__(512,2) void k_attn2(
    const float* __restrict__ feat, const float* __restrict__ emb,
    const bf16* __restrict__ mextT, const bf16* __restrict__ wvT,
    const float* __restrict__ vb, const float* __restrict__ cconst,
    const float* __restrict__ attg,
    unsigned char* __restrict__ xxb, bf16* __restrict__ xtb)
{
    __shared__ char L[81792];
    char* Lm = L;
    char* Ln = L + 33280;
    float* sFeat  = (float*)(L+61952);
    float* sAw    = (float*)(L+62400);
    float* normP  = (float*)(L+62848);   // [8][128] f32
    float* xtP    = (float*)(L+66944);   // [4][128] f32
    float* sNorm  = (float*)(L+80384);
    float* sAlpha = (float*)(L+80896);
    float* sBeta  = (float*)(L+81344);

    int b = blockIdx.x;
    int tid = threadIdx.x, w = tid>>6, lane = tid&63;
    int l15 = lane&15, l4 = lane>>4;
    bf16 (*sP)[72] = (bf16(*)[72])(L + 61952 + w*2304);

    // hoisted global loads: this wave's wvT row-tile + vb (latency hidden under staging)
    bf16x8 awv[4];
    #pragma unroll
    for (int kc=0;kc<4;kc++)
        awv[kc] = *(const bf16x8*)(wvT + (w*16+l15)*H_ + kc*32 + l4*8);
    float vbr[4];
    #pragma unroll
    for (int j=0;j<4;j++) vbr[j] = vb[w*16+l4*4+j];

    // stage sMext (rows 0..129), swizzled
    #pragma unroll 2
    for (int v = tid; v < 130*16; v += 512){
        int n = v >> 4, cg = (v & 15) * 8;
        *(u32x4*)(Lm + n*256 + SWZ(n, cg*2)) = *(const u32x4*)(mextT + n*128 + cg);
    }
    if (tid < FP) sFeat[tid] = (tid<F_) ? feat[(size_t)b*F_+tid] : 0.f;
    if (w==0){
        const float* ag = attg + (size_t)b*FP;
        float a0 = (lane<F_)? ag[lane] : -1e30f;
        float a1 = (lane+64<F_)? ag[lane+64] : -1e30f;
        float m = fmaxf(a0,a1);
        #pragma unroll
        for(int s=1;s<64;s<<=1) m = fmaxf(m, __shfl_xor(m,s,64));
        float e0 = (lane<F_)? __expf(a0-m):0.f;
        float e1 = (lane+64<F_)? __expf(a1-m):0.f;
        float s = e0+e1;
        #pragma unroll
        for(int t=1;t<64;t<<=1) s += __shfl_xor(s,t,64);
        float inv = 1.f/s;
        if (lane<FP) sAw[lane] = e0*inv;
        if (lane+64<FP) sAw[lane+64] = e1*inv;
    }
    __syncthreads();   // B1

    // pass1: column sums of squares
    int hp = (tid&63)*2, gg = tid>>6;
    {
        float fa0=0.f, fa1=0.f;
        #pragma unroll 4
        for (int it=0; it<13; ++it){
            int f = gg + 8*it;
            if (f < F_){
                float2 e2 = *(const float2*)(emb + f*H_ + hp);
                float v0 = sFeat[f]*e2.x, v1 = sFeat[f]*e2.y;
                fa0 += v0*v0; fa1 += v1*v1;
            }
        }
        *(float2*)(normP + gg*128 + hp) = make_float2(fa0, fa1);
    }
    __syncthreads();   // B2
    if (tid < 128){
        float s = 0.f;
        #pragma unroll
        for (int g2=0; g2<8; ++g2) s += normP[g2*128 + tid];
        sNorm[tid] = sqrtf(s);
    }
    __syncthreads();   // B3

    // pass2: write nx pre-scaled (swizzled), zero pad rows 100..111
    {
        float rn0 = __builtin_amdgcn_rcpf(sNorm[hp]);
        float rn1 = __builtin_amdgcn_rcpf(sNorm[hp+1]);
        #pragma unroll 4
        for (int it=0; it<13; ++it){
            int f = gg + 8*it;
            if (f < F_){
                float2 e2 = *(const float2*)(emb + f*H_ + hp);
                *(unsigned*)(Ln + f*256 + SWZ(f, hp*2)) = pack2_(sFeat[f]*e2.x*rn0, sFeat[f]*e2.y*rn1);
            }
        }
        for (int z=tid; z<768; z+=512){
            int f = 100 + (z>>6), hz = (z&63)*2;
            *(unsigned*)(Ln + f*256 + SWZ(f, hz*2)) = 0u;
        }
    }
    __syncthreads();   // B4

    int mt = w;

    // alpha/beta (sMext rows 128/129 from LDS) + xt partials
    if (mt < 7){
        int nrow = 128 + (l15&1);
        bf16x8 bfr8[4];
        #pragma unroll
        for (int kc=0;kc<4;kc++)
            bfr8[kc] = *(const bf16x8*)(Lm + nrow*256 + SWZ(nrow, (kc*32+l4*8)*2));
        f32x4 acc = {0.f,0.f,0.f,0.f};
        #pragma unroll
        for (int kc=0;kc<4;kc++){
            bf16x8 a = *(const bf16x8*)(Ln + (mt*16+l15)*256 + SWZ(mt*16+l15, (kc*32+l4*8)*2));
            acc = mfma16(a, bfr8[kc], acc);
        }
        if (l15==0){
            #pragma unroll
            for (int j=0;j<4;j++) sAlpha[mt*16+l4*4+j] = acc[j];
        }
        if (l15==1){
            #pragma unroll
            for (int j=0;j<4;j++) sBeta[mt*16+l4*4+j] = acc[j];
        }
    }
    {
        int g4 = tid>>7, h = tid&127;
        float acc=0.f;
        #pragma unroll 5
        for (int it=0; it<25; ++it){
            int f = g4 + 4*it;
            acc += sAw[f] * (float)*(const bf16*)(Ln + f*256 + SWZ(f, h*2));
        }
        xtP[g4*128+h] = acc;
    }
    __syncthreads();   // B5
    if (tid < 128)
        xtb[(size_t)b*H_+tid] = (bf16)((xtP[tid]+xtP[128+tid]+xtP[256+tid]+xtP[384+tid]) * sNorm[tid]);
    __syncthreads();   // B5b (xtP read complete before sP slots are written)

    // ---- S1 (two-pass staged in wave slot) + scores + e ----
    const float cc = cconst[0];
    unsigned uexB[3][2];
    float inv_[4];
    if (mt < 7){
        bf16x8 afxi[4];
        #pragma unroll
        for (int kc=0;kc<4;kc++)
            afxi[kc] = *(const bf16x8*)(Ln + (mt*16+l15)*256 + SWZ(mt*16+l15, (kc*32+l4*8)*2));
        f32x4 sc[7];
        #pragma unroll
        for (int gt=0; gt<7; gt++) sc[gt] = (f32x4){0.f,0.f,0.f,0.f};
        #pragma unroll 1
        for (int p=0; p<2; p++){
            #pragma unroll 2
            for (int nt4=0; nt4<4; nt4++){
                int nt = p*4 + nt4;
                bf16x8 bw[4];
                #pragma unroll
                for (int kc=0;kc<4;kc++)
                    bw[kc] = *(const bf16x8*)(Lm + (nt*16+l15)*256 + SWZ(nt*16+l15, (kc*32+l4*8)*2));
                f32x4 d = {0.f,0.f,0.f,0.f};
                #pragma unroll
                for (int kc=0;kc<4;kc++) d = mfma16(afxi[kc], bw[kc], d);
                #pragma unroll
                for (int j=0;j<4;j++) sP[l4*4+j][nt4*16+l15] = (bf16)d[j];
            }
            bf16x8 afs0 = *(const bf16x8*)&sP[l15][l4*8];
            bf16x8 afs1 = *(const bf16x8*)&sP[l15][32+l4*8];
            #pragma unroll
            for (int gt=0; gt<7; gt++){
                int r = gt*16+l15;
                bf16x8 b0 = *(const bf16x8*)(Ln + r*256 + SWZ(r, (p*64 + l4*8)*2));
                bf16x8 b1 = *(const bf16x8*)(Ln + r*256 + SWZ(r, (p*64 + 32 + l4*8)*2));
                sc[gt] = mfma16(afs0, b0, sc[gt]);
                sc[gt] = mfma16(afs1, b1, sc[gt]);
            }
        }
        float aj[4];
        #pragma unroll
        for (int j=0;j<4;j++) aj[j] = sAlpha[mt*16+l4*4+j];
        float rs[4] = {0.f,0.f,0.f,0.f};
        #pragma unroll
        for (int gt=0; gt<7; gt++){
            float bg = sBeta[gt*16+l15];
            int g = gt*16+l15;
            float e[4];
            #pragma unroll
            for (int j=0;j<4;j++){
                float val = sc[gt][j] + aj[j] + bg + cc;
                e[j] = (g<F_) ? __expf(sigmoidf_(val)) : 0.f;
                rs[j] += e[j];
            }
            if (gt < 4){
                #pragma unroll
                for (int j=0;j<4;j++) sP[l4*4+j][gt*16+l15] = (bf16)e[j];
            } else {
                uexB[gt-4][0] = pack2_(e[0],e[1]);
                uexB[gt-4][1] = pack2_(e[2],e[3]);
            }
        }
        #pragma unroll
        for (int j=0;j<4;j++){
            float v = rs[j];
            #pragma unroll
            for (int m2=1;m2<16;m2<<=1) v += __shfl_xor(v,m2,16);
            inv_[j] = 1.f/v;
        }
    }

    // ---- V^T row-tile (all 8 waves), operands already in regs ----
    unsigned vpk[7][2];
    {
        #pragma unroll
        for (int gt=0; gt<7; gt++){
            f32x4 acc = {0.f,0.f,0.f,0.f};
            #pragma unroll
            for (int kc=0;kc<4;kc++){
                int r = gt*16+l15;
                bf16x8 bfr = *(const bf16x8*)(Ln + r*256 + SWZ(r, (kc*32+l4*8)*2));
                acc = mfma16(awv[kc], bfr, acc);
            }
            vpk[gt][0] = pack2_(acc[0]+vbr[0], acc[1]+vbr[1]);
            vpk[gt][1] = pack2_(acc[2]+vbr[2], acc[3]+vbr[3]);
        }
    }
    __syncthreads();   // B6: all sNx reads complete

    union UP { unsigned u; bf16 v[2]; };
    {
        int ht = w;
        #pragma unroll
        for (int gt=0; gt<7; gt++){
            UP u0, u1;
            u0.u = vpk[gt][0]; u1.u = vpk[gt][1];
            int r0 = ht*16+l4*4;
            *(bf16*)(Ln + (r0  )*224 + SWZ(r0,   (gt*16+l15)*2)) = u0.v[0];
            *(bf16*)(Ln + (r0+1)*224 + SWZ(r0+1, (gt*16+l15)*2)) = u0.v[1];
            *(bf16*)(Ln + (r0+2)*224 + SWZ(r0+2, (gt*16+l15)*2)) = u1.v[0];
            *(bf16*)(Ln + (r0+3)*224 + SWZ(r0+3, (gt*16+l15)*2)) = u1.v[1];
        }
    }
    __syncthreads();   // B7

    // ---- PV: two passes over g; normalization deferred ----
    if (mt < 7){
        bf16x8 ap0 = *(const bf16x8*)&sP[l15][l4*8];
        bf16x8 ap1 = *(const bf16x8*)&sP[l15][32+l4*8];
        f32x4 acc8[8];
        #pragma unroll
        for (int ht=0;ht<8;ht++) acc8[ht] = (f32x4){0.f,0.f,0.f,0.f};
        #pragma unroll
        for (int ht=0; ht<8; ht++){
            int r = ht*16+l15;
            int c0 = l4*8, c1 = 32+l4*8;
            acc8[ht] = mfma16(ap0, ldb64x2((const bf16*)(Ln + r*224 + SWZ(r, c0*2)),
                                           (const bf16*)(Ln + r*224 + SWZ(r, (c0+4)*2))), acc8[ht]);
            acc8[ht] = mfma16(ap1, ldb64x2((const bf16*)(Ln + r*224 + SWZ(r, c1*2)),
                                           (const bf16*)(Ln + r*224 + SWZ(r, (c1+4)*2))), acc8[ht]);
        }
        #pragma unroll
        for (int gt=4; gt<7; gt++){
            #pragma unroll
            for (int j2=0; j2<2; j2++){
                UP u; u.u = uexB[gt-4][j2];
                sP[l4*4+j2*2  ][(gt-4)*16+l15] = u.v[0];
                sP[l4*4+j2*2+1][(gt-4)*16+l15] = u.v[1];
            }
        }
        #pragma unroll
        for (int j=0;j<4;j++) sP[l4*4+j][48+l15] = (bf16)0.f;
        bf16x8 ap2 = *(const bf16x8*)&sP[l15][l4*8];
        bf16x8 ap3 = *(const bf16x8*)&sP[l15][32+l4*8];
        #pragma unroll
        for (int ht=0; ht<8; ht++){
            int r = ht*16+l15;
            int c2 = 64+l4*8;
            int c3 = 96+l4*8;  if (c3 >= 112) c3 = 96;
            acc8[ht] = mfma16(ap2, ldb64x2((const bf16*)(Ln + r*224 + SWZ(r, c2*2)),
                                           (const bf16*)(Ln + r*224 + SWZ(r, (c2+4)*2))), acc8[ht]);
            acc8[ht] = mfma16(ap3, ldb64x2((const bf16*)(Ln + r*224 + SWZ(r, c3*2)),
                                           (const bf16*)(Ln + r*224 + SWZ(r, (c3+4)*2))), acc8[ht]);
        }
        float fs[4];
        #pragma unroll
        for (int j=0;j<4;j++) fs[j] = inv_[j]*FP8SC;
        #pragma unroll
        for (int ht=0; ht<8; ht++){
            unsigned u = cvtfp8x4_(acc8[ht][0]*fs[0], acc8[ht][1]*fs[1], acc8[ht][2]*fs[2], acc8[ht][3]*fs[3]);
            if (mt < 6){
                *(unsigned*)(xxb + (size_t)b*KC_ + (mt*8+ht)*256 + lane*4) = u;
            } else if (l4 == 0){
                *(unsigned*)(xxb + (size_t)b*KC_ + 12288 + ht*64 + l15*4) = u;
            }
        }
    }
}

// ---------------- fp8 split-K GEMM ----------------
__global__ __launch_bounds__(256,2) void k_gemm_fp8(const unsigned char* __restrict__ A,
        const unsigned char* __restrict__ Bt, float* __restrict__ part, int M, int N, int K, int KS)
{
    __shared__ unsigned char sA[128][72];
    __shared__ unsigned char sB[128][72];
    int tid=threadIdx.x, w=tid>>6, lane=tid&63, l15=lane&15, l4=lane>>4;
    int m0 = blockIdx.y*128, n0 = blockIdx.x*128;
    int kbeg = blockIdx.z*KS, kend = kbeg + KS;
    int wr = w>>1, wc = w&1;
    f32x4 acc[4][4];
    #pragma unroll
    for(int mi=0;mi<4;mi++)
        #pragma unroll
        for(int ni=0;ni<4;ni++) acc[mi][ni] = (f32x4){0.f,0.f,0.f,0.f};

    for (int k0=kbeg; k0<kend; k0+=64){
        __syncthreads();
        #pragma unroll
        for (int t2=0;t2<2;t2++){
            int t = tid + t2*256;
            int row=t>>2, col=(t&3)*16;
            *(u32x4*)&sA[row][col] = *(const u32x4*)(A + (size_t)(m0+row)*K + k0 + col);
            *(u32x4*)&sB[row][col] = *(const u32x4*)(Bt + (size_t)(n0+row)*K + k0 + col);
        }
        __syncthreads();
        #pragma unroll
        for(int ks=0;ks<2;ks++){
            long af[4], bfr[4];
            #pragma unroll
            for(int mi=0;mi<4;mi++) af[mi] = *(const long*)&sA[wr*64+mi*16+l15][ks*32+l4*8];
            #pragma unroll
            for(int ni=0;ni<4;ni++) bfr[ni] = *(const long*)&sB[wc*64+ni*16+l15][ks*32+l4*8];
            #pragma unroll
            for(int mi=0;mi<4;mi++)
                #pragma unroll
                for(int ni=0;ni<4;ni++)
                    acc[mi][ni] = mfma8(af[mi], bfr[ni], acc[mi][ni]);
        }
    }
    float* pz = part + (size_t)blockIdx.z*M*N;
    #pragma unroll
    for(int mi=0;mi<4;mi++)
        #pragma unroll
        for(int ni=0;ni<4;ni++){
            int col = n0 + wc*64 + ni*16 + l15;
            #pragma unroll
            for(int j=0;j<4;j++){
                int row = m0 + wr*64 + mi*16 + l4*4 + j;
                pz[(size_t)row*N + col] = acc[mi][ni][j];
            }
        }
}

__global__ void k_c1fin(const float* __restrict__ part, const float* __restrict__ bias,
                        bf16* __restrict__ out){
    const size_t MN = (size_t)B_*512;
    size_t e0 = ((size_t)blockIdx.x*256 + threadIdx.x)*4;
    f32x4 s = *(const f32x4*)(part + e0);
    s += *(const f32x4*)(part + MN + e0);
    s += *(const f32x4*)(part + 2*MN + e0);
    s += *(const f32x4*)(part + 3*MN + e0);
    f32x4 bb = *(const f32x4*)(bias + (e0 & 511));
    const float ds = 1.0f/(FP8SC*FP8SC);
    unsigned long long u = pack4_(eluf_(s[0]*ds+bb[0]), eluf_(s[1]*ds+bb[1]),
                                  eluf_(s[2]*ds+bb[2]), eluf_(s[3]*ds+bb[3]));
    *(unsigned long long*)(out + e0) = u;
}

// ---------------- generic tiled GEMM (c2, c3) ----------------
template<int BN, bool ELU>
__global__ __launch_bounds__(256,2) void k_gemm(const bf16* __restrict__ A, const bf16* __restrict__ Bt,
        const float* __restrict__ bias, bf16* __restrict__ out, int M, int N, int K)
{
    __shared__ bf16 sAt[128][72];
    __shared__ bf16 sBt[BN][72];
    int tid=threadIdx.x, w=tid>>6, lane=tid&63, l15=lane&15, l4=lane>>4;
    int m0 = blockIdx.y*128, n0 = blockIdx.x*BN;
    constexpr int MI = (BN==128)?4:2;
    constexpr int NI = (BN==128)?4:BN/16;
    int wr = (BN==128)? (w>>1) : w;
    int wc = (BN==128)? (w&1) : 0;
    f32x4 acc[MI][NI];
    #pragma unroll
    for(int mi=0;mi<MI;mi++)
        #pragma unroll
        for(int ni=0;ni<NI;ni++) acc[mi][ni] = (f32x4){0.f,0.f,0.f,0.f};

    for (int k0=0; k0<K; k0+=64){
        __syncthreads();
        for (int t=tid; t<128*8; t+=256){
            int row=t>>3, col=(t&7)*8;
            *(bf16x8*)&sAt[row][col] = *(const bf16x8*)(A + (size_t)(m0+row)*K + k0 + col);
        }
        for (int t=tid; t<BN*8; t+=256){
            int row=t>>3, col=(t&7)*8;
            *(bf16x8*)&sBt[row][col] = *(const bf16x8*)(Bt + (size_t)(n0+row)*K + k0 + col);
        }
        __syncthreads();
        #pragma unroll
        for(int ks=0;ks<2;ks++){
            bf16x8 af[MI], bfr[NI];
            #pragma unroll
            for(int mi=0;mi<MI;mi++) af[mi] = *(const bf16x8*)&sAt[wr*(MI*16)+mi*16+l15][ks*32+l4*8];
            #pragma unroll
            for(int ni=0;ni<NI;ni++) bfr[ni] = *(const bf16x8*)&sBt[wc*64+ni*16+l15][ks*32+l4*8];
            #pragma unroll
            for(int mi=0;mi<MI;mi++)
                #pragma unroll
                for(int ni=0;ni<NI;ni++)
                    acc[mi][ni] = mfma16(af[mi], bfr[ni], acc[mi][ni]);
        }
    }
    #pragma unroll
    for(int mi=0;mi<MI;mi++)
        #pragma unroll
        for(int ni=0;ni<NI;ni++){
            int col = n0 + wc*64 + ni*16 + l15;
            float bc = bias[col];
            #pragma unroll
            for(int j=0;j<4;j++){
                int row = m0 + wr*(MI*16) + mi*16 + l4*4 + j;
                float v = acc[mi][ni][j] + bc;
                if (ELU) v = eluf_(v);
                out[(size_t)row*N + col] = (bf16)v;
            }
        }
}

// ---------------- fused c4+c5+control heads (32 rows/block, 256 blocks) ----------------
__global__ __launch_bounds__(256,2) void k_ctail(const bf16* __restrict__ c3o,
    const float* __restrict__ c4w, const float* __restrict__ c4b,
    const float* __restrict__ c5w, const float* __restrict__ c5b,
    const float* __restrict__ clw, const float* __restrict__ clb,
    const float* __restrict__ ctw, const float* __restrict__ ctb, float* __restrict__ outp)
{
    __shared__ float sA[32][260];
    __shared__ float sB[32][132];
    __shared__ float sC[32][68];
    int tid = threadIdx.x; int r0 = blockIdx.x*32;
    for (int v=tid; v<32*64; v+=256){
        int r=v>>6, c=(v&63)*4;
        bf16x4 x = *(const bf16x4*)(c3o + (size_t)(r0+r)*256 + c);
        sA[r][c]=(float)x[0]; sA[r][c+1]=(float)x[1]; sA[r][c+2]=(float)x[2]; sA[r][c+3]=(float)x[3];
    }
    __syncthreads();
    {   // c4: K=256 -> 128
        int j = tid&127, rb = tid>>7;
        float acc[16];
        #pragma unroll
        for (int i=0;i<16;i++) acc[i]=c4b[j];
        #pragma unroll 4
        for (int h=0;h<256;h++){
            float wv = c4w[h*128+j];
            #pragma unroll
            for (int i=0;i<16;i++) acc[i] += sA[2*i+rb][h]*wv;
        }
        #pragma unroll
        for (int i=0;i<16;i++) sB[2*i+rb][j] = eluf_(acc[i]);
    }
    __syncthreads();
    {   // c5: K=128 -> 64
        int j = tid&63, rb = tid>>6;
        float acc[8];
        #pragma unroll
        for (int i=0;i<8;i++) acc[i]=c5b[j];
        #pragma unroll 4
        for (int h=0;h<128;h++){
            float wv = c5w[h*64+j];
            #pragma unroll
            for (int i=0;i<8;i++) acc[i] += sB[4*i+rb][h]*wv;
        }
        #pragma unroll
        for (int i=0;i<8;i++) sC[4*i+rb][j] = eluf_(acc[i]);
    }
    __syncthreads();
    if (tid < 32){
        float r1 = clb[0], r2 = ctb[0];
        #pragma unroll 8
        for (int k=0;k<64;k++){ float v = sC[tid][k]; r1 += v*clw[k]; r2 += v*ctw[k]; }
        int row = r0 + tid;
        outp[row] = r1;
        outp[B_ + row] = sigmoidf_(r1);
        outp[(size_t)2*B_ + row] = r2;
    }
}

// ---------------- fused uplift tower (32 rows/block, 256 blocks) ----------------
__global__ __launch_bounds__(256,2) void k_utower(const bf16* __restrict__ xtb,
    const float* __restrict__ u1w, const float* __restrict__ u1b,
    const float* __restrict__ u2w, const float* __restrict__ u2b,
    const float* __restrict__ u3w, const float* __restrict__ u3b,
    const float* __restrict__ u4w, const float* __restrict__ u4b,
    const float* __restrict__ tlw, const float* __restrict__ tlb,
    const float* __restrict__ utw, const float* __restrict__ utb, float* __restrict__ outp)
{
    __shared__ float sA[32][132];
    __shared__ float sB[32][132];
    __shared__ float sC[32][68];
    __shared__ float sD[32][36];
    __shared__ float sE[32][20];
    int tid = threadIdx.x; int r0 = blockIdx.x*32;
    for (int v=tid; v<32*32; v+=256){
        int r=v>>5, c=(v&31)*4;
        bf16x4 x = *(const bf16x4*)(xtb + (size_t)(r0+r)*128 + c);
        sA[r][c]=(float)x[0]; sA[r][c+1]=(float)x[1]; sA[r][c+2]=(float)x[2]; sA[r][c+3]=(float)x[3];
    }
    __syncthreads();
    {   // u1: 128 -> 128
        int j = tid&127, rb = tid>>7;
        float acc[16];
        #pragma unroll
        for (int i=0;i<16;i++) acc[i]=u1b[j];
        #pragma unroll 4
        for (int h=0;h<128;h++){
            float wv = u1w[h*128+j];
            #pragma unroll
            for (int i=0;i<16;i++) acc[i] += sA[2*i+rb][h]*wv;
        }
        #pragma unroll
        for (int i=0;i<16;i++) sB[2*i+rb][j] = eluf_(acc[i]);
    }
    __syncthreads();
    {   // u2: 128 -> 64
        int j = tid&63, rb = tid>>6;
        float acc[8];
        #pragma unroll
        for (int i=0;i<8;i++) acc[i]=u2b[j];
        #pragma unroll 4
        for (int h=0;h<128;h++){
            float wv = u2w[h*64+j];
            #pragma unroll
            for (int i=0;i<8;i++) acc[i] += sB[4*i+rb][h]*wv;
        }
        #pragma unroll
        for (int i=0;i<8;i++) sC[4*i+rb][j] = eluf_(acc[i]);
    }
    __syncthreads();
    {   // u3: 64 -> 32
        int j = tid&31, rb = tid>>5;
        float acc[4];
        #pragma unroll
        for (int i=0;i<4;i++) acc[i]=u3b[j];
        #pragma unroll 4
        for (int h=0;h<64;h++){
            float wv = u3w[h*32+j];
            #pragma unroll
            for (int i=0;i<4;i++) acc[i] += sC[8*i+rb][h]*wv;
        }
        #pragma unroll
        for (int i=0;i<4;i++) sD[8*i+rb][j] = eluf_(acc[i]);
    }
    __syncthreads();
    {   // u4: 32 -> 16
        int j = tid&15, rb = tid>>4;
        float acc[2];
        acc[0]=u4b[j]; acc[1]=u4b[j];
        #pragma unroll 4
        for (int h=0;h<32;h++){
            float wv = u4w[h*16+j];
            acc[0] += sD[rb][h]*wv;
            acc[1] += sD[16+rb][h]*wv;
        }
        sE[rb][j] = eluf_(acc[0]);
        sE[16+rb][j] = eluf_(acc[1]);
    }
    __syncthreads();
    if (tid < 32){
        float r1 = tlb[0], r2 = utb[0];
        #pragma unroll
        for (int k=0;k<16;k++){ float v = sE[tid][k]; r1 += v*tlw[k]; r2 += v*utw[k]; }
        int row = r0 + tid;
        outp[(size_t)3*B_ + row] = r1;
        outp[(size_t)4*B_ + row] = sigmoidf_(r1);
        outp[(size_t)5*B_ + row] = r2;
    }
}

extern "C" void kernel_launch(void* const* d_in, const int* in_sizes, int n_in,
                              void* d_out, int out_size, void* d_ws, size_t ws_size,
                              hipStream_t stream) {
    const float* feat=(const float*)d_in[0];
    const float* emb =(const float*)d_in[2];
    const float* t_w =(const float*)d_in[3]; const float* t_b=(const float*)d_in[4];
    const float* qw  =(const float*)d_in[5]; const float* qb =(const float*)d_in[6];
    const float* kw  =(const float*)d_in[7]; const float* kb =(const float*)d_in[8];
    const float* vw  =(const float*)d_in[9]; const float* vb =(const float*)d_in[10];
    const float* a1w =(const float*)d_in[11];
    const float* a2w =(const float*)d_in[12]; const float* a2b=(const float*)d_in[13];
    const float* a3w =(const float*)d_in[14];
    const float* c1w =(const float*)d_in[15]; const float* c1b=(const float*)d_in[16];
    const float* c2w =(const float*)d_in[17]; const float* c2b=(const float*)d_in[18];
    const float* c3w =(const float*)d_in[19]; const float* c3b=(const float*)d_in[20];
    const float* c4w =(const float*)d_in[21]; const float* c4b=(const float*)d_in[22];
    const float* c5w =(const float*)d_in[23]; const float* c5b=(const float*)d_in[24];
    const float* clw =(const float*)d_in[25]; const float* clb=(const float*)d_in[26];
    const float* ctw =(const float*)d_in[27]; const float* ctb=(const float*)d_in[28];
    const float* u1w =(const float*)d_in[29]; const float* u1b=(const float*)d_in[30];
    const float* u2w =(const float*)d_in[31]; const float* u2b=(const float*)d_in[32];
    const float* u3w =(const float*)d_in[33]; const float* u3b=(const float*)d_in[34];
    const float* u4w =(const float*)d_in[35]; const float* u4b=(const float*)d_in[36];
    const float* tlw =(const float*)d_in[37]; const float* tlb=(const float*)d_in[38];
    const float* utw =(const float*)d_in[39]; const float* utb=(const float*)d_in[40];
    float* outp = (float*)d_out;

    char* ws = (char*)d_ws;
    size_t off = 0;
    auto alloc = [&](size_t bytes)->char*{ char* p = ws + off; off += (bytes + 255) & ~(size_t)255; return p; };
    unsigned char* xxb = (unsigned char*)alloc((size_t)B_*KC_);
    float* part  = (float*)alloc((size_t)SPLIT_*B_*512*4);
    float* attg  = (float*)alloc((size_t)B_*FP*4);
    bf16* xtb    = (bf16*)alloc((size_t)B_*128*2);
    bf16* cbuf1  = (bf16*)alloc((size_t)B_*512*2);
    bf16* mextT  = (bf16*)alloc(144*128*2);
    bf16* wvT    = (bf16*)alloc(128*128*2);
    bf16* wa2t   = (bf16*)alloc(128*128*2);
    unsigned char* c1wtk8 = (unsigned char*)alloc((size_t)512*KC_);
    bf16* c2wt   = (bf16*)alloc((size_t)512*512*2);
    bf16* c3wt   = (bf16*)alloc((size_t)512*256*2);
    float* sigt  = (float*)alloc(128*4);
    float* cconst= (float*)alloc(4);
    bf16* cbuf2 = (bf16*)(xxb);
    bf16* cbuf3 = (bf16*)(xxb + (16u<<20));
    (void)ws_size; (void)in_sizes; (void)n_in; (void)out_size;

    k_prep_all<<<426,256,0,stream>>>(qw,qb,kw,kb,t_w,t_b,a1w, vw, a2w, c2w, c3w,
                                     mextT, sigt, cconst, wvT, wa2t, c2wt, c3wt);
    k_tc_kappa8<<<dim3(16,400),256,0,stream>>>(c1w, c1wtk8);

    k_gatt<<<7168,256,0,stream>>>(feat, emb, wa2t, a2b, a3w, sigt, attg);

    k_attn2<<<B_,512,0,stream>>>(feat,emb,mextT,wvT,vb,cconst,attg, xxb, xtb);

    k_utower<<<256,256,0,stream>>>(xtb,u1w,u1b,u2w,u2b,u3w,u3b,u4w,u4b,tlw,tlb,utw,utb,outp);

    k_gemm_fp8<<<dim3(4,64,SPLIT_),256,0,stream>>>(xxb, c1wtk8, part, B_,512,KC_, KC_/SPLIT_);
    k_c1fin<<<4096,256,0,stream>>>(part, c1b, cbuf1);

    k_gemm<128,true><<<dim3(4,64),256,0,stream>>>(cbuf1, c2wt, c2b, cbuf2, B_,512,512);
    k_gemm<128,true><<<dim3(2,64),256,0,stream>>>(cbuf2, c3wt, c3b, cbuf3, B_,256,512);
    k_ctail<<<256,256,0,stream>>>(cbuf3,c4w,c4b,c5w,c5b,clw,clb,ctw,ctb,outp);
}